// Round 5
// baseline (1328.485 us; speedup 1.0000x reference)
//
#include <hip/hip_runtime.h>
#include <cstdint>
#include <cstddef>

#define NN 100000
#define EE 1600000
#define XDIM 1553
#define HD 128

typedef __attribute__((ext_vector_type(8))) short short8;
typedef __attribute__((ext_vector_type(4))) float f32x4;

union Frag { unsigned int u[4]; short8 s; uint4 v; };

// fragment-major weight regions (ushort units).
// Element (col,k,plane): kt=k>>5, ct=col>>4, li=col&15, lg=(k>>3)&3, j=k&7
//   idx = base + ((kt*2+plane)*nct + ct)*512 + li*32 + lg*8 + j
// A wave reads one (ct,plane) fragment as 64 lanes x 16B = 1KB contiguous.
#define OFF_DES 0        // nct=8,  24 kt
#define OFF_TW  196608   // nct=8,  24 kt
#define OFF_NUM 393216   // nct=8,   1 kt
#define OFF_CAT 401408   // nct=8,   1 kt
#define OFF_WIN 409600   // nct=8,  16 kt
#define OFF_L1  540672   // nct=24,  4 kt (root1|rel1[0]|rel1[1] as cols 0..383)
#define OFF_L2  638976   // nct=24,  4 kt
#define OFF_CLS 737280   // nct=8,   4 kt
#define WT_SITES 385024  // (col,k) sites; each writes hi+lo

// hi = trunc-bf16(f), lo = trunc-bf16(f - hi). Packed: 2 elems -> 1 u32 via v_perm.
__device__ __forceinline__ void cvt_pair(float f0, float f1,
                                         unsigned int& hi, unsigned int& lo) {
  unsigned int u0 = __float_as_uint(f0), u1 = __float_as_uint(f1);
  hi = __builtin_amdgcn_perm(u1, u0, 0x07060302u);
  float l0 = f0 - __uint_as_float(u0 & 0xFFFF0000u);
  float l1 = f1 - __uint_as_float(u1 & 0xFFFF0000u);
  lo = __builtin_amdgcn_perm(__float_as_uint(l1), __float_as_uint(l0), 0x07060302u);
}

// ---------------- weight pre-convert -> fragment-major (runs once, tiny) --------
__global__ __launch_bounds__(256) void k_prepw(
    const float* __restrict__ Wdes, const float* __restrict__ Wtw,
    const float* __restrict__ Wnum, const float* __restrict__ Wcat,
    const float* __restrict__ Win,  const float* __restrict__ root1,
    const float* __restrict__ rel1, const float* __restrict__ root2,
    const float* __restrict__ rel2, const float* __restrict__ Wcls,
    unsigned short* __restrict__ Wt) {
  int id = blockIdx.x * 256 + threadIdx.x;
  if (id >= WT_SITES) return;
  const float* src; int K, Kpad, base, nct, colofs, local;
  if (id < 98304)       { src=Wdes;        K=768; Kpad=768; base=OFF_DES; nct=8;  colofs=0;   local=id; }
  else if (id < 196608) { src=Wtw;         K=768; Kpad=768; base=OFF_TW;  nct=8;  colofs=0;   local=id-98304; }
  else if (id < 200704) { src=Wnum;        K=6;   Kpad=32;  base=OFF_NUM; nct=8;  colofs=0;   local=id-196608; }
  else if (id < 204800) { src=Wcat;        K=11;  Kpad=32;  base=OFF_CAT; nct=8;  colofs=0;   local=id-200704; }
  else if (id < 270336) { src=Win;         K=512; Kpad=512; base=OFF_WIN; nct=8;  colofs=0;   local=id-204800; }
  else if (id < 286720) { src=root1;       K=128; Kpad=128; base=OFF_L1;  nct=24; colofs=0;   local=id-270336; }
  else if (id < 303104) { src=rel1;        K=128; Kpad=128; base=OFF_L1;  nct=24; colofs=128; local=id-286720; }
  else if (id < 319488) { src=rel1+16384;  K=128; Kpad=128; base=OFF_L1;  nct=24; colofs=256; local=id-303104; }
  else if (id < 335872) { src=root2;       K=128; Kpad=128; base=OFF_L2;  nct=24; colofs=0;   local=id-319488; }
  else if (id < 352256) { src=rel2;        K=128; Kpad=128; base=OFF_L2;  nct=24; colofs=128; local=id-335872; }
  else if (id < 368640) { src=rel2+16384;  K=128; Kpad=128; base=OFF_L2;  nct=24; colofs=256; local=id-352256; }
  else                  { src=Wcls;        K=128; Kpad=128; base=OFF_CLS; nct=8;  colofs=0;   local=id-368640; }
  int col = local / Kpad;
  int k = local - col * Kpad;
  float v = (k < K) ? src[(size_t)k * 128 + col] : 0.f;
  unsigned int u = __float_as_uint(v);
  float lo = v - __uint_as_float(u & 0xFFFF0000u);
  int colp = col + colofs;
  int kt = k >> 5, ct = colp >> 4, liq = colp & 15, lgq = (k >> 3) & 3, jq = k & 7;
  int hi_idx = base + ((kt * 2) * nct + ct) * 512 + liq * 32 + lgq * 8 + jq;
  Wt[hi_idx] = (unsigned short)(u >> 16);
  Wt[hi_idx + nct * 512] = (unsigned short)(__float_as_uint(lo) >> 16);
}

// ---------------- CSR build ----------------
__global__ __launch_bounds__(256) void k_count(const int* __restrict__ ei,
                                               const int* __restrict__ et,
                                               int* __restrict__ cnt2) {
  int e = blockIdx.x * 256 + threadIdx.x;
  if (e >= EE) return;
  atomicAdd(&cnt2[et[e] * NN + ei[EE + e]], 1);
}

__global__ __launch_bounds__(256) void k_scan1(const int* __restrict__ cnt2,
                                               int* __restrict__ row_ptr,
                                               int* __restrict__ bsum) {
  __shared__ int sums[256];
  int t = threadIdx.x;
  int base = blockIdx.x * 1024 + t * 4;
  int v[4]; int s = 0;
#pragma unroll
  for (int j = 0; j < 4; ++j) {
    int idx = base + j;
    v[j] = (idx < NN) ? (cnt2[idx] + cnt2[NN + idx]) : 0;
    s += v[j];
  }
  sums[t] = s;
  __syncthreads();
  for (int d = 1; d < 256; d <<= 1) {
    int val = (t >= d) ? sums[t - d] : 0;
    __syncthreads();
    sums[t] += val;
    __syncthreads();
  }
  int excl = sums[t] - s;
  if (t == 255) bsum[blockIdx.x] = sums[t];
  int run = excl;
#pragma unroll
  for (int j = 0; j < 4; ++j) {
    int idx = base + j;
    if (idx < NN) row_ptr[idx] = run;
    run += v[j];
  }
}

__global__ __launch_bounds__(128) void k_scan2(int* __restrict__ bsum, int nb) {
  __shared__ int s[128];
  int t = threadIdx.x;
  int v = (t < nb) ? bsum[t] : 0;
  s[t] = v;
  __syncthreads();
  for (int d = 1; d < 128; d <<= 1) {
    int val = (t >= d) ? s[t - d] : 0;
    __syncthreads();
    s[t] += val;
    __syncthreads();
  }
  if (t < nb) bsum[t] = s[t] - v;
}

__global__ __launch_bounds__(256) void k_scan3(int* __restrict__ row_ptr,
                                               const int* __restrict__ bsum) {
  int idx = blockIdx.x * 256 + threadIdx.x;
  if (idx < NN) row_ptr[idx] += bsum[idx >> 10];
  if (idx == NN) row_ptr[NN] = EE;
}

__global__ __launch_bounds__(256) void k_fill(const int* __restrict__ ei,
                                              const int* __restrict__ et,
                                              const int* __restrict__ row_ptr,
                                              int* __restrict__ fillpos,
                                              int* __restrict__ entries) {
  int e = blockIdx.x * 256 + threadIdx.x;
  if (e >= EE) return;
  int src = ei[e];
  int dst = ei[EE + e];
  int r = et[e];
  int pos = atomicAdd(&fillpos[dst], 1);
  entries[row_ptr[dst] + pos] = src | (r << 20);
}

// ---------------- fused projection (MFMA, split-bf16, barrier-free) -------------
// 64 nodes/block, 4 waves, wave = 16 rows x 128 cols, 3 blocks/CU.
// B fragments loaded DIRECTLY from L2-hot fragment-major Wt (1KB contiguous per
// wave-instruction) -> no LDS staging, no barriers anywhere. z (phase A->B
// transpose) is wave-private LDS. X register pipeline depth-3 (HBM latency).
__global__ __launch_bounds__(256, 3) void k_proj2(
    const float* __restrict__ x,
    const float* __restrict__ bdes, const float* __restrict__ btw,
    const float* __restrict__ bnum, const float* __restrict__ bcat,
    const float* __restrict__ bin,  const float* __restrict__ pa,
    const unsigned short* __restrict__ Wt, float* __restrict__ h0) {
  __shared__ unsigned short z_hi[64 * 128], z_lo[64 * 128];     // 16KB + 16KB

  const int t = threadIdx.x;
  const int node0 = blockIdx.x * 64;
  const int w = t >> 6, lane = t & 63;
  const int li = lane & 15, lg = lane >> 4;
  const int flo = li * 32 + lg * 8;   // ushort offset within a fragment block

  // one A-row per (wave, li)
  const int rowA = w * 16 + li;
  int nodeA = node0 + rowA;
  int ndA = nodeA < NN ? nodeA : NN - 1;
  const float* xrow = x + (size_t)ndA * XDIM;

#define CVT_A(F, AH, AL)                                                         \
  do {                                                                           \
    _Pragma("unroll")                                                            \
    for (int q_ = 0; q_ < 4; ++q_)                                               \
      cvt_pair((F)[2 * q_], (F)[2 * q_ + 1], (AH).u[q_], (AL).u[q_]);            \
  } while (0)

// 8 col-tiles, B hi/lo fragments direct from global (PB = hi-plane tile base)
#define MFMA8D(AH, AL, ACC, PB)                                                  \
  do {                                                                           \
    _Pragma("unroll")                                                            \
    for (int ct_ = 0; ct_ < 8; ++ct_) {                                          \
      Frag bh_, bl_;                                                             \
      bh_.v = *(const uint4*)((PB) + ct_ * 512 + flo);                           \
      bl_.v = *(const uint4*)((PB) + 4096 + ct_ * 512 + flo);                    \
      (ACC)[ct_] = __builtin_amdgcn_mfma_f32_16x16x32_bf16((AH).s, bl_.s, (ACC)[ct_], 0, 0, 0); \
      (ACC)[ct_] = __builtin_amdgcn_mfma_f32_16x16x32_bf16((AL).s, bh_.s, (ACC)[ct_], 0, 0, 0); \
      (ACC)[ct_] = __builtin_amdgcn_mfma_f32_16x16x32_bf16((AH).s, bh_.s, (ACC)[ct_], 0, 0, 0); \
    }                                                                            \
  } while (0)

// one K-tile of phase A: convert X[T], prefetch X(T+3) back into same buf,
// MFMA against direct-loaded W fragments. No barriers.
#define TILE(XB, T)                                                              \
  do {                                                                           \
    Frag ah_, al_;                                                               \
    CVT_A(XB, ah_, al_);                                                         \
    {                                                                            \
      int kx_ = (T) + 3; if (kx_ > 23) kx_ = 23;                                 \
      const int xo_ = kx_ * 32;                                                  \
      _Pragma("unroll")                                                          \
      for (int j_ = 0; j_ < 8; ++j_) (XB)[j_] = xr[xo_ + j_];                    \
    }                                                                            \
    MFMA8D(ah_, al_, zacc, wseg + ((T) * 16) * 512);                             \
  } while (0)

#define MFMA_BD(KT, PB)                                                          \
  do {                                                                           \
    Frag ah_, al_;                                                               \
    int byte_ = rowA * 256 + (((KT) * 32 + lg * 8) << 1);                        \
    byte_ ^= (rowA & 7) << 4;                                                    \
    ah_.v = *(const uint4*)((char*)z_hi + byte_);                                \
    al_.v = *(const uint4*)((char*)z_lo + byte_);                                \
    MFMA8D(ah_, al_, hacc, PB);                                                  \
  } while (0)

#define Z_EPI(ZACC, BIASP)                                                       \
  do {                                                                           \
    _Pragma("unroll")                                                            \
    for (int ct_ = 0; ct_ < 8; ++ct_) {                                          \
      int col_ = ct_ * 16 + li;                                                  \
      float bv_ = (BIASP)[col_];                                                 \
      _Pragma("unroll")                                                          \
      for (int r_ = 0; r_ < 4; ++r_) {                                           \
        float v_ = (ZACC)[ct_][r_] + bv_;                                        \
        v_ = v_ >= 0.f ? v_ : 0.01f * v_;                                        \
        int row_ = w * 16 + lg * 4 + r_;                                         \
        int byte_ = row_ * 256 + col_ * 2;                                       \
        byte_ ^= (row_ & 7) << 4;                                                \
        unsigned int u_ = __float_as_uint(v_);                                   \
        *(unsigned short*)((char*)z_hi + byte_) = (unsigned short)(u_ >> 16);    \
        float lo_ = v_ - __uint_as_float(u_ & 0xFFFF0000u);                      \
        *(unsigned short*)((char*)z_lo + byte_) = (unsigned short)(__float_as_uint(lo_) >> 16); \
      }                                                                          \
    }                                                                            \
  } while (0)

// phase B: hacc += z @ Win[SLICE*128 .. +127]; z is wave-private, W direct.
#define PHASE_B(SLICE)                                                           \
  do {                                                                           \
    MFMA_BD(0, Wt + OFF_WIN + (((SLICE) * 4 + 0) * 16) * 512);                   \
    MFMA_BD(1, Wt + OFF_WIN + (((SLICE) * 4 + 1) * 16) * 512);                   \
    MFMA_BD(2, Wt + OFF_WIN + (((SLICE) * 4 + 2) * 16) * 512);                   \
    MFMA_BD(3, Wt + OFF_WIN + (((SLICE) * 4 + 3) * 16) * 512);                   \
  } while (0)

  f32x4 hacc[8];
#pragma unroll
  for (int b = 0; b < 8; ++b) hacc[b] = (f32x4)0.f;

  // ---- big segments: des (s=0), tweet (s=1); K=768 = 24 K-tiles ----
#pragma unroll
  for (int s = 0; s < 2; ++s) {
    const int off = (s == 0) ? 785 : 6;
    const unsigned short* wseg = Wt + (s == 0 ? OFF_DES : OFF_TW);
    const float* bias = (s == 0) ? bdes : btw;
    const float* xr = xrow + off + lg * 8;

    f32x4 zacc[8];
#pragma unroll
    for (int b = 0; b < 8; ++b) zacc[b] = (f32x4)0.f;

    float X0[8], X1[8], X2[8];
#pragma unroll
    for (int j = 0; j < 8; ++j) X0[j] = xr[j];
#pragma unroll
    for (int j = 0; j < 8; ++j) X1[j] = xr[32 + j];
#pragma unroll
    for (int j = 0; j < 8; ++j) X2[j] = xr[64 + j];

    for (int base = 0; base < 24; base += 6) {
      TILE(X0, base + 0);
      TILE(X1, base + 1);
      TILE(X2, base + 2);
      TILE(X0, base + 3);
      TILE(X1, base + 4);
      TILE(X2, base + 5);
    }
    Z_EPI(zacc, bias);
    PHASE_B(s);
  }

  // ---- small segments: num (K=6), cat (K=11); single padded K-tile each ----
#pragma unroll
  for (int u = 0; u < 2; ++u) {
    const int offu = (u == 0) ? 0 : 774;
    const int Ksu = (u == 0) ? 6 : 11;
    const unsigned short* wseg = Wt + (u == 0 ? OFF_NUM : OFF_CAT);
    const float* biasu = (u == 0) ? bnum : bcat;
    const float* xr = xrow + offu + lg * 8;

    float f[8];
#pragma unroll
    for (int j = 0; j < 8; ++j) f[j] = (lg * 8 + j < Ksu) ? xr[j] : 0.f;

    f32x4 zacc[8];
#pragma unroll
    for (int b = 0; b < 8; ++b) zacc[b] = (f32x4)0.f;

    {
      Frag ah_, al_;
      CVT_A(f, ah_, al_);
      MFMA8D(ah_, al_, zacc, wseg);
    }
    Z_EPI(zacc, biasu);
    PHASE_B(u + 2);
  }

  // epilogue: + b_in, PReLU, store
#pragma unroll
  for (int ct = 0; ct < 8; ++ct) {
    int col = ct * 16 + li;
    float bi = bin[col];
    float p = pa[col];
#pragma unroll
    for (int r = 0; r < 4; ++r) {
      int node = node0 + w * 16 + lg * 4 + r;
      if (node < NN) {
        float v = hacc[ct][r] + bi;
        v = v >= 0.f ? v : p * v;
        h0[(size_t)node * HD + col] = v;
      }
    }
  }

#undef CVT_A
#undef MFMA8D
#undef TILE
#undef MFMA_BD
#undef Z_EPI
#undef PHASE_B
}

// ---------------- layer GEMM: hin @ [root|rel0|rel1] (barrier-free, no LDS) -----
// 64 rows/block, 4 waves: wave = 64 rows x 96 cols (of 384). B fragments direct
// from fragment-major Wt region (nct=24); A rows from global (L2-hot).
__global__ __launch_bounds__(256, 2) void k_rgemm(
    const float* __restrict__ hin, const unsigned short* __restrict__ wl,
    const float* __restrict__ bias, float* __restrict__ base_,
    float* __restrict__ mh) {
  const int t = threadIdx.x;
  const int node0 = blockIdx.x * 64;
  const int w = t >> 6, lane = t & 63;
  const int li = lane & 15, lg = lane >> 4;
  const int flo = li * 32 + lg * 8;

  const float* ab[4];
#pragma unroll
  for (int sub = 0; sub < 4; ++sub) {
    int node = node0 + sub * 16 + li;
    int nd = node < NN ? node : NN - 1;
    ab[sub] = hin + (size_t)nd * HD + lg * 8;
  }

  f32x4 acc[4][6];
#pragma unroll
  for (int a = 0; a < 4; ++a)
#pragma unroll
    for (int b = 0; b < 6; ++b) acc[a][b] = (f32x4)0.f;

#pragma unroll
  for (int kt = 0; kt < 4; ++kt) {
    Frag ah[4], al[4];
#pragma unroll
    for (int sub = 0; sub < 4; ++sub) {
      float f[8];
#pragma unroll
      for (int j = 0; j < 8; ++j) f[j] = ab[sub][kt * 32 + j];
#pragma unroll
      for (int q = 0; q < 4; ++q)
        cvt_pair(f[2 * q], f[2 * q + 1], ah[sub].u[q], al[sub].u[q]);
    }
    const unsigned short* pb = wl + (kt * 2 * 24) * 512;
#pragma unroll
    for (int ct = 0; ct < 6; ++ct) {
      int ctg = w * 6 + ct;
      Frag bh, bl;
      bh.v = *(const uint4*)(pb + ctg * 512 + flo);
      bl.v = *(const uint4*)(pb + 24 * 512 + ctg * 512 + flo);
#pragma unroll
      for (int sub = 0; sub < 4; ++sub) {
        acc[sub][ct] = __builtin_amdgcn_mfma_f32_16x16x32_bf16(ah[sub].s, bl.s, acc[sub][ct], 0, 0, 0);
        acc[sub][ct] = __builtin_amdgcn_mfma_f32_16x16x32_bf16(al[sub].s, bh.s, acc[sub][ct], 0, 0, 0);
        acc[sub][ct] = __builtin_amdgcn_mfma_f32_16x16x32_bf16(ah[sub].s, bh.s, acc[sub][ct], 0, 0, 0);
      }
    }
  }

  // epilogue
#pragma unroll
  for (int ct = 0; ct < 6; ++ct) {
    int gcol = w * 96 + ct * 16 + li;
    float bv = 0.f;
    float* dp;
    int lc;
    if (gcol < 128) { bv = bias[gcol]; dp = base_; lc = gcol; }
    else if (gcol < 256) { dp = mh; lc = gcol - 128; }
    else { dp = mh + (size_t)NN * HD; lc = gcol - 256; }
#pragma unroll
    for (int sub = 0; sub < 4; ++sub) {
#pragma unroll
      for (int r = 0; r < 4; ++r) {
        int node = node0 + sub * 16 + lg * 4 + r;
        if (node < NN) dp[(size_t)node * HD + lc] = acc[sub][ct][r] + bv;
      }
    }
  }
}

// ---------------- aggregation ----------------
__global__ __launch_bounds__(256) void k_aggregate(
    float* __restrict__ io, const float* __restrict__ mh,
    const int* __restrict__ row_ptr, const int* __restrict__ cnt2,
    const int* __restrict__ entries) {
  int i = blockIdx.x * 4 + (threadIdx.x >> 6);
  int l = threadIdx.x & 63;
  if (i >= NN) return;
  int rs = row_ptr[i], re = row_ptr[i + 1];
  int c0 = cnt2[i], c1 = cnt2[NN + i];
  float inv0 = 1.f / (float)(c0 > 0 ? c0 : 1);
  float inv1 = 1.f / (float)(c1 > 0 ? c1 : 1);
  float a0 = 0, a1 = 0, b0 = 0, b1 = 0;
  int e = rs;
  for (; e + 1 < re; e += 2) {
    int ent0 = entries[e], ent1 = entries[e + 1];
    const float* r0 = mh + (((size_t)(ent0 >> 20)) * NN + (ent0 & 0xFFFFF)) * HD;
    const float* r1 = mh + (((size_t)(ent1 >> 20)) * NN + (ent1 & 0xFFFFF)) * HD;
    float v00 = r0[l], v01 = r0[l + 64];
    float v10 = r1[l], v11 = r1[l + 64];
    if (ent0 >> 20) { b0 += v00; b1 += v01; } else { a0 += v00; a1 += v01; }
    if (ent1 >> 20) { b0 += v10; b1 += v11; } else { a0 += v10; a1 += v11; }
  }
  if (e < re) {
    int ent = entries[e];
    const float* r0 = mh + (((size_t)(ent >> 20)) * NN + (ent & 0xFFFFF)) * HD;
    float v0 = r0[l], v1 = r0[l + 64];
    if (ent >> 20) { b0 += v0; b1 += v1; } else { a0 += v0; a1 += v1; }
  }
  io[(size_t)i * HD + l] += a0 * inv0 + b0 * inv1;
  io[(size_t)i * HD + l + 64] += a1 * inv0 + b1 * inv1;
}

// ---------------- final linear (MFMA, in-place, no LDS) ----------------
// 64 rows/block, 4 waves in 2x2: wave = 32 rows x 64 cols. B fragments direct.
__global__ __launch_bounds__(256, 4) void k_cls2(
    float* __restrict__ io, const unsigned short* __restrict__ Wt,
    const float* __restrict__ b) {
  const int t = threadIdx.x;
  const int node0 = blockIdx.x * 64;
  const int w = t >> 6, lane = t & 63;
  const int li = lane & 15, lg = lane >> 4;
  const int wr = w >> 1, wc = w & 1;
  const int flo = li * 32 + lg * 8;

  int nodeA0 = node0 + wr * 32 + li; int nd0 = nodeA0 < NN ? nodeA0 : NN - 1;
  int nodeA1 = nodeA0 + 16;          int nd1 = nodeA1 < NN ? nodeA1 : NN - 1;
  const float* ap0 = io + (size_t)nd0 * HD + lg * 8;
  const float* ap1 = io + (size_t)nd1 * HD + lg * 8;

  f32x4 acc[2][4];
#pragma unroll
  for (int a = 0; a < 2; ++a)
#pragma unroll
    for (int bq = 0; bq < 4; ++bq) acc[a][bq] = (f32x4)0.f;

#pragma unroll
  for (int kt = 0; kt < 4; ++kt) {
    Frag ah[2], al[2];
    {
      float f0[8], f1[8];
#pragma unroll
      for (int j = 0; j < 8; ++j) { f0[j] = ap0[kt * 32 + j]; f1[j] = ap1[kt * 32 + j]; }
#pragma unroll
      for (int q = 0; q < 4; ++q) {
        cvt_pair(f0[2 * q], f0[2 * q + 1], ah[0].u[q], al[0].u[q]);
        cvt_pair(f1[2 * q], f1[2 * q + 1], ah[1].u[q], al[1].u[q]);
      }
    }
    const unsigned short* pb = Wt + OFF_CLS + (kt * 2 * 8) * 512;
#pragma unroll
    for (int ct = 0; ct < 4; ++ct) {
      int ctg = wc * 4 + ct;
      Frag bh, bl;
      bh.v = *(const uint4*)(pb + ctg * 512 + flo);
      bl.v = *(const uint4*)(pb + 4096 + ctg * 512 + flo);
#pragma unroll
      for (int sub = 0; sub < 2; ++sub) {
        acc[sub][ct] = __builtin_amdgcn_mfma_f32_16x16x32_bf16(ah[sub].s, bl.s, acc[sub][ct], 0, 0, 0);
        acc[sub][ct] = __builtin_amdgcn_mfma_f32_16x16x32_bf16(al[sub].s, bh.s, acc[sub][ct], 0, 0, 0);
        acc[sub][ct] = __builtin_amdgcn_mfma_f32_16x16x32_bf16(ah[sub].s, bh.s, acc[sub][ct], 0, 0, 0);
      }
    }
  }

  __syncthreads();  // all A-reads of this block's rows done before in-place writes
#pragma unroll
  for (int ct = 0; ct < 4; ++ct) {
    int col = wc * 64 + ct * 16 + li;
    float bv = b[col];
#pragma unroll
    for (int sub = 0; sub < 2; ++sub) {
#pragma unroll
      for (int r = 0; r < 4; ++r) {
        int node = node0 + wr * 32 + sub * 16 + lg * 4 + r;
        if (node < NN) io[(size_t)node * HD + col] = acc[sub][ct][r] + bv;
      }
    }
  }
}

extern "C" void kernel_launch(void* const* d_in, const int* in_sizes, int n_in,
                              void* d_out, int out_size, void* d_ws, size_t ws_size,
                              hipStream_t stream) {
  const float* x    = (const float*)d_in[0];
  const int* ei     = (const int*)d_in[1];
  const int* et     = (const int*)d_in[2];
  const float* Wdes = (const float*)d_in[3];
  const float* bdes = (const float*)d_in[4];
  const float* Wtw  = (const float*)d_in[5];
  const float* btw  = (const float*)d_in[6];
  const float* Wnum = (const float*)d_in[7];
  const float* bnum = (const float*)d_in[8];
  const float* Wcat = (const float*)d_in[9];
  const float* bcat = (const float*)d_in[10];
  const float* Win  = (const float*)d_in[11];
  const float* bin  = (const float*)d_in[12];
  const float* pa   = (const float*)d_in[13];
  const float* root1 = (const float*)d_in[14];
  const float* rel1  = (const float*)d_in[15];
  const float* bias1 = (const float*)d_in[16];
  const float* root2 = (const float*)d_in[17];
  const float* rel2  = (const float*)d_in[18];
  const float* bias2 = (const float*)d_in[19];
  const float* Wcls  = (const float*)d_in[20];
  const float* bcls  = (const float*)d_in[21];
  float* out = (float*)d_out;

  char* p = (char*)d_ws;
  float* mh = (float*)p;      p += (size_t)2 * NN * HD * 4;   // 102.4 MB
  float* hB = (float*)p;      p += (size_t)NN * HD * 4;       // 51.2 MB
  int* row_ptr = (int*)p;     p += ((size_t)NN + 4) * 4;
  int* cnt2 = (int*)p;        p += (size_t)2 * NN * 4;
  int* fillpos = (int*)p;     p += (size_t)NN * 4;
  int* entries = (int*)p;     p += (size_t)EE * 4;
  int* bsum = (int*)p;        p += 512;
  unsigned short* Wt = (unsigned short*)p;  p += (size_t)WT_SITES * 2 * 2;

  // weight pre-convert (independent of everything else)
  k_prepw<<<(WT_SITES + 255) / 256, 256, 0, stream>>>(
      Wdes, Wtw, Wnum, Wcat, Win, root1, rel1, root2, rel2, Wcls, Wt);

  // CSR build
  hipMemsetAsync(cnt2, 0, (size_t)3 * NN * 4, stream);  // cnt2 + fillpos
  k_count<<<EE / 256, 256, 0, stream>>>(ei, et, cnt2);
  int nb = (NN + 1023) / 1024;
  k_scan1<<<nb, 256, 0, stream>>>(cnt2, row_ptr, bsum);
  k_scan2<<<1, 128, 0, stream>>>(bsum, nb);
  k_scan3<<<(NN + 1 + 255) / 256, 256, 0, stream>>>(row_ptr, bsum);
  k_fill<<<EE / 256, 256, 0, stream>>>(ei, et, row_ptr, fillpos, entries);

  const int nblk = (NN + 63) / 64;  // 1563
  // h0 -> d_out
  k_proj2<<<nblk, 256, 0, stream>>>(x, bdes, btw, bnum, bcat, bin, pa, Wt, out);
  // layer 1
  k_rgemm<<<nblk, 256, 0, stream>>>(out, Wt + OFF_L1, bias1, hB, mh);
  k_aggregate<<<NN / 4, 256, 0, stream>>>(hB, mh, row_ptr, cnt2, entries);
  // layer 2
  k_rgemm<<<nblk, 256, 0, stream>>>(hB, Wt + OFF_L2, bias2, out, mh);
  k_aggregate<<<NN / 4, 256, 0, stream>>>(out, mh, row_ptr, cnt2, entries);
  // classifier (MFMA, in-place)
  k_cls2<<<nblk, 256, 0, stream>>>(out, Wt, bcls);
}

// Round 6
// 1083.603 us; speedup vs baseline: 1.2260x; 1.2260x over previous
//
#include <hip/hip_runtime.h>
#include <cstdint>
#include <cstddef>

#define NN 100000
#define EE 1600000
#define XDIM 1553
#define HD 128

typedef __attribute__((ext_vector_type(8))) short short8;
typedef __attribute__((ext_vector_type(4))) float f32x4;

union Frag { unsigned int u[4]; short8 s; uint4 v; };

// weight area offsets (ushort units); hi/lo are separate regions
#define OFF_DES_HI 0
#define OFF_DES_LO 98304
#define OFF_TW_HI  196608
#define OFF_TW_LO  294912
#define OFF_NUM_HI 393216
#define OFF_NUM_LO 397312
#define OFF_CAT_HI 401408
#define OFF_CAT_LO 405504
#define OFF_WIN_HI 409600
#define OFF_WIN_LO 475136
#define OFF_L1_HI  540672
#define OFF_L1_LO  589824
#define OFF_L2_HI  638976
#define OFF_L2_LO  688128
#define OFF_CLS_HI 737280
#define OFF_CLS_LO 753664
#define WT_SITES   385024   // (col,k) sites; each writes hi+lo

// hi = trunc-bf16(f), lo = trunc-bf16(f - hi). Packed: 2 elems -> 1 u32 via v_perm.
__device__ __forceinline__ void cvt_pair(float f0, float f1,
                                         unsigned int& hi, unsigned int& lo) {
  unsigned int u0 = __float_as_uint(f0), u1 = __float_as_uint(f1);
  hi = __builtin_amdgcn_perm(u1, u0, 0x07060302u);
  float l0 = f0 - __uint_as_float(u0 & 0xFFFF0000u);
  float l1 = f1 - __uint_as_float(u1 & 0xFFFF0000u);
  lo = __builtin_amdgcn_perm(__float_as_uint(l1), __float_as_uint(l0), 0x07060302u);
}

// raw barriers: no vmcnt drain (prefetched global loads ride across);
// lgkm0 variant publishes ds_writes before the barrier.
__device__ __forceinline__ void fence_barrier() {
  asm volatile("" ::: "memory");
  __builtin_amdgcn_s_barrier();
  asm volatile("" ::: "memory");
}
__device__ __forceinline__ void lgkm0_barrier() {
  asm volatile("s_waitcnt lgkmcnt(0)" ::: "memory");
  __builtin_amdgcn_s_barrier();
  asm volatile("" ::: "memory");
}

// ---------------- weight pre-convert/transpose (runs once, tiny) ----------------
__global__ __launch_bounds__(256) void k_prepw(
    const float* __restrict__ Wdes, const float* __restrict__ Wtw,
    const float* __restrict__ Wnum, const float* __restrict__ Wcat,
    const float* __restrict__ Win,  const float* __restrict__ root1,
    const float* __restrict__ rel1, const float* __restrict__ root2,
    const float* __restrict__ rel2, const float* __restrict__ Wcls,
    unsigned short* __restrict__ Wt) {
  int id = blockIdx.x * 256 + threadIdx.x;
  if (id >= WT_SITES) return;
  const float* src; int K, Kpad, dhi, dlo, local;
  if (id < 98304)       { src=Wdes;        K=768; Kpad=768; dhi=OFF_DES_HI;       dlo=OFF_DES_LO;       local=id; }
  else if (id < 196608) { src=Wtw;         K=768; Kpad=768; dhi=OFF_TW_HI;        dlo=OFF_TW_LO;        local=id-98304; }
  else if (id < 200704) { src=Wnum;        K=6;   Kpad=32;  dhi=OFF_NUM_HI;       dlo=OFF_NUM_LO;       local=id-196608; }
  else if (id < 204800) { src=Wcat;        K=11;  Kpad=32;  dhi=OFF_CAT_HI;       dlo=OFF_CAT_LO;       local=id-200704; }
  else if (id < 270336) { src=Win;         K=512; Kpad=512; dhi=OFF_WIN_HI;       dlo=OFF_WIN_LO;       local=id-204800; }
  else if (id < 286720) { src=root1;       K=128; Kpad=128; dhi=OFF_L1_HI;        dlo=OFF_L1_LO;        local=id-270336; }
  else if (id < 303104) { src=rel1;        K=128; Kpad=128; dhi=OFF_L1_HI+16384;  dlo=OFF_L1_LO+16384;  local=id-286720; }
  else if (id < 319488) { src=rel1+16384;  K=128; Kpad=128; dhi=OFF_L1_HI+32768;  dlo=OFF_L1_LO+32768;  local=id-303104; }
  else if (id < 335872) { src=root2;       K=128; Kpad=128; dhi=OFF_L2_HI;        dlo=OFF_L2_LO;        local=id-319488; }
  else if (id < 352256) { src=rel2;        K=128; Kpad=128; dhi=OFF_L2_HI+16384;  dlo=OFF_L2_LO+16384;  local=id-335872; }
  else if (id < 368640) { src=rel2+16384;  K=128; Kpad=128; dhi=OFF_L2_HI+32768;  dlo=OFF_L2_LO+32768;  local=id-352256; }
  else                  { src=Wcls;        K=128; Kpad=128; dhi=OFF_CLS_HI;       dlo=OFF_CLS_LO;       local=id-368640; }
  int col = local / Kpad;
  int k = local - col * Kpad;
  float v = (k < K) ? src[(size_t)k * 128 + col] : 0.f;
  unsigned int u = __float_as_uint(v);
  float lo = v - __uint_as_float(u & 0xFFFF0000u);
  Wt[dhi + col * Kpad + k] = (unsigned short)(u >> 16);
  Wt[dlo + col * Kpad + k] = (unsigned short)(__float_as_uint(lo) >> 16);
}

// ---------------- CSR build ----------------
__global__ __launch_bounds__(256) void k_count(const int* __restrict__ ei,
                                               const int* __restrict__ et,
                                               int* __restrict__ cnt2) {
  int e = blockIdx.x * 256 + threadIdx.x;
  if (e >= EE) return;
  atomicAdd(&cnt2[et[e] * NN + ei[EE + e]], 1);
}

__global__ __launch_bounds__(256) void k_scan1(const int* __restrict__ cnt2,
                                               int* __restrict__ row_ptr,
                                               int* __restrict__ bsum) {
  __shared__ int sums[256];
  int t = threadIdx.x;
  int base = blockIdx.x * 1024 + t * 4;
  int v[4]; int s = 0;
#pragma unroll
  for (int j = 0; j < 4; ++j) {
    int idx = base + j;
    v[j] = (idx < NN) ? (cnt2[idx] + cnt2[NN + idx]) : 0;
    s += v[j];
  }
  sums[t] = s;
  __syncthreads();
  for (int d = 1; d < 256; d <<= 1) {
    int val = (t >= d) ? sums[t - d] : 0;
    __syncthreads();
    sums[t] += val;
    __syncthreads();
  }
  int excl = sums[t] - s;
  if (t == 255) bsum[blockIdx.x] = sums[t];
  int run = excl;
#pragma unroll
  for (int j = 0; j < 4; ++j) {
    int idx = base + j;
    if (idx < NN) row_ptr[idx] = run;
    run += v[j];
  }
}

__global__ __launch_bounds__(128) void k_scan2(int* __restrict__ bsum, int nb) {
  __shared__ int s[128];
  int t = threadIdx.x;
  int v = (t < nb) ? bsum[t] : 0;
  s[t] = v;
  __syncthreads();
  for (int d = 1; d < 128; d <<= 1) {
    int val = (t >= d) ? s[t - d] : 0;
    __syncthreads();
    s[t] += val;
    __syncthreads();
  }
  if (t < nb) bsum[t] = s[t] - v;
}

__global__ __launch_bounds__(256) void k_scan3(int* __restrict__ row_ptr,
                                               const int* __restrict__ bsum) {
  int idx = blockIdx.x * 256 + threadIdx.x;
  if (idx < NN) row_ptr[idx] += bsum[idx >> 10];
  if (idx == NN) row_ptr[NN] = EE;
}

__global__ __launch_bounds__(256) void k_fill(const int* __restrict__ ei,
                                              const int* __restrict__ et,
                                              const int* __restrict__ row_ptr,
                                              int* __restrict__ fillpos,
                                              int* __restrict__ entries) {
  int e = blockIdx.x * 256 + threadIdx.x;
  if (e >= EE) return;
  int src = ei[e];
  int dst = ei[EE + e];
  int r = et[e];
  int pos = atomicAdd(&fillpos[dst], 1);
  entries[row_ptr[dst] + pos] = src | (r << 20);
}

// ---------------- fused projection (MFMA, split-bf16, pipelined, raw barriers) ----
// 128 nodes/block, 8 waves x (16 rows x 128 cols), 512 threads, 2 blocks/CU
// (16 waves/CU = 4/SIMD). B-tile LDS writes + W global loads amortize over 8
// waves; each wave keeps the no-spill 16-row shape (R3: 84 VGPR). X register
// pipeline depth-3; raw barriers (no vmcnt drain) let prefetches ride across.
__global__ __launch_bounds__(512, 4) void k_proj2(
    const float* __restrict__ x,
    const float* __restrict__ bdes, const float* __restrict__ btw,
    const float* __restrict__ bnum, const float* __restrict__ bcat,
    const float* __restrict__ bin,  const float* __restrict__ pa,
    const unsigned short* __restrict__ Wt, float* __restrict__ h0) {
  __shared__ unsigned short bt_hi[128 * 32], bt_lo[128 * 32];   // 8KB + 8KB
  __shared__ unsigned short z_hi[128 * 128], z_lo[128 * 128];   // 32KB + 32KB

  const int t = threadIdx.x;            // 0..511
  const int node0 = blockIdx.x * 128;
  const int w = t >> 6, lane = t & 63;  // w 0..7
  const int li = lane & 15, lg = lane >> 4;

  // B-staging: each of 512 threads owns exactly one (colrow, c-chunk) site
  const int cr0 = t >> 2, c0 = t & 3;   // cr0 0..127
  const unsigned stb0 = cr0 * 64 + ((c0 ^ ((cr0 >> 1) & 3)) << 4);

  // one A-row per (wave, li)
  const int rowA = w * 16 + li;         // 0..127
  int nodeA = node0 + rowA;
  int ndA = nodeA < NN ? nodeA : NN - 1;
  const float* xrow = x + (size_t)ndA * XDIM;

#define STORE_BT(SH0, SL0)                        \
  do {                                            \
    *(uint4*)((char*)bt_hi + stb0) = (SH0);       \
    *(uint4*)((char*)bt_lo + stb0) = (SL0);       \
  } while (0)

#define CVT_A(F, AH, AL)                                                         \
  do {                                                                           \
    _Pragma("unroll")                                                            \
    for (int q_ = 0; q_ < 4; ++q_)                                               \
      cvt_pair((F)[2 * q_], (F)[2 * q_ + 1], (AH).u[q_], (AL).u[q_]);            \
  } while (0)

#define MFMA8(AH, AL, ACC)                                                       \
  do {                                                                           \
    _Pragma("unroll")                                                            \
    for (int ct_ = 0; ct_ < 8; ++ct_) {                                          \
      int colrow_ = ct_ * 16 + li;                                               \
      int byte_ = colrow_ * 64 + (lg << 4);                                      \
      byte_ ^= ((colrow_ >> 1) & 3) << 4;                                        \
      Frag bh_, bl_;                                                             \
      bh_.v = *(const uint4*)((char*)bt_hi + byte_);                             \
      bl_.v = *(const uint4*)((char*)bt_lo + byte_);                             \
      (ACC)[ct_] = __builtin_amdgcn_mfma_f32_16x16x32_bf16((AH).s, bl_.s, (ACC)[ct_], 0, 0, 0); \
      (ACC)[ct_] = __builtin_amdgcn_mfma_f32_16x16x32_bf16((AL).s, bh_.s, (ACC)[ct_], 0, 0, 0); \
      (ACC)[ct_] = __builtin_amdgcn_mfma_f32_16x16x32_bf16((AH).s, bh_.s, (ACC)[ct_], 0, 0, 0); \
    }                                                                            \
  } while (0)

// one K-tile of phase A: store W tile (cur), barrier, convert X, prefetch
// W(T+1, into next buf) + X(T+3, back into same X buf), MFMA, barrier.
#define TILE(WC0, WC1, WN0, WN1, XB, T)                                          \
  do {                                                                           \
    STORE_BT(WC0, WC1);                                                          \
    lgkm0_barrier();                                                             \
    Frag ah_, al_;                                                               \
    CVT_A(XB, ah_, al_);                                                         \
    {                                                                            \
      const int kw_ = ((T) + 1) * 32;                                            \
      WN0 = *(const uint4*)(ph0 + kw_); WN1 = *(const uint4*)(pl0 + kw_);        \
      int kx_ = (T) + 3; if (kx_ > 23) kx_ = 23; kx_ *= 32;                      \
      _Pragma("unroll")                                                          \
      for (int j_ = 0; j_ < 8; ++j_) XB[j_] = xr[kx_ + j_];                      \
    }                                                                            \
    MFMA8(ah_, al_, zacc);                                                       \
    fence_barrier();                                                             \
  } while (0)

#define MFMA_B(KT)                                                               \
  do {                                                                           \
    Frag ah_, al_;                                                               \
    int byte_ = rowA * 256 + (((KT) * 32 + lg * 8) << 1);                        \
    byte_ ^= (rowA & 7) << 4;                                                    \
    ah_.v = *(const uint4*)((char*)z_hi + byte_);                                \
    al_.v = *(const uint4*)((char*)z_lo + byte_);                                \
    MFMA8(ah_, al_, hacc);                                                       \
  } while (0)

#define Z_EPI(ZACC, BIASP)                                                       \
  do {                                                                           \
    _Pragma("unroll")                                                            \
    for (int ct_ = 0; ct_ < 8; ++ct_) {                                          \
      int col_ = ct_ * 16 + li;                                                  \
      float bv_ = (BIASP)[col_];                                                 \
      _Pragma("unroll")                                                          \
      for (int r_ = 0; r_ < 4; ++r_) {                                           \
        float v_ = (ZACC)[ct_][r_] + bv_;                                        \
        v_ = v_ >= 0.f ? v_ : 0.01f * v_;                                        \
        int row_ = w * 16 + lg * 4 + r_;                                         \
        int byte_ = row_ * 256 + col_ * 2;                                       \
        byte_ ^= (row_ & 7) << 4;                                                \
        unsigned int u_ = __float_as_uint(v_);                                   \
        *(unsigned short*)((char*)z_hi + byte_) = (unsigned short)(u_ >> 16);    \
        float lo_ = v_ - __uint_as_float(u_ & 0xFFFF0000u);                      \
        *(unsigned short*)((char*)z_lo + byte_) = (unsigned short)(__float_as_uint(lo_) >> 16); \
      }                                                                          \
    }                                                                            \
  } while (0)

// phase B: hacc += z @ Win[SLICE*128 .. +127], 4 K-tiles, fully unrolled,
// 1-deep prefetch of the next Win tile.
#define PHASE_B(SLICE)                                                           \
  do {                                                                           \
    const unsigned short* qh0_ = Wt + OFF_WIN_HI + cr0 * 512 + (SLICE) * 128 + c0 * 8; \
    const unsigned short* ql0_ = Wt + OFF_WIN_LO + cr0 * 512 + (SLICE) * 128 + c0 * 8; \
    uint4 wA0_ = *(const uint4*)(qh0_), wA1_ = *(const uint4*)(ql0_);            \
    uint4 wB0_, wB1_;                                                            \
    STORE_BT(wA0_, wA1_);                                                        \
    lgkm0_barrier();                                                             \
    wB0_ = *(const uint4*)(qh0_ + 32); wB1_ = *(const uint4*)(ql0_ + 32);        \
    MFMA_B(0);                                                                   \
    fence_barrier();                                                             \
    STORE_BT(wB0_, wB1_);                                                        \
    lgkm0_barrier();                                                             \
    wA0_ = *(const uint4*)(qh0_ + 64); wA1_ = *(const uint4*)(ql0_ + 64);        \
    MFMA_B(1);                                                                   \
    fence_barrier();                                                             \
    STORE_BT(wA0_, wA1_);                                                        \
    lgkm0_barrier();                                                             \
    wB0_ = *(const uint4*)(qh0_ + 96); wB1_ = *(const uint4*)(ql0_ + 96);        \
    MFMA_B(2);                                                                   \
    fence_barrier();                                                             \
    STORE_BT(wB0_, wB1_);                                                        \
    lgkm0_barrier();                                                             \
    MFMA_B(3);                                                                   \
    fence_barrier();                                                             \
  } while (0)

  f32x4 hacc[8];
#pragma unroll
  for (int b = 0; b < 8; ++b) hacc[b] = (f32x4)0.f;

  // ---- big segments: des (s=0), tweet (s=1); K=768 = 24 K-tiles, pipelined ----
#pragma unroll
  for (int s = 0; s < 2; ++s) {
    const int off = (s == 0) ? 785 : 6;
    const unsigned short* wh = Wt + (s == 0 ? OFF_DES_HI : OFF_TW_HI);
    const unsigned short* wl = Wt + (s == 0 ? OFF_DES_LO : OFF_TW_LO);
    const float* bias = (s == 0) ? bdes : btw;

    const float* xr = xrow + off + lg * 8;
    const unsigned short* ph0 = wh + cr0 * 768 + c0 * 8;
    const unsigned short* pl0 = wl + cr0 * 768 + c0 * 8;

    f32x4 zacc[8];
#pragma unroll
    for (int b = 0; b < 8; ++b) zacc[b] = (f32x4)0.f;

    uint4 WA0, WA1, WB0, WB1;
    float X0[8], X1[8], X2[8];

    // prologue: W tile 0, X tiles 0..2
    WA0 = *(const uint4*)(ph0); WA1 = *(const uint4*)(pl0);
#pragma unroll
    for (int j = 0; j < 8; ++j) X0[j] = xr[j];
#pragma unroll
    for (int j = 0; j < 8; ++j) X1[j] = xr[32 + j];
#pragma unroll
    for (int j = 0; j < 8; ++j) X2[j] = xr[64 + j];

    for (int base = 0; base < 24; base += 6) {
      TILE(WA0, WA1, WB0, WB1, X0, base + 0);
      TILE(WB0, WB1, WA0, WA1, X1, base + 1);
      TILE(WA0, WA1, WB0, WB1, X2, base + 2);
      TILE(WB0, WB1, WA0, WA1, X0, base + 3);
      TILE(WA0, WA1, WB0, WB1, X1, base + 4);
      TILE(WB0, WB1, WA0, WA1, X2, base + 5);
    }
    Z_EPI(zacc, bias);   // z slots are wave-private
    PHASE_B(s);
  }

  // ---- small segments: num (K=6), cat (K=11); single padded K-tile each ----
#pragma unroll
  for (int u = 0; u < 2; ++u) {
    const int offu = (u == 0) ? 0 : 774;
    const int Ksu = (u == 0) ? 6 : 11;
    const unsigned short* wh = Wt + (u == 0 ? OFF_NUM_HI : OFF_CAT_HI);
    const unsigned short* wl = Wt + (u == 0 ? OFF_NUM_LO : OFF_CAT_LO);
    const float* biasu = (u == 0) ? bnum : bcat;
    const float* xr = xrow + offu + lg * 8;

    uint4 s0 = *(const uint4*)(wh + cr0 * 32 + c0 * 8);
    uint4 s1 = *(const uint4*)(wl + cr0 * 32 + c0 * 8);
    float f[8];
#pragma unroll
    for (int j = 0; j < 8; ++j) f[j] = (lg * 8 + j < Ksu) ? xr[j] : 0.f;

    f32x4 zacc[8];
#pragma unroll
    for (int b = 0; b < 8; ++b) zacc[b] = (f32x4)0.f;

    STORE_BT(s0, s1);
    lgkm0_barrier();
    {
      Frag ah_, al_;
      CVT_A(f, ah_, al_);
      MFMA8(ah_, al_, zacc);
    }
    fence_barrier();
    Z_EPI(zacc, biasu);
    PHASE_B(u + 2);
  }

  // epilogue: + b_in, PReLU, store
#pragma unroll
  for (int ct = 0; ct < 8; ++ct) {
    int col = ct * 16 + li;
    float bi = bin[col];
    float p = pa[col];
#pragma unroll
    for (int r = 0; r < 4; ++r) {
      int node = node0 + w * 16 + lg * 4 + r;
      if (node < NN) {
        float v = hacc[ct][r] + bi;
        v = v >= 0.f ? v : p * v;
        h0[(size_t)node * HD + col] = v;
      }
    }
  }

#undef STORE_BT
#undef CVT_A
#undef MFMA8
#undef TILE
#undef MFMA_B
#undef Z_EPI
#undef PHASE_B
}

// ---------------- layer GEMM: hin @ [root|rel0|rel1] (MFMA split-bf16) ----------------
// 64 rows/block, 4 waves: wave = 64 rows x 96 cols (of 384).
// Raw barriers + 1-deep ping-pong prefetch of the A (hin) row fragments.
__global__ __launch_bounds__(256, 2) void k_rgemm(
    const float* __restrict__ hin, const unsigned short* __restrict__ wl_hi,
    const unsigned short* __restrict__ wl_lo, const float* __restrict__ bias,
    float* __restrict__ base, float* __restrict__ mh) {
  __shared__ unsigned short bt_hi[384 * 32], bt_lo[384 * 32];  // 24KB + 24KB

  const int t = threadIdx.x;
  const int node0 = blockIdx.x * 64;
  const int w = t >> 6, lane = t & 63;
  const int li = lane & 15, lg = lane >> 4;

  const float* ab[4];
#pragma unroll
  for (int sub = 0; sub < 4; ++sub) {
    int node = node0 + sub * 16 + li;
    int nd = node < NN ? node : NN - 1;
    ab[sub] = hin + (size_t)nd * HD + lg * 8;
  }

  f32x4 acc[4][6];
#pragma unroll
  for (int a = 0; a < 4; ++a)
#pragma unroll
    for (int b = 0; b < 6; ++b) acc[a][b] = (f32x4)0.f;

// stage B tile [384][32] hi/lo in two halves (keeps reg peak low)
#define RG_STAGE(KT)                                                             \
  do {                                                                           \
    _Pragma("unroll")                                                            \
    for (int h_ = 0; h_ < 2; ++h_) {                                             \
      uint4 sh_[3], sl_[3];                                                      \
      _Pragma("unroll")                                                          \
      for (int j_ = 0; j_ < 3; ++j_) {                                           \
        int cid_ = t + (h_ * 3 + j_) * 256;                                      \
        int cr_ = cid_ >> 2, c_ = cid_ & 3;                                      \
        sh_[j_] = *(const uint4*)(wl_hi + cr_ * 128 + (KT) * 32 + c_ * 8);       \
        sl_[j_] = *(const uint4*)(wl_lo + cr_ * 128 + (KT) * 32 + c_ * 8);       \
      }                                                                          \
      _Pragma("unroll")                                                          \
      for (int j_ = 0; j_ < 3; ++j_) {                                           \
        int cid_ = t + (h_ * 3 + j_) * 256;                                      \
        int cr_ = cid_ >> 2, c_ = cid_ & 3;                                      \
        unsigned b_ = cr_ * 64 + ((c_ ^ ((cr_ >> 1) & 3)) << 4);                 \
        *(uint4*)((char*)bt_hi + b_) = sh_[j_];                                  \
        *(uint4*)((char*)bt_lo + b_) = sl_[j_];                                  \
      }                                                                          \
    }                                                                            \
  } while (0)

#define RG_LOADA(KT, F)                                                          \
  do {                                                                           \
    _Pragma("unroll")                                                            \
    for (int sub_ = 0; sub_ < 4; ++sub_) {                                       \
      _Pragma("unroll")                                                          \
      for (int j_ = 0; j_ < 8; ++j_) (F)[sub_][j_] = ab[sub_][(KT) * 32 + j_];   \
    }                                                                            \
  } while (0)

#define RG_MFMA(F)                                                               \
  do {                                                                           \
    Frag ah_[4], al_[4];                                                         \
    _Pragma("unroll")                                                            \
    for (int sub_ = 0; sub_ < 4; ++sub_)                                         \
      _Pragma("unroll")                                                          \
      for (int q_ = 0; q_ < 4; ++q_)                                             \
        cvt_pair((F)[sub_][2 * q_], (F)[sub_][2 * q_ + 1], ah_[sub_].u[q_], al_[sub_].u[q_]); \
    _Pragma("unroll")                                                            \
    for (int ct_ = 0; ct_ < 6; ++ct_) {                                          \
      int colrow_ = w * 96 + ct_ * 16 + li;                                      \
      int byte_ = colrow_ * 64 + (lg << 4);                                      \
      byte_ ^= ((colrow_ >> 1) & 3) << 4;                                        \
      Frag bh_, bl_;                                                             \
      bh_.v = *(const uint4*)((char*)bt_hi + byte_);                             \
      bl_.v = *(const uint4*)((char*)bt_lo + byte_);                             \
      _Pragma("unroll")                                                          \
      for (int sub_ = 0; sub_ < 4; ++sub_) {                                     \
        acc[sub_][ct_] = __builtin_amdgcn_mfma_f32_16x16x32_bf16(ah_[sub_].s, bl_.s, acc[sub_][ct_], 0, 0, 0); \
        acc[sub_][ct_] = __builtin_amdgcn_mfma_f32_16x16x32_bf16(al_[sub_].s, bh_.s, acc[sub_][ct_], 0, 0, 0); \
        acc[sub_][ct_] = __builtin_amdgcn_mfma_f32_16x16x32_bf16(ah_[sub_].s, bh_.s, acc[sub_][ct_], 0, 0, 0); \
      }                                                                          \
    }                                                                            \
  } while (0)

  float fA[4][8], fB[4][8];
  RG_LOADA(0, fA);

  RG_STAGE(0);
  RG_LOADA(1, fB);
  lgkm0_barrier();
  RG_MFMA(fA);
  fence_barrier();

  RG_STAGE(1);
  RG_LOADA(2, fA);
  lgkm0_barrier();
  RG_MFMA(fB);
  fence_barrier();

  RG_STAGE(2);
  RG_LOADA(3, fB);
  lgkm0_barrier();
  RG_MFMA(fA);
  fence_barrier();

  RG_STAGE(3);
  lgkm0_barrier();
  RG_MFMA(fB);

#undef RG_STAGE
#undef RG_LOADA
#undef RG_MFMA

  // epilogue
#pragma unroll
  for (int ct = 0; ct < 6; ++ct) {
    int gcol = w * 96 + ct * 16 + li;
    float bv = 0.f;
    float* dp;
    int lc;
    if (gcol < 128) { bv = bias[gcol]; dp = base; lc = gcol; }
    else if (gcol < 256) { dp = mh; lc = gcol - 128; }
    else { dp = mh + (size_t)NN * HD; lc = gcol - 256; }
#pragma unroll
    for (int sub = 0; sub < 4; ++sub) {
#pragma unroll
      for (int r = 0; r < 4; ++r) {
        int node = node0 + sub * 16 + lg * 4 + r;
        if (node < NN) dp[(size_t)node * HD + lc] = acc[sub][ct][r] + bv;
      }
    }
  }
}

// ---------------- aggregation (float2-vectorized) ----------------
// lane l handles cols {2l, 2l+1}: one 8B load per gathered row, halved VMEM
// instruction count; per-column accumulation order unchanged (same edge order).
__global__ __launch_bounds__(256) void k_aggregate(
    float* __restrict__ io, const float* __restrict__ mh,
    const int* __restrict__ row_ptr, const int* __restrict__ cnt2,
    const int* __restrict__ entries) {
  int i = blockIdx.x * 4 + (threadIdx.x >> 6);
  int l = threadIdx.x & 63;
  if (i >= NN) return;
  int rs = row_ptr[i], re = row_ptr[i + 1];
  int c0 = cnt2[i], c1 = cnt2[NN + i];
  float inv0 = 1.f / (float)(c0 > 0 ? c0 : 1);
  float inv1 = 1.f / (float)(c1 > 0 ? c1 : 1);
  float a0 = 0, a1 = 0, b0 = 0, b1 = 0;
  int e = rs;
  for (; e + 1 < re; e += 2) {
    int ent0 = entries[e], ent1 = entries[e + 1];
    const float2* r0 = (const float2*)(mh + (((size_t)(ent0 >> 20)) * NN + (ent0 & 0xFFFFF)) * HD);
    const float2* r1 = (const float2*)(mh + (((size_t)(ent1 >> 20)) * NN + (ent1 & 0xFFFFF)) * HD);
    float2 v0 = r0[l], v1 = r1[l];
    if (ent0 >> 20) { b0 += v0.x; b1 += v0.y; } else { a0 += v0.x; a1 += v0.y; }
    if (ent1 >> 20) { b0 += v1.x; b1 += v1.y; } else { a0 += v1.x; a1 += v1.y; }
  }
  if (e < re) {
    int ent = entries[e];
    const float2* r0 = (const float2*)(mh + (((size_t)(ent >> 20)) * NN + (ent & 0xFFFFF)) * HD);
    float2 v0 = r0[l];
    if (ent >> 20) { b0 += v0.x; b1 += v0.y; } else { a0 += v0.x; a1 += v0.y; }
  }
  float2* iop = (float2*)(io + (size_t)i * HD);
  float2 cur = iop[l];
  cur.x += a0 * inv0 + b0 * inv1;
  cur.y += a1 * inv0 + b1 * inv1;
  iop[l] = cur;
}

// ---------------- final linear (MFMA, in-place) ----------------
// 64 rows/block, 4 waves in 2x2: wave = 32 rows x 64 cols.
// Raw barriers + 1-deep ping-pong prefetch of the A (io) row fragments.
__global__ __launch_bounds__(256, 4) void k_cls2(
    float* __restrict__ io, const unsigned short* __restrict__ Wt,
    const float* __restrict__ b) {
  __shared__ unsigned short bt_hi[128 * 32], bt_lo[128 * 32];  // 8KB + 8KB

  const int t = threadIdx.x;
  const int node0 = blockIdx.x * 64;
  const int w = t >> 6, lane = t & 63;
  const int li = lane & 15, lg = lane >> 4;
  const int wr = w >> 1, wc = w & 1;

  int nodeA0 = node0 + wr * 32 + li; int nd0 = nodeA0 < NN ? nodeA0 : NN - 1;
  int nodeA1 = nodeA0 + 16;          int nd1 = nodeA1 < NN ? nodeA1 : NN - 1;
  const float* ap0 = io + (size_t)nd0 * HD + lg * 8;
  const float* ap1 = io + (size_t)nd1 * HD + lg * 8;

  f32x4 acc[2][4];
#pragma unroll
  for (int a = 0; a < 2; ++a)
#pragma unroll
    for (int bq = 0; bq < 4; ++bq) acc[a][bq] = (f32x4)0.f;

#define CL_STAGE(KT)                                                             \
  do {                                                                           \
    uint4 sh_[2], sl_[2];                                                        \
    _Pragma("unroll")                                                            \
    for (int j_ = 0; j_ < 2; ++j_) {                                             \
      int cid_ = t + j_ * 256;                                                   \
      int cr_ = cid_ >> 2, c_ = cid_ & 3;                                        \
      sh_[j_] = *(const uint4*)(Wt + OFF_CLS_HI + cr_ * 128 + (KT) * 32 + c_ * 8); \
      sl_[j_] = *(const uint4*)(Wt + OFF_CLS_LO + cr_ * 128 + (KT) * 32 + c_ * 8); \
    }                                                                            \
    _Pragma("unroll")                                                            \
    for (int j_ = 0; j_ < 2; ++j_) {                                             \
      int cid_ = t + j_ * 256;                                                   \
      int cr_ = cid_ >> 2, c_ = cid_ & 3;                                        \
      unsigned b_ = cr_ * 64 + ((c_ ^ ((cr_ >> 1) & 3)) << 4);                   \
      *(uint4*)((char*)bt_hi + b_) = sh_[j_];                                    \
      *(uint4*)((char*)bt_lo + b_) = sl_[j_];                                    \
    }                                                                            \
  } while (0)

#define CL_LOADA(KT, F)                                                          \
  do {                                                                           \
    _Pragma("unroll")                                                            \
    for (int j_ = 0; j_ < 8; ++j_) {                                             \
      (F)[0][j_] = ap0[(KT) * 32 + j_];                                          \
      (F)[1][j_] = ap1[(KT) * 32 + j_];                                          \
    }                                                                            \
  } while (0)

#define CL_MFMA(F)                                                               \
  do {                                                                           \
    Frag ah_[2], al_[2];                                                         \
    _Pragma("unroll")                                                            \
    for (int sub_ = 0; sub_ < 2; ++sub_)                                         \
      _Pragma("unroll")                                                          \
      for (int q_ = 0; q_ < 4; ++q_)                                             \
        cvt_pair((F)[sub_][2 * q_], (F)[sub_][2 * q_ + 1], ah_[sub_].u[q_], al_[sub_].u[q_]); \
    _Pragma("unroll")                                                            \
    for (int ct_ = 0; ct_ < 4; ++ct_) {                                          \
      int colrow_ = wc * 64 + ct_ * 16 + li;                                     \
      int byte_ = colrow_ * 64 + (lg << 4);                                      \
      byte_ ^= ((colrow_ >> 1) & 3) << 4;                                        \
      Frag bh_, bl_;                                                             \
      bh_.v = *(const uint4*)((char*)bt_hi + byte_);                             \
      bl_.v = *(const uint4*)((char*)bt_lo + byte_);                             \
      _Pragma("unroll")                                                          \
      for (int sub_ = 0; sub_ < 2; ++sub_) {                                     \
        acc[sub_][ct_] = __builtin_amdgcn_mfma_f32_16x16x32_bf16(ah_[sub_].s, bl_.s, acc[sub_][ct_], 0, 0, 0); \
        acc[sub_][ct_] = __builtin_amdgcn_mfma_f32_16x16x32_bf16(al_[sub_].s, bh_.s, acc[sub_][ct_], 0, 0, 0); \
        acc[sub_][ct_] = __builtin_amdgcn_mfma_f32_16x16x32_bf16(ah_[sub_].s, bh_.s, acc[sub_][ct_], 0, 0, 0); \
      }                                                                          \
    }                                                                            \
  } while (0)

  float fA[2][8], fB[2][8];
  CL_LOADA(0, fA);

  CL_STAGE(0);
  CL_LOADA(1, fB);
  lgkm0_barrier();
  CL_MFMA(fA);
  fence_barrier();

  CL_STAGE(1);
  CL_LOADA(2, fA);
  lgkm0_barrier();
  CL_MFMA(fB);
  fence_barrier();

  CL_STAGE(2);
  CL_LOADA(3, fB);
  lgkm0_barrier();
  CL_MFMA(fA);
  fence_barrier();

  CL_STAGE(3);
  lgkm0_barrier();
  CL_MFMA(fB);

#undef CL_STAGE
#undef CL_LOADA
#undef CL_MFMA

  __syncthreads();  // all A-reads of this block's rows done before in-place writes
#pragma unroll
  for (int ct = 0; ct < 4; ++ct) {
    int col = wc * 64 + ct * 16 + li;
    float bv = b[col];
#pragma unroll
    for (int sub = 0; sub < 2; ++sub) {
#pragma unroll
      for (int r = 0; r < 4; ++r) {
        int node = node0 + wr * 32 + sub * 16 + lg * 4 + r;
        if (node < NN) io[(size_t)node * HD + col] = acc[sub][ct][r] + bv;
      }
    }
  }
}

extern "C" void kernel_launch(void* const* d_in, const int* in_sizes, int n_in,
                              void* d_out, int out_size, void* d_ws, size_t ws_size,
                              hipStream_t stream) {
  const float* x    = (const float*)d_in[0];
  const int* ei     = (const int*)d_in[1];
  const int* et     = (const int*)d_in[2];
  const float* Wdes = (const float*)d_in[3];
  const float* bdes = (const float*)d_in[4];
  const float* Wtw  = (const float*)d_in[5];
  const float* btw  = (const float*)d_in[6];
  const float* Wnum = (const float*)d_in[7];
  const float* bnum = (const float*)d_in[8];
  const float* Wcat = (const float*)d_in[9];
  const float* bcat = (const float*)d_in[10];
  const float* Win  = (const float*)d_in[11];
  const float* bin  = (const float*)d_in[12];
  const float* pa   = (const float*)d_in[13];
  const float* root1 = (const float*)d_in[14];
  const float* rel1  = (const float*)d_in[15];
  const float* bias1 = (const float*)d_in[16];
  const float* root2 = (const float*)d_in[17];
  const float* rel2  = (const float*)d_in[18];
  const float* bias2 = (const float*)d_in[19];
  const float* Wcls  = (const float*)d_in[20];
  const float* bcls  = (const float*)d_in[21];
  float* out = (float*)d_out;

  char* p = (char*)d_ws;
  float* mh = (float*)p;      p += (size_t)2 * NN * HD * 4;   // 102.4 MB
  float* hB = (float*)p;      p += (size_t)NN * HD * 4;       // 51.2 MB
  int* row_ptr = (int*)p;     p += ((size_t)NN + 4) * 4;
  int* cnt2 = (int*)p;        p += (size_t)2 * NN * 4;
  int* fillpos = (int*)p;     p += (size_t)NN * 4;
  int* entries = (int*)p;     p += (size_t)EE * 4;
  int* bsum = (int*)p;        p += 512;
  unsigned short* Wt = (unsigned short*)p;  p += (size_t)WT_SITES * 2 * 2;

  // weight pre-convert (independent of everything else)
  k_prepw<<<(WT_SITES + 255) / 256, 256, 0, stream>>>(
      Wdes, Wtw, Wnum, Wcat, Win, root1, rel1, root2, rel2, Wcls, Wt);

  // CSR build
  hipMemsetAsync(cnt2, 0, (size_t)3 * NN * 4, stream);  // cnt2 + fillpos
  k_count<<<EE / 256, 256, 0, stream>>>(ei, et, cnt2);
  int nb = (NN + 1023) / 1024;
  k_scan1<<<nb, 256, 0, stream>>>(cnt2, row_ptr, bsum);
  k_scan2<<<1, 128, 0, stream>>>(bsum, nb);
  k_scan3<<<(NN + 1 + 255) / 256, 256, 0, stream>>>(row_ptr, bsum);
  k_fill<<<EE / 256, 256, 0, stream>>>(ei, et, row_ptr, fillpos, entries);

  const int nblkP = (NN + 127) / 128;  // 782
  const int nblk = (NN + 63) / 64;     // 1563
  // h0 -> d_out
  k_proj2<<<nblkP, 512, 0, stream>>>(x, bdes, btw, bnum, bcat, bin, pa, Wt, out);
  // layer 1
  k_rgemm<<<nblk, 256, 0, stream>>>(out, Wt + OFF_L1_HI, Wt + OFF_L1_LO, bias1, hB, mh);
  k_aggregate<<<NN / 4, 256, 0, stream>>>(hB, mh, row_ptr, cnt2, entries);
  // layer 2
  k_rgemm<<<nblk, 256, 0, stream>>>(hB, Wt + OFF_L2_HI, Wt + OFF_L2_LO, bias2, out, mh);
  k_aggregate<<<NN / 4, 256, 0, stream>>>(out, mh, row_ptr, cnt2, entries);
  // classifier (MFMA, in-place)
  k_cls2<<<nblk, 256, 0, stream>>>(out, Wt, bcls);
}

// Round 7
// 1052.371 us; speedup vs baseline: 1.2624x; 1.0297x over previous
//
#include <hip/hip_runtime.h>
#include <cstdint>
#include <cstddef>

#define NN 100000
#define EE 1600000
#define XDIM 1553
#define HD 128

typedef __attribute__((ext_vector_type(8))) short short8;
typedef __attribute__((ext_vector_type(4))) float f32x4;
// unaligned-capable 4-float vector: hardware allows 4B-aligned dwordx4
typedef float f32x4u __attribute__((vector_size(16), aligned(4)));

union Frag { unsigned int u[4]; short8 s; uint4 v; };

// weight area offsets (ushort units); hi/lo are separate regions
#define OFF_DES_HI 0
#define OFF_DES_LO 98304
#define OFF_TW_HI  196608
#define OFF_TW_LO  294912
#define OFF_NUM_HI 393216
#define OFF_NUM_LO 397312
#define OFF_CAT_HI 401408
#define OFF_CAT_LO 405504
#define OFF_WIN_HI 409600
#define OFF_WIN_LO 475136
#define OFF_L1_HI  540672
#define OFF_L1_LO  589824
#define OFF_L2_HI  638976
#define OFF_L2_LO  688128
#define OFF_CLS_HI 737280
#define OFF_CLS_LO 753664
#define WT_SITES   385024   // (col,k) sites; each writes hi+lo

// hi = trunc-bf16(f), lo = trunc-bf16(f - hi). Packed: 2 elems -> 1 u32 via v_perm.
__device__ __forceinline__ void cvt_pair(float f0, float f1,
                                         unsigned int& hi, unsigned int& lo) {
  unsigned int u0 = __float_as_uint(f0), u1 = __float_as_uint(f1);
  hi = __builtin_amdgcn_perm(u1, u0, 0x07060302u);
  float l0 = f0 - __uint_as_float(u0 & 0xFFFF0000u);
  float l1 = f1 - __uint_as_float(u1 & 0xFFFF0000u);
  lo = __builtin_amdgcn_perm(__float_as_uint(l1), __float_as_uint(l0), 0x07060302u);
}

// raw barriers: no vmcnt drain (prefetched global loads ride across);
// lgkm0 variant publishes ds_writes before the barrier.
__device__ __forceinline__ void fence_barrier() {
  asm volatile("" ::: "memory");
  __builtin_amdgcn_s_barrier();
  asm volatile("" ::: "memory");
}
__device__ __forceinline__ void lgkm0_barrier() {
  asm volatile("s_waitcnt lgkmcnt(0)" ::: "memory");
  __builtin_amdgcn_s_barrier();
  asm volatile("" ::: "memory");
}

// ---------------- weight pre-convert/transpose (runs once, tiny) ----------------
__global__ __launch_bounds__(256) void k_prepw(
    const float* __restrict__ Wdes, const float* __restrict__ Wtw,
    const float* __restrict__ Wnum, const float* __restrict__ Wcat,
    const float* __restrict__ Win,  const float* __restrict__ root1,
    const float* __restrict__ rel1, const float* __restrict__ root2,
    const float* __restrict__ rel2, const float* __restrict__ Wcls,
    unsigned short* __restrict__ Wt) {
  int id = blockIdx.x * 256 + threadIdx.x;
  if (id >= WT_SITES) return;
  const float* src; int K, Kpad, dhi, dlo, local;
  if (id < 98304)       { src=Wdes;        K=768; Kpad=768; dhi=OFF_DES_HI;       dlo=OFF_DES_LO;       local=id; }
  else if (id < 196608) { src=Wtw;         K=768; Kpad=768; dhi=OFF_TW_HI;        dlo=OFF_TW_LO;        local=id-98304; }
  else if (id < 200704) { src=Wnum;        K=6;   Kpad=32;  dhi=OFF_NUM_HI;       dlo=OFF_NUM_LO;       local=id-196608; }
  else if (id < 204800) { src=Wcat;        K=11;  Kpad=32;  dhi=OFF_CAT_HI;       dlo=OFF_CAT_LO;       local=id-200704; }
  else if (id < 270336) { src=Win;         K=512; Kpad=512; dhi=OFF_WIN_HI;       dlo=OFF_WIN_LO;       local=id-204800; }
  else if (id < 286720) { src=root1;       K=128; Kpad=128; dhi=OFF_L1_HI;        dlo=OFF_L1_LO;        local=id-270336; }
  else if (id < 303104) { src=rel1;        K=128; Kpad=128; dhi=OFF_L1_HI+16384;  dlo=OFF_L1_LO+16384;  local=id-286720; }
  else if (id < 319488) { src=rel1+16384;  K=128; Kpad=128; dhi=OFF_L1_HI+32768;  dlo=OFF_L1_LO+32768;  local=id-303104; }
  else if (id < 335872) { src=root2;       K=128; Kpad=128; dhi=OFF_L2_HI;        dlo=OFF_L2_LO;        local=id-319488; }
  else if (id < 352256) { src=rel2;        K=128; Kpad=128; dhi=OFF_L2_HI+16384;  dlo=OFF_L2_LO+16384;  local=id-335872; }
  else if (id < 368640) { src=rel2+16384;  K=128; Kpad=128; dhi=OFF_L2_HI+32768;  dlo=OFF_L2_LO+32768;  local=id-352256; }
  else                  { src=Wcls;        K=128; Kpad=128; dhi=OFF_CLS_HI;       dlo=OFF_CLS_LO;       local=id-368640; }
  int col = local / Kpad;
  int k = local - col * Kpad;
  float v = (k < K) ? src[(size_t)k * 128 + col] : 0.f;
  unsigned int u = __float_as_uint(v);
  float lo = v - __uint_as_float(u & 0xFFFF0000u);
  Wt[dhi + col * Kpad + k] = (unsigned short)(u >> 16);
  Wt[dlo + col * Kpad + k] = (unsigned short)(__float_as_uint(lo) >> 16);
}

// ---------------- CSR build ----------------
__global__ __launch_bounds__(256) void k_count(const int* __restrict__ ei,
                                               const int* __restrict__ et,
                                               int* __restrict__ cnt2) {
  int e = blockIdx.x * 256 + threadIdx.x;
  if (e >= EE) return;
  atomicAdd(&cnt2[et[e] * NN + ei[EE + e]], 1);
}

__global__ __launch_bounds__(256) void k_scan1(const int* __restrict__ cnt2,
                                               int* __restrict__ row_ptr,
                                               int* __restrict__ bsum) {
  __shared__ int sums[256];
  int t = threadIdx.x;
  int base = blockIdx.x * 1024 + t * 4;
  int v[4]; int s = 0;
#pragma unroll
  for (int j = 0; j < 4; ++j) {
    int idx = base + j;
    v[j] = (idx < NN) ? (cnt2[idx] + cnt2[NN + idx]) : 0;
    s += v[j];
  }
  sums[t] = s;
  __syncthreads();
  for (int d = 1; d < 256; d <<= 1) {
    int val = (t >= d) ? sums[t - d] : 0;
    __syncthreads();
    sums[t] += val;
    __syncthreads();
  }
  int excl = sums[t] - s;
  if (t == 255) bsum[blockIdx.x] = sums[t];
  int run = excl;
#pragma unroll
  for (int j = 0; j < 4; ++j) {
    int idx = base + j;
    if (idx < NN) row_ptr[idx] = run;
    run += v[j];
  }
}

__global__ __launch_bounds__(128) void k_scan2(int* __restrict__ bsum, int nb) {
  __shared__ int s[128];
  int t = threadIdx.x;
  int v = (t < nb) ? bsum[t] : 0;
  s[t] = v;
  __syncthreads();
  for (int d = 1; d < 128; d <<= 1) {
    int val = (t >= d) ? s[t - d] : 0;
    __syncthreads();
    s[t] += val;
    __syncthreads();
  }
  if (t < nb) bsum[t] = s[t] - v;
}

__global__ __launch_bounds__(256) void k_scan3(int* __restrict__ row_ptr,
                                               const int* __restrict__ bsum) {
  int idx = blockIdx.x * 256 + threadIdx.x;
  if (idx < NN) row_ptr[idx] += bsum[idx >> 10];
  if (idx == NN) row_ptr[NN] = EE;
}

__global__ __launch_bounds__(256) void k_fill(const int* __restrict__ ei,
                                              const int* __restrict__ et,
                                              const int* __restrict__ row_ptr,
                                              int* __restrict__ fillpos,
                                              int* __restrict__ entries) {
  int e = blockIdx.x * 256 + threadIdx.x;
  if (e >= EE) return;
  int src = ei[e];
  int dst = ei[EE + e];
  int r = et[e];
  int pos = atomicAdd(&fillpos[dst], 1);
  entries[row_ptr[dst] + pos] = src | (r << 20);
}

// ---------------- fused projection (MFMA, split-bf16, pipelined, raw barriers) ----
// 64 nodes/block, 4 waves, wave = 16 rows x 128 cols, 3 blocks/CU (R3 shape,
// 84 VGPR no-spill). X loads are 2x unaligned global_load_dwordx4 per lane-tile
// (f32x4u, align-4: x rows are only 4B-aligned because XDIM=1553 is odd) --
// 4x fewer TA instructions than the scalar-gather path. X pipeline depth-3.
__global__ __launch_bounds__(256, 3) void k_proj2(
    const float* __restrict__ x,
    const float* __restrict__ bdes, const float* __restrict__ btw,
    const float* __restrict__ bnum, const float* __restrict__ bcat,
    const float* __restrict__ bin,  const float* __restrict__ pa,
    const unsigned short* __restrict__ Wt, float* __restrict__ h0) {
  __shared__ unsigned short bt_hi[128 * 32], bt_lo[128 * 32];   // 8KB + 8KB
  __shared__ unsigned short z_hi[64 * 128], z_lo[64 * 128];     // 16KB + 16KB

  const int t = threadIdx.x;
  const int node0 = blockIdx.x * 64;
  const int w = t >> 6, lane = t & 63;
  const int li = lane & 15, lg = lane >> 4;

  // B-staging constants (loop-invariant per thread)
  const int cr0 = t >> 2, c0 = t & 3;
  const int cr1 = cr0 + 64;
  const unsigned stb0 = cr0 * 64 + ((c0 ^ ((cr0 >> 1) & 3)) << 4);
  const unsigned stb1 = cr1 * 64 + ((c0 ^ ((cr1 >> 1) & 3)) << 4);

  // one A-row per (wave, li)
  const int rowA = w * 16 + li;
  int nodeA = node0 + rowA;
  int ndA = nodeA < NN ? nodeA : NN - 1;
  const float* xrow = x + (size_t)ndA * XDIM;

#define STORE_BT(SH0, SL0, SH1, SL1)              \
  do {                                            \
    *(uint4*)((char*)bt_hi + stb0) = (SH0);       \
    *(uint4*)((char*)bt_lo + stb0) = (SL0);       \
    *(uint4*)((char*)bt_hi + stb1) = (SH1);       \
    *(uint4*)((char*)bt_lo + stb1) = (SL1);       \
  } while (0)

#define CVT_A2(FA, FB, AH, AL)                                                   \
  do {                                                                           \
    cvt_pair((FA)[0], (FA)[1], (AH).u[0], (AL).u[0]);                            \
    cvt_pair((FA)[2], (FA)[3], (AH).u[1], (AL).u[1]);                            \
    cvt_pair((FB)[0], (FB)[1], (AH).u[2], (AL).u[2]);                            \
    cvt_pair((FB)[2], (FB)[3], (AH).u[3], (AL).u[3]);                            \
  } while (0)

#define MFMA8(AH, AL, ACC)                                                       \
  do {                                                                           \
    _Pragma("unroll")                                                            \
    for (int ct_ = 0; ct_ < 8; ++ct_) {                                          \
      int colrow_ = ct_ * 16 + li;                                               \
      int byte_ = colrow_ * 64 + (lg << 4);                                      \
      byte_ ^= ((colrow_ >> 1) & 3) << 4;                                        \
      Frag bh_, bl_;                                                             \
      bh_.v = *(const uint4*)((char*)bt_hi + byte_);                             \
      bl_.v = *(const uint4*)((char*)bt_lo + byte_);                             \
      (ACC)[ct_] = __builtin_amdgcn_mfma_f32_16x16x32_bf16((AH).s, bl_.s, (ACC)[ct_], 0, 0, 0); \
      (ACC)[ct_] = __builtin_amdgcn_mfma_f32_16x16x32_bf16((AL).s, bh_.s, (ACC)[ct_], 0, 0, 0); \
      (ACC)[ct_] = __builtin_amdgcn_mfma_f32_16x16x32_bf16((AH).s, bh_.s, (ACC)[ct_], 0, 0, 0); \
    }                                                                            \
  } while (0)

// one K-tile of phase A: store W tile (cur), barrier, convert X, prefetch
// W(T+1, into next buf) + X(T+3, dwordx4 pair back into same X bufs), MFMA, barrier.
#define TILE(WC0, WC1, WC2, WC3, WN0, WN1, WN2, WN3, XA, XB, T)                  \
  do {                                                                           \
    STORE_BT(WC0, WC1, WC2, WC3);                                                \
    lgkm0_barrier();                                                             \
    Frag ah_, al_;                                                               \
    CVT_A2(XA, XB, ah_, al_);                                                    \
    {                                                                            \
      const int kw_ = ((T) + 1) * 32;                                            \
      WN0 = *(const uint4*)(ph0 + kw_); WN1 = *(const uint4*)(pl0 + kw_);        \
      WN2 = *(const uint4*)(ph1 + kw_); WN3 = *(const uint4*)(pl1 + kw_);        \
      int kx_ = (T) + 3; if (kx_ > 23) kx_ = 23; kx_ *= 32;                      \
      XA = *(const f32x4u*)(xr + kx_);                                           \
      XB = *(const f32x4u*)(xr + kx_ + 4);                                       \
    }                                                                            \
    MFMA8(ah_, al_, zacc);                                                       \
    fence_barrier();                                                             \
  } while (0)

#define MFMA_B(KT)                                                               \
  do {                                                                           \
    Frag ah_, al_;                                                               \
    int byte_ = rowA * 256 + (((KT) * 32 + lg * 8) << 1);                        \
    byte_ ^= (rowA & 7) << 4;                                                    \
    ah_.v = *(const uint4*)((char*)z_hi + byte_);                                \
    al_.v = *(const uint4*)((char*)z_lo + byte_);                                \
    MFMA8(ah_, al_, hacc);                                                       \
  } while (0)

#define Z_EPI(ZACC, BIASP)                                                       \
  do {                                                                           \
    _Pragma("unroll")                                                            \
    for (int ct_ = 0; ct_ < 8; ++ct_) {                                          \
      int col_ = ct_ * 16 + li;                                                  \
      float bv_ = (BIASP)[col_];                                                 \
      _Pragma("unroll")                                                          \
      for (int r_ = 0; r_ < 4; ++r_) {                                           \
        float v_ = (ZACC)[ct_][r_] + bv_;                                        \
        v_ = v_ >= 0.f ? v_ : 0.01f * v_;                                        \
        int row_ = w * 16 + lg * 4 + r_;                                         \
        int byte_ = row_ * 256 + col_ * 2;                                       \
        byte_ ^= (row_ & 7) << 4;                                                \
        unsigned int u_ = __float_as_uint(v_);                                   \
        *(unsigned short*)((char*)z_hi + byte_) = (unsigned short)(u_ >> 16);    \
        float lo_ = v_ - __uint_as_float(u_ & 0xFFFF0000u);                      \
        *(unsigned short*)((char*)z_lo + byte_) = (unsigned short)(__float_as_uint(lo_) >> 16); \
      }                                                                          \
    }                                                                            \
  } while (0)

// phase B: hacc += z @ Win[SLICE*128 .. +127], 4 K-tiles, fully unrolled,
// 1-deep prefetch of the next Win tile.
#define PHASE_B(SLICE)                                                           \
  do {                                                                           \
    const unsigned short* qh0_ = Wt + OFF_WIN_HI + cr0 * 512 + (SLICE) * 128 + c0 * 8; \
    const unsigned short* ql0_ = Wt + OFF_WIN_LO + cr0 * 512 + (SLICE) * 128 + c0 * 8; \
    const unsigned short* qh1_ = Wt + OFF_WIN_HI + cr1 * 512 + (SLICE) * 128 + c0 * 8; \
    const unsigned short* ql1_ = Wt + OFF_WIN_LO + cr1 * 512 + (SLICE) * 128 + c0 * 8; \
    uint4 wA0_ = *(const uint4*)(qh0_), wA1_ = *(const uint4*)(ql0_);            \
    uint4 wA2_ = *(const uint4*)(qh1_), wA3_ = *(const uint4*)(ql1_);            \
    uint4 wB0_, wB1_, wB2_, wB3_;                                                \
    STORE_BT(wA0_, wA1_, wA2_, wA3_);                                            \
    lgkm0_barrier();                                                             \
    wB0_ = *(const uint4*)(qh0_ + 32); wB1_ = *(const uint4*)(ql0_ + 32);        \
    wB2_ = *(const uint4*)(qh1_ + 32); wB3_ = *(const uint4*)(ql1_ + 32);        \
    MFMA_B(0);                                                                   \
    fence_barrier();                                                             \
    STORE_BT(wB0_, wB1_, wB2_, wB3_);                                            \
    lgkm0_barrier();                                                             \
    wA0_ = *(const uint4*)(qh0_ + 64); wA1_ = *(const uint4*)(ql0_ + 64);        \
    wA2_ = *(const uint4*)(qh1_ + 64); wA3_ = *(const uint4*)(ql1_ + 64);        \
    MFMA_B(1);                                                                   \
    fence_barrier();                                                             \
    STORE_BT(wA0_, wA1_, wA2_, wA3_);                                            \
    lgkm0_barrier();                                                             \
    wB0_ = *(const uint4*)(qh0_ + 96); wB1_ = *(const uint4*)(ql0_ + 96);        \
    wB2_ = *(const uint4*)(qh1_ + 96); wB3_ = *(const uint4*)(ql1_ + 96);        \
    MFMA_B(2);                                                                   \
    fence_barrier();                                                             \
    STORE_BT(wB0_, wB1_, wB2_, wB3_);                                            \
    lgkm0_barrier();                                                             \
    MFMA_B(3);                                                                   \
    fence_barrier();                                                             \
  } while (0)

  f32x4 hacc[8];
#pragma unroll
  for (int b = 0; b < 8; ++b) hacc[b] = (f32x4)0.f;

  // ---- big segments: des (s=0), tweet (s=1); K=768 = 24 K-tiles, pipelined ----
#pragma unroll
  for (int s = 0; s < 2; ++s) {
    const int off = (s == 0) ? 785 : 6;
    const unsigned short* wh = Wt + (s == 0 ? OFF_DES_HI : OFF_TW_HI);
    const unsigned short* wl = Wt + (s == 0 ? OFF_DES_LO : OFF_TW_LO);
    const float* bias = (s == 0) ? bdes : btw;

    const float* xr = xrow + off + lg * 8;
    const unsigned short* ph0 = wh + cr0 * 768 + c0 * 8;
    const unsigned short* pl0 = wl + cr0 * 768 + c0 * 8;
    const unsigned short* ph1 = wh + cr1 * 768 + c0 * 8;
    const unsigned short* pl1 = wl + cr1 * 768 + c0 * 8;

    f32x4 zacc[8];
#pragma unroll
    for (int b = 0; b < 8; ++b) zacc[b] = (f32x4)0.f;

    uint4 WA0, WA1, WA2, WA3, WB0, WB1, WB2, WB3;
    f32x4u X0a, X0b, X1a, X1b, X2a, X2b;

    // prologue: W tile 0, X tiles 0..2 (dwordx4 pairs)
    WA0 = *(const uint4*)(ph0); WA1 = *(const uint4*)(pl0);
    WA2 = *(const uint4*)(ph1); WA3 = *(const uint4*)(pl1);
    X0a = *(const f32x4u*)(xr);      X0b = *(const f32x4u*)(xr + 4);
    X1a = *(const f32x4u*)(xr + 32); X1b = *(const f32x4u*)(xr + 36);
    X2a = *(const f32x4u*)(xr + 64); X2b = *(const f32x4u*)(xr + 68);

    for (int base = 0; base < 24; base += 6) {
      TILE(WA0, WA1, WA2, WA3, WB0, WB1, WB2, WB3, X0a, X0b, base + 0);
      TILE(WB0, WB1, WB2, WB3, WA0, WA1, WA2, WA3, X1a, X1b, base + 1);
      TILE(WA0, WA1, WA2, WA3, WB0, WB1, WB2, WB3, X2a, X2b, base + 2);
      TILE(WB0, WB1, WB2, WB3, WA0, WA1, WA2, WA3, X0a, X0b, base + 3);
      TILE(WA0, WA1, WA2, WA3, WB0, WB1, WB2, WB3, X1a, X1b, base + 4);
      TILE(WB0, WB1, WB2, WB3, WA0, WA1, WA2, WA3, X2a, X2b, base + 5);
    }
    Z_EPI(zacc, bias);   // z is wave-private: no barrier needed for z itself
    PHASE_B(s);
  }

  // ---- small segments: num (K=6), cat (K=11); single padded K-tile each ----
#pragma unroll
  for (int u = 0; u < 2; ++u) {
    const int offu = (u == 0) ? 0 : 774;
    const int Ksu = (u == 0) ? 6 : 11;
    const unsigned short* wh = Wt + (u == 0 ? OFF_NUM_HI : OFF_CAT_HI);
    const unsigned short* wl = Wt + (u == 0 ? OFF_NUM_LO : OFF_CAT_LO);
    const float* biasu = (u == 0) ? bnum : bcat;
    const float* xr = xrow + offu + lg * 8;

    uint4 s0 = *(const uint4*)(wh + cr0 * 32 + c0 * 8);
    uint4 s1 = *(const uint4*)(wl + cr0 * 32 + c0 * 8);
    uint4 s2 = *(const uint4*)(wh + cr1 * 32 + c0 * 8);
    uint4 s3 = *(const uint4*)(wl + cr1 * 32 + c0 * 8);
    f32x4u fa = *(const f32x4u*)(xr);
    f32x4u fb = *(const f32x4u*)(xr + 4);
#pragma unroll
    for (int j = 0; j < 4; ++j) {
      if (lg * 8 + j >= Ksu) fa[j] = 0.f;
      if (lg * 8 + 4 + j >= Ksu) fb[j] = 0.f;
    }

    f32x4 zacc[8];
#pragma unroll
    for (int b = 0; b < 8; ++b) zacc[b] = (f32x4)0.f;

    STORE_BT(s0, s1, s2, s3);
    lgkm0_barrier();
    {
      Frag ah_, al_;
      CVT_A2(fa, fb, ah_, al_);
      MFMA8(ah_, al_, zacc);
    }
    fence_barrier();
    Z_EPI(zacc, biasu);
    PHASE_B(u + 2);
  }

  // epilogue: + b_in, PReLU, store
#pragma unroll
  for (int ct = 0; ct < 8; ++ct) {
    int col = ct * 16 + li;
    float bi = bin[col];
    float p = pa[col];
#pragma unroll
    for (int r = 0; r < 4; ++r) {
      int node = node0 + w * 16 + lg * 4 + r;
      if (node < NN) {
        float v = hacc[ct][r] + bi;
        v = v >= 0.f ? v : p * v;
        h0[(size_t)node * HD + col] = v;
      }
    }
  }

#undef STORE_BT
#undef CVT_A2
#undef MFMA8
#undef TILE
#undef MFMA_B
#undef Z_EPI
#undef PHASE_B
}

// ---------------- layer GEMM: hin @ [root|rel0|rel1] (MFMA split-bf16) ----------------
// 64 rows/block, 4 waves: wave = 64 rows x 96 cols (of 384).
// Raw barriers + 1-deep ping-pong prefetch of the A (hin) row fragments
// (dwordx4 pairs via f32x4u).
__global__ __launch_bounds__(256, 2) void k_rgemm(
    const float* __restrict__ hin, const unsigned short* __restrict__ wl_hi,
    const unsigned short* __restrict__ wl_lo, const float* __restrict__ bias,
    float* __restrict__ base, float* __restrict__ mh) {
  __shared__ unsigned short bt_hi[384 * 32], bt_lo[384 * 32];  // 24KB + 24KB

  const int t = threadIdx.x;
  const int node0 = blockIdx.x * 64;
  const int w = t >> 6, lane = t & 63;
  const int li = lane & 15, lg = lane >> 4;

  const float* ab[4];
#pragma unroll
  for (int sub = 0; sub < 4; ++sub) {
    int node = node0 + sub * 16 + li;
    int nd = node < NN ? node : NN - 1;
    ab[sub] = hin + (size_t)nd * HD + lg * 8;
  }

  f32x4 acc[4][6];
#pragma unroll
  for (int a = 0; a < 4; ++a)
#pragma unroll
    for (int b = 0; b < 6; ++b) acc[a][b] = (f32x4)0.f;

// stage B tile [384][32] hi/lo in two halves (keeps reg peak low)
#define RG_STAGE(KT)                                                             \
  do {                                                                           \
    _Pragma("unroll")                                                            \
    for (int h_ = 0; h_ < 2; ++h_) {                                             \
      uint4 sh_[3], sl_[3];                                                      \
      _Pragma("unroll")                                                          \
      for (int j_ = 0; j_ < 3; ++j_) {                                           \
        int cid_ = t + (h_ * 3 + j_) * 256;                                      \
        int cr_ = cid_ >> 2, c_ = cid_ & 3;                                      \
        sh_[j_] = *(const uint4*)(wl_hi + cr_ * 128 + (KT) * 32 + c_ * 8);       \
        sl_[j_] = *(const uint4*)(wl_lo + cr_ * 128 + (KT) * 32 + c_ * 8);       \
      }                                                                          \
      _Pragma("unroll")                                                          \
      for (int j_ = 0; j_ < 3; ++j_) {                                           \
        int cid_ = t + (h_ * 3 + j_) * 256;                                      \
        int cr_ = cid_ >> 2, c_ = cid_ & 3;                                      \
        unsigned b_ = cr_ * 64 + ((c_ ^ ((cr_ >> 1) & 3)) << 4);                 \
        *(uint4*)((char*)bt_hi + b_) = sh_[j_];                                  \
        *(uint4*)((char*)bt_lo + b_) = sl_[j_];                                  \
      }                                                                          \
    }                                                                            \
  } while (0)

#define RG_LOADA(KT, F)                                                          \
  do {                                                                           \
    _Pragma("unroll")                                                            \
    for (int sub_ = 0; sub_ < 4; ++sub_) {                                       \
      (F)[sub_][0] = *(const f32x4u*)(ab[sub_] + (KT) * 32);                     \
      (F)[sub_][1] = *(const f32x4u*)(ab[sub_] + (KT) * 32 + 4);                 \
    }                                                                            \
  } while (0)

#define RG_MFMA(F)                                                               \
  do {                                                                           \
    Frag ah_[4], al_[4];                                                         \
    _Pragma("unroll")                                                            \
    for (int sub_ = 0; sub_ < 4; ++sub_) {                                       \
      cvt_pair((F)[sub_][0][0], (F)[sub_][0][1], ah_[sub_].u[0], al_[sub_].u[0]); \
      cvt_pair((F)[sub_][0][2], (F)[sub_][0][3], ah_[sub_].u[1], al_[sub_].u[1]); \
      cvt_pair((F)[sub_][1][0], (F)[sub_][1][1], ah_[sub_].u[2], al_[sub_].u[2]); \
      cvt_pair((F)[sub_][1][2], (F)[sub_][1][3], ah_[sub_].u[3], al_[sub_].u[3]); \
    }                                                                            \
    _Pragma("unroll")                                                            \
    for (int ct_ = 0; ct_ < 6; ++ct_) {                                          \
      int colrow_ = w * 96 + ct_ * 16 + li;                                      \
      int byte_ = colrow_ * 64 + (lg << 4);                                      \
      byte_ ^= ((colrow_ >> 1) & 3) << 4;                                        \
      Frag bh_, bl_;                                                             \
      bh_.v = *(const uint4*)((char*)bt_hi + byte_);                             \
      bl_.v = *(const uint4*)((char*)bt_lo + byte_);                             \
      _Pragma("unroll")                                                          \
      for (int sub_ = 0; sub_ < 4; ++sub_) {                                     \
        acc[sub_][ct_] = __builtin_amdgcn_mfma_f32_16x16x32_bf16(ah_[sub_].s, bl_.s, acc[sub_][ct_], 0, 0, 0); \
        acc[sub_][ct_] = __builtin_amdgcn_mfma_f32_16x16x32_bf16(al_[sub_].s, bh_.s, acc[sub_][ct_], 0, 0, 0); \
        acc[sub_][ct_] = __builtin_amdgcn_mfma_f32_16x16x32_bf16(ah_[sub_].s, bh_.s, acc[sub_][ct_], 0, 0, 0); \
      }                                                                          \
    }                                                                            \
  } while (0)

  f32x4u fA[4][2], fB[4][2];
  RG_LOADA(0, fA);

  RG_STAGE(0);
  RG_LOADA(1, fB);
  lgkm0_barrier();
  RG_MFMA(fA);
  fence_barrier();

  RG_STAGE(1);
  RG_LOADA(2, fA);
  lgkm0_barrier();
  RG_MFMA(fB);
  fence_barrier();

  RG_STAGE(2);
  RG_LOADA(3, fB);
  lgkm0_barrier();
  RG_MFMA(fA);
  fence_barrier();

  RG_STAGE(3);
  lgkm0_barrier();
  RG_MFMA(fB);

#undef RG_STAGE
#undef RG_LOADA
#undef RG_MFMA

  // epilogue
#pragma unroll
  for (int ct = 0; ct < 6; ++ct) {
    int gcol = w * 96 + ct * 16 + li;
    float bv = 0.f;
    float* dp;
    int lc;
    if (gcol < 128) { bv = bias[gcol]; dp = base; lc = gcol; }
    else if (gcol < 256) { dp = mh; lc = gcol - 128; }
    else { dp = mh + (size_t)NN * HD; lc = gcol - 256; }
#pragma unroll
    for (int sub = 0; sub < 4; ++sub) {
#pragma unroll
      for (int r = 0; r < 4; ++r) {
        int node = node0 + sub * 16 + lg * 4 + r;
        if (node < NN) dp[(size_t)node * HD + lc] = acc[sub][ct][r] + bv;
      }
    }
  }
}

// ---------------- aggregation (float2-vectorized) ----------------
// lane l handles cols {2l, 2l+1}: one 8B load per gathered row; per-column
// accumulation order unchanged (same edge order) -> bit-identical.
__global__ __launch_bounds__(256) void k_aggregate(
    float* __restrict__ io, const float* __restrict__ mh,
    const int* __restrict__ row_ptr, const int* __restrict__ cnt2,
    const int* __restrict__ entries) {
  int i = blockIdx.x * 4 + (threadIdx.x >> 6);
  int l = threadIdx.x & 63;
  if (i >= NN) return;
  int rs = row_ptr[i], re = row_ptr[i + 1];
  int c0 = cnt2[i], c1 = cnt2[NN + i];
  float inv0 = 1.f / (float)(c0 > 0 ? c0 : 1);
  float inv1 = 1.f / (float)(c1 > 0 ? c1 : 1);
  float a0 = 0, a1 = 0, b0 = 0, b1 = 0;
  int e = rs;
  for (; e + 1 < re; e += 2) {
    int ent0 = entries[e], ent1 = entries[e + 1];
    const float2* r0 = (const float2*)(mh + (((size_t)(ent0 >> 20)) * NN + (ent0 & 0xFFFFF)) * HD);
    const float2* r1 = (const float2*)(mh + (((size_t)(ent1 >> 20)) * NN + (ent1 & 0xFFFFF)) * HD);
    float2 v0 = r0[l], v1 = r1[l];
    if (ent0 >> 20) { b0 += v0.x; b1 += v0.y; } else { a0 += v0.x; a1 += v0.y; }
    if (ent1 >> 20) { b0 += v1.x; b1 += v1.y; } else { a0 += v1.x; a1 += v1.y; }
  }
  if (e < re) {
    int ent = entries[e];
    const float2* r0 = (const float2*)(mh + (((size_t)(ent >> 20)) * NN + (ent & 0xFFFFF)) * HD);
    float2 v0 = r0[l];
    if (ent >> 20) { b0 += v0.x; b1 += v0.y; } else { a0 += v0.x; a1 += v0.y; }
  }
  float2* iop = (float2*)(io + (size_t)i * HD);
  float2 cur = iop[l];
  cur.x += a0 * inv0 + b0 * inv1;
  cur.y += a1 * inv0 + b1 * inv1;
  iop[l] = cur;
}

// ---------------- final linear (MFMA, in-place) ----------------
// 64 rows/block, 4 waves in 2x2: wave = 32 rows x 64 cols.
// Raw barriers + 1-deep ping-pong prefetch of the A (io) row fragments.
__global__ __launch_bounds__(256, 4) void k_cls2(
    float* __restrict__ io, const unsigned short* __restrict__ Wt,
    const float* __restrict__ b) {
  __shared__ unsigned short bt_hi[128 * 32], bt_lo[128 * 32];  // 8KB + 8KB

  const int t = threadIdx.x;
  const int node0 = blockIdx.x * 64;
  const int w = t >> 6, lane = t & 63;
  const int li = lane & 15, lg = lane >> 4;
  const int wr = w >> 1, wc = w & 1;

  int nodeA0 = node0 + wr * 32 + li; int nd0 = nodeA0 < NN ? nodeA0 : NN - 1;
  int nodeA1 = nodeA0 + 16;          int nd1 = nodeA1 < NN ? nodeA1 : NN - 1;
  const float* ap0 = io + (size_t)nd0 * HD + lg * 8;
  const float* ap1 = io + (size_t)nd1 * HD + lg * 8;

  f32x4 acc[2][4];
#pragma unroll
  for (int a = 0; a < 2; ++a)
#pragma unroll
    for (int bq = 0; bq < 4; ++bq) acc[a][bq] = (f32x4)0.f;

#define CL_STAGE(KT)                                                             \
  do {                                                                           \
    uint4 sh_[2], sl_[2];                                                        \
    _Pragma("unroll")                                                            \
    for (int j_ = 0; j_ < 2; ++j_) {                                             \
      int cid_ = t + j_ * 256;                                                   \
      int cr_ = cid_ >> 2, c_ = cid_ & 3;                                        \
      sh_[j_] = *(const uint4*)(Wt + OFF_CLS_HI + cr_ * 128 + (KT) * 32 + c_ * 8); \
      sl_[j_] = *(const uint4*)(Wt + OFF_CLS_LO + cr_ * 128 + (KT) * 32 + c_ * 8); \
    }                                                                            \
    _Pragma("unroll")                                                            \
    for (int j_ = 0; j_ < 2; ++j_) {                                             \
      int cid_ = t + j_ * 256;                                                   \
      int cr_ = cid_ >> 2, c_ = cid_ & 3;                                        \
      unsigned b_ = cr_ * 64 + ((c_ ^ ((cr_ >> 1) & 3)) << 4);                   \
      *(uint4*)((char*)bt_hi + b_) = sh_[j_];                                    \
      *(uint4*)((char*)bt_lo + b_) = sl_[j_];                                    \
    }                                                                            \
  } while (0)

#define CL_LOADA(KT, F)                                                          \
  do {                                                                           \
    (F)[0][0] = *(const f32x4u*)(ap0 + (KT) * 32);                               \
    (F)[0][1] = *(const f32x4u*)(ap0 + (KT) * 32 + 4);                           \
    (F)[1][0] = *(const f32x4u*)(ap1 + (KT) * 32);                               \
    (F)[1][1] = *(const f32x4u*)(ap1 + (KT) * 32 + 4);                           \
  } while (0)

#define CL_MFMA(F)                                                               \
  do {                                                                           \
    Frag ah_[2], al_[2];                                                         \
    _Pragma("unroll")                                                            \
    for (int sub_ = 0; sub_ < 2; ++sub_) {                                       \
      cvt_pair((F)[sub_][0][0], (F)[sub_][0][1], ah_[sub_].u[0], al_[sub_].u[0]); \
      cvt_pair((F)[sub_][0][2], (F)[sub_][0][3], ah_[sub_].u[1], al_[sub_].u[1]); \
      cvt_pair((F)[sub_][1][0], (F)[sub_][1][1], ah_[sub_].u[2], al_[sub_].u[2]); \
      cvt_pair((F)[sub_][1][2], (F)[sub_][1][3], ah_[sub_].u[3], al_[sub_].u[3]); \
    }                                                                            \
    _Pragma("unroll")                                                            \
    for (int ct_ = 0; ct_ < 4; ++ct_) {                                          \
      int colrow_ = wc * 64 + ct_ * 16 + li;                                     \
      int byte_ = colrow_ * 64 + (lg << 4);                                      \
      byte_ ^= ((colrow_ >> 1) & 3) << 4;                                        \
      Frag bh_, bl_;                                                             \
      bh_.v = *(const uint4*)((char*)bt_hi + byte_);                             \
      bl_.v = *(const uint4*)((char*)bt_lo + byte_);                             \
      _Pragma("unroll")                                                          \
      for (int sub_ = 0; sub_ < 2; ++sub_) {                                     \
        acc[sub_][ct_] = __builtin_amdgcn_mfma_f32_16x16x32_bf16(ah_[sub_].s, bl_.s, acc[sub_][ct_], 0, 0, 0); \
        acc[sub_][ct_] = __builtin_amdgcn_mfma_f32_16x16x32_bf16(al_[sub_].s, bh_.s, acc[sub_][ct_], 0, 0, 0); \
        acc[sub_][ct_] = __builtin_amdgcn_mfma_f32_16x16x32_bf16(ah_[sub_].s, bh_.s, acc[sub_][ct_], 0, 0, 0); \
      }                                                                          \
    }                                                                            \
  } while (0)

  f32x4u fA[2][2], fB[2][2];
  CL_LOADA(0, fA);

  CL_STAGE(0);
  CL_LOADA(1, fB);
  lgkm0_barrier();
  CL_MFMA(fA);
  fence_barrier();

  CL_STAGE(1);
  CL_LOADA(2, fA);
  lgkm0_barrier();
  CL_MFMA(fB);
  fence_barrier();

  CL_STAGE(2);
  CL_LOADA(3, fB);
  lgkm0_barrier();
  CL_MFMA(fA);
  fence_barrier();

  CL_STAGE(3);
  lgkm0_barrier();
  CL_MFMA(fB);

#undef CL_STAGE
#undef CL_LOADA
#undef CL_MFMA

  __syncthreads();  // all A-reads of this block's rows done before in-place writes
#pragma unroll
  for (int ct = 0; ct < 4; ++ct) {
    int col = wc * 64 + ct * 16 + li;
    float bv = b[col];
#pragma unroll
    for (int sub = 0; sub < 2; ++sub) {
#pragma unroll
      for (int r = 0; r < 4; ++r) {
        int node = node0 + wr * 32 + sub * 16 + lg * 4 + r;
        if (node < NN) io[(size_t)node * HD + col] = acc[sub][ct][r] + bv;
      }
    }
  }
}

extern "C" void kernel_launch(void* const* d_in, const int* in_sizes, int n_in,
                              void* d_out, int out_size, void* d_ws, size_t ws_size,
                              hipStream_t stream) {
  const float* x    = (const float*)d_in[0];
  const int* ei     = (const int*)d_in[1];
  const int* et     = (const int*)d_in[2];
  const float* Wdes = (const float*)d_in[3];
  const float* bdes = (const float*)d_in[4];
  const float* Wtw  = (const float*)d_in[5];
  const float* btw  = (const float*)d_in[6];
  const float* Wnum = (const float*)d_in[7];
  const float* bnum = (const float*)d_in[8];
  const float* Wcat = (const float*)d_in[9];
  const float* bcat = (const float*)d_in[10];
  const float* Win  = (const float*)d_in[11];
  const float* bin  = (const float*)d_in[12];
  const float* pa   = (const float*)d_in[13];
  const float* root1 = (const float*)d_in[14];
  const float* rel1  = (const float*)d_in[15];
  const float* bias1 = (const float*)d_in[16];
  const float* root2 = (const float*)d_in[17];
  const float* rel2  = (const float*)d_in[18];
  const float* bias2 = (const float*)d_in[19];
  const float* Wcls  = (const float*)d_in[20];
  const float* bcls  = (const float*)d_in[21];
  float* out = (float*)d_out;

  char* p = (char*)d_ws;
  float* mh = (float*)p;      p += (size_t)2 * NN * HD * 4;   // 102.4 MB
  float* hB = (float*)p;      p += (size_t)NN * HD * 4;       // 51.2 MB
  int* row_ptr = (int*)p;     p += ((size_t)NN + 4) * 4;
  int* cnt2 = (int*)p;        p += (size_t)2 * NN * 4;
  int* fillpos = (int*)p;     p += (size_t)NN * 4;
  int* entries = (int*)p;     p += (size_t)EE * 4;
  int* bsum = (int*)p;        p += 512;
  unsigned short* Wt = (unsigned short*)p;  p += (size_t)WT_SITES * 2 * 2;

  // weight pre-convert (independent of everything else)
  k_prepw<<<(WT_SITES + 255) / 256, 256, 0, stream>>>(
      Wdes, Wtw, Wnum, Wcat, Win, root1, rel1, root2, rel2, Wcls, Wt);

  // CSR build
  hipMemsetAsync(cnt2, 0, (size_t)3 * NN * 4, stream);  // cnt2 + fillpos
  k_count<<<EE / 256, 256, 0, stream>>>(ei, et, cnt2);
  int nb = (NN + 1023) / 1024;
  k_scan1<<<nb, 256, 0, stream>>>(cnt2, row_ptr, bsum);
  k_scan2<<<1, 128, 0, stream>>>(bsum, nb);
  k_scan3<<<(NN + 1 + 255) / 256, 256, 0, stream>>>(row_ptr, bsum);
  k_fill<<<EE / 256, 256, 0, stream>>>(ei, et, row_ptr, fillpos, entries);

  const int nblk = (NN + 63) / 64;  // 1563
  // h0 -> d_out
  k_proj2<<<nblk, 256, 0, stream>>>(x, bdes, btw, bnum, bcat, bin, pa, Wt, out);
  // layer 1
  k_rgemm<<<nblk, 256, 0, stream>>>(out, Wt + OFF_L1_HI, Wt + OFF_L1_LO, bias1, hB, mh);
  k_aggregate<<<NN / 4, 256, 0, stream>>>(hB, mh, row_ptr, cnt2, entries);
  // layer 2
  k_rgemm<<<nblk, 256, 0, stream>>>(hB, Wt + OFF_L2_HI, Wt + OFF_L2_LO, bias2, out, mh);
  k_aggregate<<<NN / 4, 256, 0, stream>>>(out, mh, row_ptr, cnt2, entries);
  // classifier (MFMA, in-place)
  k_cls2<<<nblk, 256, 0, stream>>>(out, Wt, bcls);
}

// Round 8
// 976.097 us; speedup vs baseline: 1.3610x; 1.0781x over previous
//
#include <hip/hip_runtime.h>
#include <cstdint>
#include <cstddef>

#define NN 100000
#define EE 1600000
#define XDIM 1553
#define HD 128

typedef __attribute__((ext_vector_type(8))) short short8;
typedef __attribute__((ext_vector_type(4))) float f32x4;
// unaligned-capable 4-float vector: hardware allows 4B-aligned dwordx4
typedef float f32x4u __attribute__((vector_size(16), aligned(4)));

union Frag { unsigned int u[4]; short8 s; uint4 v; };

// weight area offsets (ushort units); hi/lo are separate regions
#define OFF_DES_HI 0
#define OFF_DES_LO 98304
#define OFF_TW_HI  196608
#define OFF_TW_LO  294912
#define OFF_NUM_HI 393216
#define OFF_NUM_LO 397312
#define OFF_CAT_HI 401408
#define OFF_CAT_LO 405504
#define OFF_WIN_HI 409600
#define OFF_WIN_LO 475136
#define OFF_L1_HI  540672
#define OFF_L1_LO  589824
#define OFF_L2_HI  638976
#define OFF_L2_LO  688128
#define OFF_CLS_HI 737280
#define OFF_CLS_LO 753664
#define WT_SITES   385024   // (col,k) sites; each writes hi+lo

// hi = trunc-bf16(f), lo = trunc-bf16(f - hi). Packed: 2 elems -> 1 u32 via v_perm.
__device__ __forceinline__ void cvt_pair(float f0, float f1,
                                         unsigned int& hi, unsigned int& lo) {
  unsigned int u0 = __float_as_uint(f0), u1 = __float_as_uint(f1);
  hi = __builtin_amdgcn_perm(u1, u0, 0x07060302u);
  float l0 = f0 - __uint_as_float(u0 & 0xFFFF0000u);
  float l1 = f1 - __uint_as_float(u1 & 0xFFFF0000u);
  lo = __builtin_amdgcn_perm(__float_as_uint(l1), __float_as_uint(l0), 0x07060302u);
}

// raw barriers: no vmcnt drain (prefetched global loads ride across);
// lgkm0 variant publishes ds_writes before the barrier.
__device__ __forceinline__ void fence_barrier() {
  asm volatile("" ::: "memory");
  __builtin_amdgcn_s_barrier();
  asm volatile("" ::: "memory");
}
__device__ __forceinline__ void lgkm0_barrier() {
  asm volatile("s_waitcnt lgkmcnt(0)" ::: "memory");
  __builtin_amdgcn_s_barrier();
  asm volatile("" ::: "memory");
}

// ---------------- weight pre-convert/transpose (runs once, tiny) ----------------
__global__ __launch_bounds__(256) void k_prepw(
    const float* __restrict__ Wdes, const float* __restrict__ Wtw,
    const float* __restrict__ Wnum, const float* __restrict__ Wcat,
    const float* __restrict__ Win,  const float* __restrict__ root1,
    const float* __restrict__ rel1, const float* __restrict__ root2,
    const float* __restrict__ rel2, const float* __restrict__ Wcls,
    unsigned short* __restrict__ Wt) {
  int id = blockIdx.x * 256 + threadIdx.x;
  if (id >= WT_SITES) return;
  const float* src; int K, Kpad, dhi, dlo, local;
  if (id < 98304)       { src=Wdes;        K=768; Kpad=768; dhi=OFF_DES_HI;       dlo=OFF_DES_LO;       local=id; }
  else if (id < 196608) { src=Wtw;         K=768; Kpad=768; dhi=OFF_TW_HI;        dlo=OFF_TW_LO;        local=id-98304; }
  else if (id < 200704) { src=Wnum;        K=6;   Kpad=32;  dhi=OFF_NUM_HI;       dlo=OFF_NUM_LO;       local=id-196608; }
  else if (id < 204800) { src=Wcat;        K=11;  Kpad=32;  dhi=OFF_CAT_HI;       dlo=OFF_CAT_LO;       local=id-200704; }
  else if (id < 270336) { src=Win;         K=512; Kpad=512; dhi=OFF_WIN_HI;       dlo=OFF_WIN_LO;       local=id-204800; }
  else if (id < 286720) { src=root1;       K=128; Kpad=128; dhi=OFF_L1_HI;        dlo=OFF_L1_LO;        local=id-270336; }
  else if (id < 303104) { src=rel1;        K=128; Kpad=128; dhi=OFF_L1_HI+16384;  dlo=OFF_L1_LO+16384;  local=id-286720; }
  else if (id < 319488) { src=rel1+16384;  K=128; Kpad=128; dhi=OFF_L1_HI+32768;  dlo=OFF_L1_LO+32768;  local=id-303104; }
  else if (id < 335872) { src=root2;       K=128; Kpad=128; dhi=OFF_L2_HI;        dlo=OFF_L2_LO;        local=id-319488; }
  else if (id < 352256) { src=rel2;        K=128; Kpad=128; dhi=OFF_L2_HI+16384;  dlo=OFF_L2_LO+16384;  local=id-335872; }
  else if (id < 368640) { src=rel2+16384;  K=128; Kpad=128; dhi=OFF_L2_HI+32768;  dlo=OFF_L2_LO+32768;  local=id-352256; }
  else                  { src=Wcls;        K=128; Kpad=128; dhi=OFF_CLS_HI;       dlo=OFF_CLS_LO;       local=id-368640; }
  int col = local / Kpad;
  int k = local - col * Kpad;
  float v = (k < K) ? src[(size_t)k * 128 + col] : 0.f;
  unsigned int u = __float_as_uint(v);
  float lo = v - __uint_as_float(u & 0xFFFF0000u);
  Wt[dhi + col * Kpad + k] = (unsigned short)(u >> 16);
  Wt[dlo + col * Kpad + k] = (unsigned short)(__float_as_uint(lo) >> 16);
}

// ---------------- CSR build ----------------
__global__ __launch_bounds__(256) void k_count(const int* __restrict__ ei,
                                               const int* __restrict__ et,
                                               int* __restrict__ cnt2) {
  int e = blockIdx.x * 256 + threadIdx.x;
  if (e >= EE) return;
  atomicAdd(&cnt2[et[e] * NN + ei[EE + e]], 1);
}

__global__ __launch_bounds__(256) void k_scan1(const int* __restrict__ cnt2,
                                               int* __restrict__ row_ptr,
                                               int* __restrict__ bsum) {
  __shared__ int sums[256];
  int t = threadIdx.x;
  int base = blockIdx.x * 1024 + t * 4;
  int v[4]; int s = 0;
#pragma unroll
  for (int j = 0; j < 4; ++j) {
    int idx = base + j;
    v[j] = (idx < NN) ? (cnt2[idx] + cnt2[NN + idx]) : 0;
    s += v[j];
  }
  sums[t] = s;
  __syncthreads();
  for (int d = 1; d < 256; d <<= 1) {
    int val = (t >= d) ? sums[t - d] : 0;
    __syncthreads();
    sums[t] += val;
    __syncthreads();
  }
  int excl = sums[t] - s;
  if (t == 255) bsum[blockIdx.x] = sums[t];
  int run = excl;
#pragma unroll
  for (int j = 0; j < 4; ++j) {
    int idx = base + j;
    if (idx < NN) row_ptr[idx] = run;
    run += v[j];
  }
}

__global__ __launch_bounds__(128) void k_scan2(int* __restrict__ bsum, int nb) {
  __shared__ int s[128];
  int t = threadIdx.x;
  int v = (t < nb) ? bsum[t] : 0;
  s[t] = v;
  __syncthreads();
  for (int d = 1; d < 128; d <<= 1) {
    int val = (t >= d) ? s[t - d] : 0;
    __syncthreads();
    s[t] += val;
    __syncthreads();
  }
  if (t < nb) bsum[t] = s[t] - v;
}

__global__ __launch_bounds__(256) void k_scan3(int* __restrict__ row_ptr,
                                               const int* __restrict__ bsum) {
  int idx = blockIdx.x * 256 + threadIdx.x;
  if (idx < NN) row_ptr[idx] += bsum[idx >> 10];
  if (idx == NN) row_ptr[NN] = EE;
}

__global__ __launch_bounds__(256) void k_fill(const int* __restrict__ ei,
                                              const int* __restrict__ et,
                                              const int* __restrict__ row_ptr,
                                              int* __restrict__ fillpos,
                                              int* __restrict__ entries) {
  int e = blockIdx.x * 256 + threadIdx.x;
  if (e >= EE) return;
  int src = ei[e];
  int dst = ei[EE + e];
  int r = et[e];
  int pos = atomicAdd(&fillpos[dst], 1);
  entries[row_ptr[dst] + pos] = src | (r << 20);
}

// ---------------- fused projection (MFMA, split-bf16, pipelined, raw barriers) ----
// 64 nodes/block, 4 waves, wave = 16 rows x 128 cols, 3 blocks/CU (R3 shape,
// 84 VGPR no-spill). X pipeline depth-3; raw barriers (no vmcnt drain).
__global__ __launch_bounds__(256, 3) void k_proj2(
    const float* __restrict__ x,
    const float* __restrict__ bdes, const float* __restrict__ btw,
    const float* __restrict__ bnum, const float* __restrict__ bcat,
    const float* __restrict__ bin,  const float* __restrict__ pa,
    const unsigned short* __restrict__ Wt, float* __restrict__ h0) {
  __shared__ unsigned short bt_hi[128 * 32], bt_lo[128 * 32];   // 8KB + 8KB
  __shared__ unsigned short z_hi[64 * 128], z_lo[64 * 128];     // 16KB + 16KB

  const int t = threadIdx.x;
  const int node0 = blockIdx.x * 64;
  const int w = t >> 6, lane = t & 63;
  const int li = lane & 15, lg = lane >> 4;

  // B-staging constants (loop-invariant per thread)
  const int cr0 = t >> 2, c0 = t & 3;
  const int cr1 = cr0 + 64;
  const unsigned stb0 = cr0 * 64 + ((c0 ^ ((cr0 >> 1) & 3)) << 4);
  const unsigned stb1 = cr1 * 64 + ((c0 ^ ((cr1 >> 1) & 3)) << 4);

  // one A-row per (wave, li)
  const int rowA = w * 16 + li;
  int nodeA = node0 + rowA;
  int ndA = nodeA < NN ? nodeA : NN - 1;
  const float* xrow = x + (size_t)ndA * XDIM;

#define STORE_BT(SH0, SL0, SH1, SL1)              \
  do {                                            \
    *(uint4*)((char*)bt_hi + stb0) = (SH0);       \
    *(uint4*)((char*)bt_lo + stb0) = (SL0);       \
    *(uint4*)((char*)bt_hi + stb1) = (SH1);       \
    *(uint4*)((char*)bt_lo + stb1) = (SL1);       \
  } while (0)

#define CVT_A2(FA, FB, AH, AL)                                                   \
  do {                                                                           \
    cvt_pair((FA)[0], (FA)[1], (AH).u[0], (AL).u[0]);                            \
    cvt_pair((FA)[2], (FA)[3], (AH).u[1], (AL).u[1]);                            \
    cvt_pair((FB)[0], (FB)[1], (AH).u[2], (AL).u[2]);                            \
    cvt_pair((FB)[2], (FB)[3], (AH).u[3], (AL).u[3]);                            \
  } while (0)

#define MFMA8(AH, AL, ACC)                                                       \
  do {                                                                           \
    _Pragma("unroll")                                                            \
    for (int ct_ = 0; ct_ < 8; ++ct_) {                                          \
      int colrow_ = ct_ * 16 + li;                                               \
      int byte_ = colrow_ * 64 + (lg << 4);                                      \
      byte_ ^= ((colrow_ >> 1) & 3) << 4;                                        \
      Frag bh_, bl_;                                                             \
      bh_.v = *(const uint4*)((char*)bt_hi + byte_);                             \
      bl_.v = *(const uint4*)((char*)bt_lo + byte_);                             \
      (ACC)[ct_] = __builtin_amdgcn_mfma_f32_16x16x32_bf16((AH).s, bl_.s, (ACC)[ct_], 0, 0, 0); \
      (ACC)[ct_] = __builtin_amdgcn_mfma_f32_16x16x32_bf16((AL).s, bh_.s, (ACC)[ct_], 0, 0, 0); \
      (ACC)[ct_] = __builtin_amdgcn_mfma_f32_16x16x32_bf16((AH).s, bh_.s, (ACC)[ct_], 0, 0, 0); \
    }                                                                            \
  } while (0)

// one K-tile of phase A: store W tile (cur), barrier, convert X, prefetch
// W(T+1, into next buf) + X(T+3, dwordx4 pair back into same X bufs), MFMA, barrier.
#define TILE(WC0, WC1, WC2, WC3, WN0, WN1, WN2, WN3, XA, XB, T)                  \
  do {                                                                           \
    STORE_BT(WC0, WC1, WC2, WC3);                                                \
    lgkm0_barrier();                                                             \
    Frag ah_, al_;                                                               \
    CVT_A2(XA, XB, ah_, al_);                                                    \
    {                                                                            \
      const int kw_ = ((T) + 1) * 32;                                            \
      WN0 = *(const uint4*)(ph0 + kw_); WN1 = *(const uint4*)(pl0 + kw_);        \
      WN2 = *(const uint4*)(ph1 + kw_); WN3 = *(const uint4*)(pl1 + kw_);        \
      int kx_ = (T) + 3; if (kx_ > 23) kx_ = 23; kx_ *= 32;                      \
      XA = *(const f32x4u*)(xr + kx_);                                           \
      XB = *(const f32x4u*)(xr + kx_ + 4);                                       \
    }                                                                            \
    MFMA8(ah_, al_, zacc);                                                       \
    fence_barrier();                                                             \
  } while (0)

#define MFMA_B(KT)                                                               \
  do {                                                                           \
    Frag ah_, al_;                                                               \
    int byte_ = rowA * 256 + (((KT) * 32 + lg * 8) << 1);                        \
    byte_ ^= (rowA & 7) << 4;                                                    \
    ah_.v = *(const uint4*)((char*)z_hi + byte_);                                \
    al_.v = *(const uint4*)((char*)z_lo + byte_);                                \
    MFMA8(ah_, al_, hacc);                                                       \
  } while (0)

#define Z_EPI(ZACC, BIASP)                                                       \
  do {                                                                           \
    _Pragma("unroll")                                                            \
    for (int ct_ = 0; ct_ < 8; ++ct_) {                                          \
      int col_ = ct_ * 16 + li;                                                  \
      float bv_ = (BIASP)[col_];                                                 \
      _Pragma("unroll")                                                          \
      for (int r_ = 0; r_ < 4; ++r_) {                                           \
        float v_ = (ZACC)[ct_][r_] + bv_;                                        \
        v_ = v_ >= 0.f ? v_ : 0.01f * v_;                                        \
        int row_ = w * 16 + lg * 4 + r_;                                         \
        int byte_ = row_ * 256 + col_ * 2;                                       \
        byte_ ^= (row_ & 7) << 4;                                                \
        unsigned int u_ = __float_as_uint(v_);                                   \
        *(unsigned short*)((char*)z_hi + byte_) = (unsigned short)(u_ >> 16);    \
        float lo_ = v_ - __uint_as_float(u_ & 0xFFFF0000u);                      \
        *(unsigned short*)((char*)z_lo + byte_) = (unsigned short)(__float_as_uint(lo_) >> 16); \
      }                                                                          \
    }                                                                            \
  } while (0)

// phase B: hacc += z @ Win[SLICE*128 .. +127], 4 K-tiles, fully unrolled,
// 1-deep prefetch of the next Win tile.
#define PHASE_B(SLICE)                                                           \
  do {                                                                           \
    const unsigned short* qh0_ = Wt + OFF_WIN_HI + cr0 * 512 + (SLICE) * 128 + c0 * 8; \
    const unsigned short* ql0_ = Wt + OFF_WIN_LO + cr0 * 512 + (SLICE) * 128 + c0 * 8; \
    const unsigned short* qh1_ = Wt + OFF_WIN_HI + cr1 * 512 + (SLICE) * 128 + c0 * 8; \
    const unsigned short* ql1_ = Wt + OFF_WIN_LO + cr1 * 512 + (SLICE) * 128 + c0 * 8; \
    uint4 wA0_ = *(const uint4*)(qh0_), wA1_ = *(const uint4*)(ql0_);            \
    uint4 wA2_ = *(const uint4*)(qh1_), wA3_ = *(const uint4*)(ql1_);            \
    uint4 wB0_, wB1_, wB2_, wB3_;                                                \
    STORE_BT(wA0_, wA1_, wA2_, wA3_);                                            \
    lgkm0_barrier();                                                             \
    wB0_ = *(const uint4*)(qh0_ + 32); wB1_ = *(const uint4*)(ql0_ + 32);        \
    wB2_ = *(const uint4*)(qh1_ + 32); wB3_ = *(const uint4*)(ql1_ + 32);        \
    MFMA_B(0);                                                                   \
    fence_barrier();                                                             \
    STORE_BT(wB0_, wB1_, wB2_, wB3_);                                            \
    lgkm0_barrier();                                                             \
    wA0_ = *(const uint4*)(qh0_ + 64); wA1_ = *(const uint4*)(ql0_ + 64);        \
    wA2_ = *(const uint4*)(qh1_ + 64); wA3_ = *(const uint4*)(ql1_ + 64);        \
    MFMA_B(1);                                                                   \
    fence_barrier();                                                             \
    STORE_BT(wA0_, wA1_, wA2_, wA3_);                                            \
    lgkm0_barrier();                                                             \
    wB0_ = *(const uint4*)(qh0_ + 96); wB1_ = *(const uint4*)(ql0_ + 96);        \
    wB2_ = *(const uint4*)(qh1_ + 96); wB3_ = *(const uint4*)(ql1_ + 96);        \
    MFMA_B(2);                                                                   \
    fence_barrier();                                                             \
    STORE_BT(wB0_, wB1_, wB2_, wB3_);                                            \
    lgkm0_barrier();                                                             \
    MFMA_B(3);                                                                   \
    fence_barrier();                                                             \
  } while (0)

  f32x4 hacc[8];
#pragma unroll
  for (int b = 0; b < 8; ++b) hacc[b] = (f32x4)0.f;

  // ---- big segments: des (s=0), tweet (s=1); K=768 = 24 K-tiles, pipelined ----
#pragma unroll
  for (int s = 0; s < 2; ++s) {
    const int off = (s == 0) ? 785 : 6;
    const unsigned short* wh = Wt + (s == 0 ? OFF_DES_HI : OFF_TW_HI);
    const unsigned short* wl = Wt + (s == 0 ? OFF_DES_LO : OFF_TW_LO);
    const float* bias = (s == 0) ? bdes : btw;

    const float* xr = xrow + off + lg * 8;
    const unsigned short* ph0 = wh + cr0 * 768 + c0 * 8;
    const unsigned short* pl0 = wl + cr0 * 768 + c0 * 8;
    const unsigned short* ph1 = wh + cr1 * 768 + c0 * 8;
    const unsigned short* pl1 = wl + cr1 * 768 + c0 * 8;

    f32x4 zacc[8];
#pragma unroll
    for (int b = 0; b < 8; ++b) zacc[b] = (f32x4)0.f;

    uint4 WA0, WA1, WA2, WA3, WB0, WB1, WB2, WB3;
    f32x4u X0a, X0b, X1a, X1b, X2a, X2b;

    // prologue: W tile 0, X tiles 0..2 (dwordx4 pairs)
    WA0 = *(const uint4*)(ph0); WA1 = *(const uint4*)(pl0);
    WA2 = *(const uint4*)(ph1); WA3 = *(const uint4*)(pl1);
    X0a = *(const f32x4u*)(xr);      X0b = *(const f32x4u*)(xr + 4);
    X1a = *(const f32x4u*)(xr + 32); X1b = *(const f32x4u*)(xr + 36);
    X2a = *(const f32x4u*)(xr + 64); X2b = *(const f32x4u*)(xr + 68);

    for (int base = 0; base < 24; base += 6) {
      TILE(WA0, WA1, WA2, WA3, WB0, WB1, WB2, WB3, X0a, X0b, base + 0);
      TILE(WB0, WB1, WB2, WB3, WA0, WA1, WA2, WA3, X1a, X1b, base + 1);
      TILE(WA0, WA1, WA2, WA3, WB0, WB1, WB2, WB3, X2a, X2b, base + 2);
      TILE(WB0, WB1, WB2, WB3, WA0, WA1, WA2, WA3, X0a, X0b, base + 3);
      TILE(WA0, WA1, WA2, WA3, WB0, WB1, WB2, WB3, X1a, X1b, base + 4);
      TILE(WB0, WB1, WB2, WB3, WA0, WA1, WA2, WA3, X2a, X2b, base + 5);
    }
    Z_EPI(zacc, bias);   // z is wave-private: no barrier needed for z itself
    PHASE_B(s);
  }

  // ---- small segments: num (K=6), cat (K=11); single padded K-tile each ----
#pragma unroll
  for (int u = 0; u < 2; ++u) {
    const int offu = (u == 0) ? 0 : 774;
    const int Ksu = (u == 0) ? 6 : 11;
    const unsigned short* wh = Wt + (u == 0 ? OFF_NUM_HI : OFF_CAT_HI);
    const unsigned short* wl = Wt + (u == 0 ? OFF_NUM_LO : OFF_CAT_LO);
    const float* biasu = (u == 0) ? bnum : bcat;
    const float* xr = xrow + offu + lg * 8;

    uint4 s0 = *(const uint4*)(wh + cr0 * 32 + c0 * 8);
    uint4 s1 = *(const uint4*)(wl + cr0 * 32 + c0 * 8);
    uint4 s2 = *(const uint4*)(wh + cr1 * 32 + c0 * 8);
    uint4 s3 = *(const uint4*)(wl + cr1 * 32 + c0 * 8);
    f32x4u fa = *(const f32x4u*)(xr);
    f32x4u fb = *(const f32x4u*)(xr + 4);
#pragma unroll
    for (int j = 0; j < 4; ++j) {
      if (lg * 8 + j >= Ksu) fa[j] = 0.f;
      if (lg * 8 + 4 + j >= Ksu) fb[j] = 0.f;
    }

    f32x4 zacc[8];
#pragma unroll
    for (int b = 0; b < 8; ++b) zacc[b] = (f32x4)0.f;

    STORE_BT(s0, s1, s2, s3);
    lgkm0_barrier();
    {
      Frag ah_, al_;
      CVT_A2(fa, fb, ah_, al_);
      MFMA8(ah_, al_, zacc);
    }
    fence_barrier();
    Z_EPI(zacc, biasu);
    PHASE_B(u + 2);
  }

  // epilogue: + b_in, PReLU, store
#pragma unroll
  for (int ct = 0; ct < 8; ++ct) {
    int col = ct * 16 + li;
    float bi = bin[col];
    float p = pa[col];
#pragma unroll
    for (int r = 0; r < 4; ++r) {
      int node = node0 + w * 16 + lg * 4 + r;
      if (node < NN) {
        float v = hacc[ct][r] + bi;
        v = v >= 0.f ? v : p * v;
        h0[(size_t)node * HD + col] = v;
      }
    }
  }

#undef TILE
#undef MFMA_B
#undef Z_EPI
#undef PHASE_B
}

// ---------------- neighbor-mean gather: aggH_r[dst] = mean_{src in N_r} h[src] --
// Linearity: mean(h[src] @ rel) == mean(h[src]) @ rel, so gather raw h rows
// (51MB working set, L3-resident) instead of materialized messages.
__global__ __launch_bounds__(256) void k_gather(
    const float* __restrict__ h, float* __restrict__ aggH,
    const int* __restrict__ row_ptr, const int* __restrict__ cnt2,
    const int* __restrict__ entries) {
  int i = blockIdx.x * 4 + (threadIdx.x >> 6);
  int l = threadIdx.x & 63;
  if (i >= NN) return;
  int rs = row_ptr[i], re = row_ptr[i + 1];
  int c0 = cnt2[i], c1 = cnt2[NN + i];
  float inv0 = 1.f / (float)(c0 > 0 ? c0 : 1);
  float inv1 = 1.f / (float)(c1 > 0 ? c1 : 1);
  float a0 = 0, a1 = 0, b0 = 0, b1 = 0;
  int e = rs;
  for (; e + 1 < re; e += 2) {
    int ent0 = entries[e], ent1 = entries[e + 1];
    const float2* r0 = (const float2*)(h + (size_t)(ent0 & 0xFFFFF) * HD);
    const float2* r1 = (const float2*)(h + (size_t)(ent1 & 0xFFFFF) * HD);
    float2 v0 = r0[l], v1 = r1[l];
    if (ent0 >> 20) { b0 += v0.x; b1 += v0.y; } else { a0 += v0.x; a1 += v0.y; }
    if (ent1 >> 20) { b0 += v1.x; b1 += v1.y; } else { a0 += v1.x; a1 += v1.y; }
  }
  if (e < re) {
    int ent = entries[e];
    const float2* r0 = (const float2*)(h + (size_t)(ent & 0xFFFFF) * HD);
    float2 v0 = r0[l];
    if (ent >> 20) { b0 += v0.x; b1 += v0.y; } else { a0 += v0.x; a1 += v0.y; }
  }
  float2* p0 = (float2*)(aggH + (size_t)i * HD);
  float2* p1 = (float2*)(aggH + (size_t)NN * HD + (size_t)i * HD);
  p0[l] = make_float2(a0 * inv0, a1 * inv0);
  p1[l] = make_float2(b0 * inv1, b1 * inv1);
}

// ---------------- fused layer GEMM: out = [h|aggH0|aggH1] @ [root;rel0;rel1] + b --
// Single K=384 GEMM (linearity fusion). 64 rows/block, 4 waves x (16 rows x
// 128 cols), 4 blocks/CU (16KB LDS). Proven proj phase-A skeleton: ping-pong W
// staging, depth-3 A prefetch, raw barriers. No mh materialization, no io RMW.
__global__ __launch_bounds__(256, 4) void k_rgemm2(
    const float* __restrict__ hin, const float* __restrict__ aggH,
    const unsigned short* __restrict__ wl_hi, const unsigned short* __restrict__ wl_lo,
    const float* __restrict__ bias, float* __restrict__ outp) {
  __shared__ unsigned short bt_hi[128 * 32], bt_lo[128 * 32];   // 8KB + 8KB

  const int t = threadIdx.x;
  const int node0 = blockIdx.x * 64;
  const int w = t >> 6, lane = t & 63;
  const int li = lane & 15, lg = lane >> 4;

  const int cr0 = t >> 2, c0 = t & 3;
  const int cr1 = cr0 + 64;
  const unsigned stb0 = cr0 * 64 + ((c0 ^ ((cr0 >> 1) & 3)) << 4);
  const unsigned stb1 = cr1 * 64 + ((c0 ^ ((cr1 >> 1) & 3)) << 4);

  const int rowA = w * 16 + li;
  int nodeA = node0 + rowA;
  int ndA = nodeA < NN ? nodeA : NN - 1;
  const float* a0p = hin + (size_t)ndA * HD + lg * 8;
  const float* a1p = aggH + (size_t)ndA * HD + lg * 8;
  const float* a2p = aggH + (size_t)NN * HD + (size_t)ndA * HD + lg * 8;

// A source/offset for stacked K: kt 0-3 -> h, 4-7 -> aggH0, 8-11 -> aggH1
#define APTR(KT) ((KT) < 4 ? a0p : (KT) < 8 ? a1p : a2p)
#define AOFF(KT) (((KT) & 3) * 32)
// W site pointers: sub-region (kt>>2)*16384, within-region k = (kt&3)*32
#define W2H(KT, CR) (wl_hi + ((KT) >> 2) * 16384 + (CR) * 128 + ((KT) & 3) * 32 + c0 * 8)
#define W2L(KT, CR) (wl_lo + ((KT) >> 2) * 16384 + (CR) * 128 + ((KT) & 3) * 32 + c0 * 8)

#define TILE2(WC0, WC1, WC2, WC3, WN0, WN1, WN2, WN3, XA, XB, T)                 \
  do {                                                                           \
    STORE_BT(WC0, WC1, WC2, WC3);                                                \
    lgkm0_barrier();                                                             \
    Frag ah_, al_;                                                               \
    CVT_A2(XA, XB, ah_, al_);                                                    \
    {                                                                            \
      int kn_ = (T) + 1; if (kn_ > 11) kn_ = 11;                                 \
      WN0 = *(const uint4*)W2H(kn_, cr0); WN1 = *(const uint4*)W2L(kn_, cr0);    \
      WN2 = *(const uint4*)W2H(kn_, cr1); WN3 = *(const uint4*)W2L(kn_, cr1);    \
      int kx_ = (T) + 3; if (kx_ > 11) kx_ = 11;                                 \
      const float* ap_ = (kx_ < 4) ? a0p : (kx_ < 8) ? a1p : a2p;                \
      XA = *(const f32x4u*)(ap_ + (kx_ & 3) * 32);                               \
      XB = *(const f32x4u*)(ap_ + (kx_ & 3) * 32 + 4);                           \
    }                                                                            \
    MFMA8(ah_, al_, acc);                                                        \
    fence_barrier();                                                             \
  } while (0)

  f32x4 acc[8];
#pragma unroll
  for (int b = 0; b < 8; ++b) acc[b] = (f32x4)0.f;

  uint4 WA0, WA1, WA2, WA3, WB0, WB1, WB2, WB3;
  f32x4u X0a, X0b, X1a, X1b, X2a, X2b;

  // prologue: W tile 0, A tiles 0..2
  WA0 = *(const uint4*)W2H(0, cr0); WA1 = *(const uint4*)W2L(0, cr0);
  WA2 = *(const uint4*)W2H(0, cr1); WA3 = *(const uint4*)W2L(0, cr1);
  X0a = *(const f32x4u*)(a0p);      X0b = *(const f32x4u*)(a0p + 4);
  X1a = *(const f32x4u*)(a0p + 32); X1b = *(const f32x4u*)(a0p + 36);
  X2a = *(const f32x4u*)(a0p + 64); X2b = *(const f32x4u*)(a0p + 68);

  TILE2(WA0, WA1, WA2, WA3, WB0, WB1, WB2, WB3, X0a, X0b, 0);
  TILE2(WB0, WB1, WB2, WB3, WA0, WA1, WA2, WA3, X1a, X1b, 1);
  TILE2(WA0, WA1, WA2, WA3, WB0, WB1, WB2, WB3, X2a, X2b, 2);
  TILE2(WB0, WB1, WB2, WB3, WA0, WA1, WA2, WA3, X0a, X0b, 3);
  TILE2(WA0, WA1, WA2, WA3, WB0, WB1, WB2, WB3, X1a, X1b, 4);
  TILE2(WB0, WB1, WB2, WB3, WA0, WA1, WA2, WA3, X2a, X2b, 5);
  TILE2(WA0, WA1, WA2, WA3, WB0, WB1, WB2, WB3, X0a, X0b, 6);
  TILE2(WB0, WB1, WB2, WB3, WA0, WA1, WA2, WA3, X1a, X1b, 7);
  TILE2(WA0, WA1, WA2, WA3, WB0, WB1, WB2, WB3, X2a, X2b, 8);
  TILE2(WB0, WB1, WB2, WB3, WA0, WA1, WA2, WA3, X0a, X0b, 9);
  TILE2(WA0, WA1, WA2, WA3, WB0, WB1, WB2, WB3, X1a, X1b, 10);
  TILE2(WB0, WB1, WB2, WB3, WA0, WA1, WA2, WA3, X2a, X2b, 11);

  // epilogue: + bias, store
#pragma unroll
  for (int ct = 0; ct < 8; ++ct) {
    int col = ct * 16 + li;
    float bv = bias[col];
#pragma unroll
    for (int r = 0; r < 4; ++r) {
      int node = node0 + w * 16 + lg * 4 + r;
      if (node < NN) outp[(size_t)node * HD + col] = acc[ct][r] + bv;
    }
  }

#undef APTR
#undef AOFF
#undef W2H
#undef W2L
#undef TILE2
}

// ---------------- final linear (MFMA, in-place) ----------------
// 64 rows/block, 4 waves in 2x2: wave = 32 rows x 64 cols.
// Raw barriers + 1-deep ping-pong prefetch of the A (io) row fragments.
__global__ __launch_bounds__(256, 4) void k_cls2(
    float* __restrict__ io, const unsigned short* __restrict__ Wt,
    const float* __restrict__ b) {
  __shared__ unsigned short bt_hi[128 * 32], bt_lo[128 * 32];  // 8KB + 8KB

  const int t = threadIdx.x;
  const int node0 = blockIdx.x * 64;
  const int w = t >> 6, lane = t & 63;
  const int li = lane & 15, lg = lane >> 4;
  const int wr = w >> 1, wc = w & 1;

  int nodeA0 = node0 + wr * 32 + li; int nd0 = nodeA0 < NN ? nodeA0 : NN - 1;
  int nodeA1 = nodeA0 + 16;          int nd1 = nodeA1 < NN ? nodeA1 : NN - 1;
  const float* ap0 = io + (size_t)nd0 * HD + lg * 8;
  const float* ap1 = io + (size_t)nd1 * HD + lg * 8;

  f32x4 acc[2][4];
#pragma unroll
  for (int a = 0; a < 2; ++a)
#pragma unroll
    for (int bq = 0; bq < 4; ++bq) acc[a][bq] = (f32x4)0.f;

#define CL_STAGE(KT)                                                             \
  do {                                                                           \
    uint4 sh_[2], sl_[2];                                                        \
    _Pragma("unroll")                                                            \
    for (int j_ = 0; j_ < 2; ++j_) {                                             \
      int cid_ = t + j_ * 256;                                                   \
      int cr_ = cid_ >> 2, c_ = cid_ & 3;                                        \
      sh_[j_] = *(const uint4*)(Wt + OFF_CLS_HI + cr_ * 128 + (KT) * 32 + c_ * 8); \
      sl_[j_] = *(const uint4*)(Wt + OFF_CLS_LO + cr_ * 128 + (KT) * 32 + c_ * 8); \
    }                                                                            \
    _Pragma("unroll")                                                            \
    for (int j_ = 0; j_ < 2; ++j_) {                                             \
      int cid_ = t + j_ * 256;                                                   \
      int cr_ = cid_ >> 2, c_ = cid_ & 3;                                        \
      unsigned b_ = cr_ * 64 + ((c_ ^ ((cr_ >> 1) & 3)) << 4);                   \
      *(uint4*)((char*)bt_hi + b_) = sh_[j_];                                    \
      *(uint4*)((char*)bt_lo + b_) = sl_[j_];                                    \
    }                                                                            \
  } while (0)

#define CL_LOADA(KT, F)                                                          \
  do {                                                                           \
    (F)[0][0] = *(const f32x4u*)(ap0 + (KT) * 32);                               \
    (F)[0][1] = *(const f32x4u*)(ap0 + (KT) * 32 + 4);                           \
    (F)[1][0] = *(const f32x4u*)(ap1 + (KT) * 32);                               \
    (F)[1][1] = *(const f32x4u*)(ap1 + (KT) * 32 + 4);                           \
  } while (0)

#define CL_MFMA(F)                                                               \
  do {                                                                           \
    Frag ah_[2], al_[2];                                                         \
    _Pragma("unroll")                                                            \
    for (int sub_ = 0; sub_ < 2; ++sub_) {                                       \
      cvt_pair((F)[sub_][0][0], (F)[sub_][0][1], ah_[sub_].u[0], al_[sub_].u[0]); \
      cvt_pair((F)[sub_][0][2], (F)[sub_][0][3], ah_[sub_].u[1], al_[sub_].u[1]); \
      cvt_pair((F)[sub_][1][0], (F)[sub_][1][1], ah_[sub_].u[2], al_[sub_].u[2]); \
      cvt_pair((F)[sub_][1][2], (F)[sub_][1][3], ah_[sub_].u[3], al_[sub_].u[3]); \
    }                                                                            \
    _Pragma("unroll")                                                            \
    for (int ct_ = 0; ct_ < 4; ++ct_) {                                          \
      int colrow_ = wc * 64 + ct_ * 16 + li;                                     \
      int byte_ = colrow_ * 64 + (lg << 4);                                      \
      byte_ ^= ((colrow_ >> 1) & 3) << 4;                                        \
      Frag bh_, bl_;                                                             \
      bh_.v = *(const uint4*)((char*)bt_hi + byte_);                             \
      bl_.v = *(const uint4*)((char*)bt_lo + byte_);                             \
      _Pragma("unroll")                                                          \
      for (int sub_ = 0; sub_ < 2; ++sub_) {                                     \
        acc[sub_][ct_] = __builtin_amdgcn_mfma_f32_16x16x32_bf16(ah_[sub_].s, bl_.s, acc[sub_][ct_], 0, 0, 0); \
        acc[sub_][ct_] = __builtin_amdgcn_mfma_f32_16x16x32_bf16(al_[sub_].s, bh_.s, acc[sub_][ct_], 0, 0, 0); \
        acc[sub_][ct_] = __builtin_amdgcn_mfma_f32_16x16x32_bf16(ah_[sub_].s, bh_.s, acc[sub_][ct_], 0, 0, 0); \
      }                                                                          \
    }                                                                            \
  } while (0)

  f32x4u fA[2][2], fB[2][2];
  CL_LOADA(0, fA);

  CL_STAGE(0);
  CL_LOADA(1, fB);
  lgkm0_barrier();
  CL_MFMA(fA);
  fence_barrier();

  CL_STAGE(1);
  CL_LOADA(2, fA);
  lgkm0_barrier();
  CL_MFMA(fB);
  fence_barrier();

  CL_STAGE(2);
  CL_LOADA(3, fB);
  lgkm0_barrier();
  CL_MFMA(fA);
  fence_barrier();

  CL_STAGE(3);
  lgkm0_barrier();
  CL_MFMA(fB);

#undef CL_STAGE
#undef CL_LOADA
#undef CL_MFMA

  __syncthreads();  // all A-reads of this block's rows done before in-place writes
#pragma unroll
  for (int ct = 0; ct < 4; ++ct) {
    int col = wc * 64 + ct * 16 + li;
    float bv = b[col];
#pragma unroll
    for (int sub = 0; sub < 2; ++sub) {
#pragma unroll
      for (int r = 0; r < 4; ++r) {
        int node = node0 + wr * 32 + sub * 16 + lg * 4 + r;
        if (node < NN) io[(size_t)node * HD + col] = acc[sub][ct][r] + bv;
      }
    }
  }
}

extern "C" void kernel_launch(void* const* d_in, const int* in_sizes, int n_in,
                              void* d_out, int out_size, void* d_ws, size_t ws_size,
                              hipStream_t stream) {
  const float* x    = (const float*)d_in[0];
  const int* ei     = (const int*)d_in[1];
  const int* et     = (const int*)d_in[2];
  const float* Wdes = (const float*)d_in[3];
  const float* bdes = (const float*)d_in[4];
  const float* Wtw  = (const float*)d_in[5];
  const float* btw  = (const float*)d_in[6];
  const float* Wnum = (const float*)d_in[7];
  const float* bnum = (const float*)d_in[8];
  const float* Wcat = (const float*)d_in[9];
  const float* bcat = (const float*)d_in[10];
  const float* Win  = (const float*)d_in[11];
  const float* bin  = (const float*)d_in[12];
  const float* pa   = (const float*)d_in[13];
  const float* root1 = (const float*)d_in[14];
  const float* rel1  = (const float*)d_in[15];
  const float* bias1 = (const float*)d_in[16];
  const float* root2 = (const float*)d_in[17];
  const float* rel2  = (const float*)d_in[18];
  const float* bias2 = (const float*)d_in[19];
  const float* Wcls  = (const float*)d_in[20];
  const float* bcls  = (const float*)d_in[21];
  float* out = (float*)d_out;

  char* p = (char*)d_ws;
  float* aggH = (float*)p;    p += (size_t)2 * NN * HD * 4;   // 102.4 MB
  float* hB = (float*)p;      p += (size_t)NN * HD * 4;       // 51.2 MB
  int* row_ptr = (int*)p;     p += ((size_t)NN + 4) * 4;
  int* cnt2 = (int*)p;        p += (size_t)2 * NN * 4;
  int* fillpos = (int*)p;     p += (size_t)NN * 4;
  int* entries = (int*)p;     p += (size_t)EE * 4;
  int* bsum = (int*)p;        p += 512;
  unsigned short* Wt = (unsigned short*)p;  p += (size_t)WT_SITES * 2 * 2;

  // weight pre-convert (independent of everything else)
  k_prepw<<<(WT_SITES + 255) / 256, 256, 0, stream>>>(
      Wdes, Wtw, Wnum, Wcat, Win, root1, rel1, root2, rel2, Wcls, Wt);

  // CSR build
  hipMemsetAsync(cnt2, 0, (size_t)3 * NN * 4, stream);  // cnt2 + fillpos
  k_count<<<EE / 256, 256, 0, stream>>>(ei, et, cnt2);
  int nb = (NN + 1023) / 1024;
  k_scan1<<<nb, 256, 0, stream>>>(cnt2, row_ptr, bsum);
  k_scan2<<<1, 128, 0, stream>>>(bsum, nb);
  k_scan3<<<(NN + 1 + 255) / 256, 256, 0, stream>>>(row_ptr, bsum);
  k_fill<<<EE / 256, 256, 0, stream>>>(ei, et, row_ptr, fillpos, entries);

  const int nblk = (NN + 63) / 64;  // 1563
  // h0 -> d_out
  k_proj2<<<nblk, 256, 0, stream>>>(x, bdes, btw, bnum, bcat, bin, pa, Wt, out);
  // layer 1: gather neighbor means of h0, then fused K=384 GEMM -> hB
  k_gather<<<NN / 4, 256, 0, stream>>>(out, aggH, row_ptr, cnt2, entries);
  k_rgemm2<<<nblk, 256, 0, stream>>>(out, aggH, Wt + OFF_L1_HI, Wt + OFF_L1_LO,
                                     bias1, hB);
  // layer 2
  k_gather<<<NN / 4, 256, 0, stream>>>(hB, aggH, row_ptr, cnt2, entries);
  k_rgemm2<<<nblk, 256, 0, stream>>>(hB, aggH, Wt + OFF_L2_HI, Wt + OFF_L2_LO,
                                     bias2, out);
  // classifier (MFMA, in-place)
  k_cls2<<<nblk, 256, 0, stream>>>(out, Wt, bcls);
}

// Round 9
// 946.051 us; speedup vs baseline: 1.4042x; 1.0318x over previous
//
#include <hip/hip_runtime.h>
#include <cstdint>
#include <cstddef>

#define NN 100000
#define EE 1600000
#define XDIM 1553
#define HD 128

typedef __attribute__((ext_vector_type(8))) short short8;
typedef __attribute__((ext_vector_type(4))) float f32x4;
// unaligned-capable 4-float vector: hardware allows 4B-aligned dwordx4
typedef float f32x4u __attribute__((vector_size(16), aligned(4)));

union Frag { unsigned int u[4]; short8 s; uint4 v; };

// weight area offsets (ushort units); hi/lo are separate regions
#define OFF_DES_HI 0
#define OFF_DES_LO 98304
#define OFF_TW_HI  196608
#define OFF_TW_LO  294912
#define OFF_NUM_HI 393216
#define OFF_NUM_LO 397312
#define OFF_CAT_HI 401408
#define OFF_CAT_LO 405504
#define OFF_WIN_HI 409600
#define OFF_WIN_LO 475136
#define OFF_L1_HI  540672
#define OFF_L1_LO  589824
#define OFF_L2_HI  638976
#define OFF_L2_LO  688128
#define OFF_CLS_HI 737280
#define OFF_CLS_LO 753664
#define WT_SITES   385024   // (col,k) sites; each writes hi+lo

// hi = trunc-bf16(f), lo = trunc-bf16(f - hi). Packed: 2 elems -> 1 u32 via v_perm.
__device__ __forceinline__ void cvt_pair(float f0, float f1,
                                         unsigned int& hi, unsigned int& lo) {
  unsigned int u0 = __float_as_uint(f0), u1 = __float_as_uint(f1);
  hi = __builtin_amdgcn_perm(u1, u0, 0x07060302u);
  float l0 = f0 - __uint_as_float(u0 & 0xFFFF0000u);
  float l1 = f1 - __uint_as_float(u1 & 0xFFFF0000u);
  lo = __builtin_amdgcn_perm(__float_as_uint(l1), __float_as_uint(l0), 0x07060302u);
}

// raw barriers: no vmcnt drain (prefetched global loads ride across);
// lgkm0 variant publishes ds_writes before the barrier.
__device__ __forceinline__ void fence_barrier() {
  asm volatile("" ::: "memory");
  __builtin_amdgcn_s_barrier();
  asm volatile("" ::: "memory");
}
__device__ __forceinline__ void lgkm0_barrier() {
  asm volatile("s_waitcnt lgkmcnt(0)" ::: "memory");
  __builtin_amdgcn_s_barrier();
  asm volatile("" ::: "memory");
}

// ---------------- weight pre-convert/transpose (runs once, tiny) ----------------
__global__ __launch_bounds__(256) void k_prepw(
    const float* __restrict__ Wdes, const float* __restrict__ Wtw,
    const float* __restrict__ Wnum, const float* __restrict__ Wcat,
    const float* __restrict__ Win,  const float* __restrict__ root1,
    const float* __restrict__ rel1, const float* __restrict__ root2,
    const float* __restrict__ rel2, const float* __restrict__ Wcls,
    unsigned short* __restrict__ Wt) {
  int id = blockIdx.x * 256 + threadIdx.x;
  if (id >= WT_SITES) return;
  const float* src; int K, Kpad, dhi, dlo, local;
  if (id < 98304)       { src=Wdes;        K=768; Kpad=768; dhi=OFF_DES_HI;       dlo=OFF_DES_LO;       local=id; }
  else if (id < 196608) { src=Wtw;         K=768; Kpad=768; dhi=OFF_TW_HI;        dlo=OFF_TW_LO;        local=id-98304; }
  else if (id < 200704) { src=Wnum;        K=6;   Kpad=32;  dhi=OFF_NUM_HI;       dlo=OFF_NUM_LO;       local=id-196608; }
  else if (id < 204800) { src=Wcat;        K=11;  Kpad=32;  dhi=OFF_CAT_HI;       dlo=OFF_CAT_LO;       local=id-200704; }
  else if (id < 270336) { src=Win;         K=512; Kpad=512; dhi=OFF_WIN_HI;       dlo=OFF_WIN_LO;       local=id-204800; }
  else if (id < 286720) { src=root1;       K=128; Kpad=128; dhi=OFF_L1_HI;        dlo=OFF_L1_LO;        local=id-270336; }
  else if (id < 303104) { src=rel1;        K=128; Kpad=128; dhi=OFF_L1_HI+16384;  dlo=OFF_L1_LO+16384;  local=id-286720; }
  else if (id < 319488) { src=rel1+16384;  K=128; Kpad=128; dhi=OFF_L1_HI+32768;  dlo=OFF_L1_LO+32768;  local=id-303104; }
  else if (id < 335872) { src=root2;       K=128; Kpad=128; dhi=OFF_L2_HI;        dlo=OFF_L2_LO;        local=id-319488; }
  else if (id < 352256) { src=rel2;        K=128; Kpad=128; dhi=OFF_L2_HI+16384;  dlo=OFF_L2_LO+16384;  local=id-335872; }
  else if (id < 368640) { src=rel2+16384;  K=128; Kpad=128; dhi=OFF_L2_HI+32768;  dlo=OFF_L2_LO+32768;  local=id-352256; }
  else                  { src=Wcls;        K=128; Kpad=128; dhi=OFF_CLS_HI;       dlo=OFF_CLS_LO;       local=id-368640; }
  int col = local / Kpad;
  int k = local - col * Kpad;
  float v = (k < K) ? src[(size_t)k * 128 + col] : 0.f;
  unsigned int u = __float_as_uint(v);
  float lo = v - __uint_as_float(u & 0xFFFF0000u);
  Wt[dhi + col * Kpad + k] = (unsigned short)(u >> 16);
  Wt[dlo + col * Kpad + k] = (unsigned short)(__float_as_uint(lo) >> 16);
}

// ---------------- classifier fusion: Wfused = [root2;rel2] @ Wcls (K-stacked) ----
// out = h2 @ Wcls + bcls and h2 = [h|agg0|agg1] @ W2 + b2 (no nonlinearity
// between) => out = [h|agg0|agg1] @ (W2@Wcls) + (b2@Wcls + bcls).
// Overwrites the OFF_L2 region (prepw ran before us on the same stream).
// blockIdx 0..383 = weight rows; block 384 = fused bias.
__global__ __launch_bounds__(128) void k_fusew(
    const float* __restrict__ root2, const float* __restrict__ rel2,
    const float* __restrict__ Wcls,  const float* __restrict__ bias2,
    const float* __restrict__ bcls,  unsigned short* __restrict__ Wt,
    float* __restrict__ bfused) {
  int k = blockIdx.x;
  int c = threadIdx.x;
  const float* wrow;
  if (k < 128)      wrow = root2 + (size_t)k * 128;
  else if (k < 256) wrow = rel2 + (size_t)(k - 128) * 128;
  else if (k < 384) wrow = rel2 + 16384 + (size_t)(k - 256) * 128;
  else              wrow = bias2;
  float s = 0.f;
  for (int j = 0; j < 128; ++j) s += wrow[j] * Wcls[(size_t)j * 128 + c];
  if (k == 384) { bfused[c] = s + bcls[c]; return; }
  unsigned int u = __float_as_uint(s);
  float lo = s - __uint_as_float(u & 0xFFFF0000u);
  int sub = k >> 7, kl = k & 127;
  Wt[OFF_L2_HI + sub * 16384 + c * 128 + kl] = (unsigned short)(u >> 16);
  Wt[OFF_L2_LO + sub * 16384 + c * 128 + kl] = (unsigned short)(__float_as_uint(lo) >> 16);
}

// ---------------- CSR build ----------------
__global__ __launch_bounds__(256) void k_count(const int* __restrict__ ei,
                                               const int* __restrict__ et,
                                               int* __restrict__ cnt2) {
  int e = blockIdx.x * 256 + threadIdx.x;
  if (e >= EE) return;
  atomicAdd(&cnt2[et[e] * NN + ei[EE + e]], 1);
}

__global__ __launch_bounds__(256) void k_scan1(const int* __restrict__ cnt2,
                                               int* __restrict__ row_ptr,
                                               int* __restrict__ bsum) {
  __shared__ int sums[256];
  int t = threadIdx.x;
  int base = blockIdx.x * 1024 + t * 4;
  int v[4]; int s = 0;
#pragma unroll
  for (int j = 0; j < 4; ++j) {
    int idx = base + j;
    v[j] = (idx < NN) ? (cnt2[idx] + cnt2[NN + idx]) : 0;
    s += v[j];
  }
  sums[t] = s;
  __syncthreads();
  for (int d = 1; d < 256; d <<= 1) {
    int val = (t >= d) ? sums[t - d] : 0;
    __syncthreads();
    sums[t] += val;
    __syncthreads();
  }
  int excl = sums[t] - s;
  if (t == 255) bsum[blockIdx.x] = sums[t];
  int run = excl;
#pragma unroll
  for (int j = 0; j < 4; ++j) {
    int idx = base + j;
    if (idx < NN) row_ptr[idx] = run;
    run += v[j];
  }
}

__global__ __launch_bounds__(128) void k_scan2(int* __restrict__ bsum, int nb) {
  __shared__ int s[128];
  int t = threadIdx.x;
  int v = (t < nb) ? bsum[t] : 0;
  s[t] = v;
  __syncthreads();
  for (int d = 1; d < 128; d <<= 1) {
    int val = (t >= d) ? s[t - d] : 0;
    __syncthreads();
    s[t] += val;
    __syncthreads();
  }
  if (t < nb) bsum[t] = s[t] - v;
}

__global__ __launch_bounds__(256) void k_scan3(int* __restrict__ row_ptr,
                                               const int* __restrict__ bsum) {
  int idx = blockIdx.x * 256 + threadIdx.x;
  if (idx < NN) row_ptr[idx] += bsum[idx >> 10];
  if (idx == NN) row_ptr[NN] = EE;
}

__global__ __launch_bounds__(256) void k_fill(const int* __restrict__ ei,
                                              const int* __restrict__ et,
                                              const int* __restrict__ row_ptr,
                                              int* __restrict__ fillpos,
                                              int* __restrict__ entries) {
  int e = blockIdx.x * 256 + threadIdx.x;
  if (e >= EE) return;
  int src = ei[e];
  int dst = ei[EE + e];
  int r = et[e];
  int pos = atomicAdd(&fillpos[dst], 1);
  entries[row_ptr[dst] + pos] = src | (r << 20);
}

// ---------------- fused projection (MFMA, split-bf16, pipelined, raw barriers) ----
// 64 nodes/block, 4 waves, wave = 16 rows x 128 cols, 3 blocks/CU (R3 shape,
// 84 VGPR no-spill). X pipeline depth-3; raw barriers (no vmcnt drain).
__global__ __launch_bounds__(256, 3) void k_proj2(
    const float* __restrict__ x,
    const float* __restrict__ bdes, const float* __restrict__ btw,
    const float* __restrict__ bnum, const float* __restrict__ bcat,
    const float* __restrict__ bin,  const float* __restrict__ pa,
    const unsigned short* __restrict__ Wt, float* __restrict__ h0) {
  __shared__ unsigned short bt_hi[128 * 32], bt_lo[128 * 32];   // 8KB + 8KB
  __shared__ unsigned short z_hi[64 * 128], z_lo[64 * 128];     // 16KB + 16KB

  const int t = threadIdx.x;
  const int node0 = blockIdx.x * 64;
  const int w = t >> 6, lane = t & 63;
  const int li = lane & 15, lg = lane >> 4;

  // B-staging constants (loop-invariant per thread)
  const int cr0 = t >> 2, c0 = t & 3;
  const int cr1 = cr0 + 64;
  const unsigned stb0 = cr0 * 64 + ((c0 ^ ((cr0 >> 1) & 3)) << 4);
  const unsigned stb1 = cr1 * 64 + ((c0 ^ ((cr1 >> 1) & 3)) << 4);

  // one A-row per (wave, li)
  const int rowA = w * 16 + li;
  int nodeA = node0 + rowA;
  int ndA = nodeA < NN ? nodeA : NN - 1;
  const float* xrow = x + (size_t)ndA * XDIM;

#define STORE_BT(SH0, SL0, SH1, SL1)              \
  do {                                            \
    *(uint4*)((char*)bt_hi + stb0) = (SH0);       \
    *(uint4*)((char*)bt_lo + stb0) = (SL0);       \
    *(uint4*)((char*)bt_hi + stb1) = (SH1);       \
    *(uint4*)((char*)bt_lo + stb1) = (SL1);       \
  } while (0)

#define CVT_A2(FA, FB, AH, AL)                                                   \
  do {                                                                           \
    cvt_pair((FA)[0], (FA)[1], (AH).u[0], (AL).u[0]);                            \
    cvt_pair((FA)[2], (FA)[3], (AH).u[1], (AL).u[1]);                            \
    cvt_pair((FB)[0], (FB)[1], (AH).u[2], (AL).u[2]);                            \
    cvt_pair((FB)[2], (FB)[3], (AH).u[3], (AL).u[3]);                            \
  } while (0)

#define MFMA8(AH, AL, ACC)                                                       \
  do {                                                                           \
    _Pragma("unroll")                                                            \
    for (int ct_ = 0; ct_ < 8; ++ct_) {                                          \
      int colrow_ = ct_ * 16 + li;                                               \
      int byte_ = colrow_ * 64 + (lg << 4);                                      \
      byte_ ^= ((colrow_ >> 1) & 3) << 4;                                        \
      Frag bh_, bl_;                                                             \
      bh_.v = *(const uint4*)((char*)bt_hi + byte_);                             \
      bl_.v = *(const uint4*)((char*)bt_lo + byte_);                             \
      (ACC)[ct_] = __builtin_amdgcn_mfma_f32_16x16x32_bf16((AH).s, bl_.s, (ACC)[ct_], 0, 0, 0); \
      (ACC)[ct_] = __builtin_amdgcn_mfma_f32_16x16x32_bf16((AL).s, bh_.s, (ACC)[ct_], 0, 0, 0); \
      (ACC)[ct_] = __builtin_amdgcn_mfma_f32_16x16x32_bf16((AH).s, bh_.s, (ACC)[ct_], 0, 0, 0); \
    }                                                                            \
  } while (0)

// one K-tile of phase A: store W tile (cur), barrier, convert X, prefetch
// W(T+1, into next buf) + X(T+3, dwordx4 pair back into same X bufs), MFMA, barrier.
#define TILE(WC0, WC1, WC2, WC3, WN0, WN1, WN2, WN3, XA, XB, T)                  \
  do {                                                                           \
    STORE_BT(WC0, WC1, WC2, WC3);                                                \
    lgkm0_barrier();                                                             \
    Frag ah_, al_;                                                               \
    CVT_A2(XA, XB, ah_, al_);                                                    \
    {                                                                            \
      const int kw_ = ((T) + 1) * 32;                                            \
      WN0 = *(const uint4*)(ph0 + kw_); WN1 = *(const uint4*)(pl0 + kw_);        \
      WN2 = *(const uint4*)(ph1 + kw_); WN3 = *(const uint4*)(pl1 + kw_);        \
      int kx_ = (T) + 3; if (kx_ > 23) kx_ = 23; kx_ *= 32;                      \
      XA = *(const f32x4u*)(xr + kx_);                                           \
      XB = *(const f32x4u*)(xr + kx_ + 4);                                       \
    }                                                                            \
    MFMA8(ah_, al_, zacc);                                                       \
    fence_barrier();                                                             \
  } while (0)

#define MFMA_B(KT)                                                               \
  do {                                                                           \
    Frag ah_, al_;                                                               \
    int byte_ = rowA * 256 + (((KT) * 32 + lg * 8) << 1);                        \
    byte_ ^= (rowA & 7) << 4;                                                    \
    ah_.v = *(const uint4*)((char*)z_hi + byte_);                                \
    al_.v = *(const uint4*)((char*)z_lo + byte_);                                \
    MFMA8(ah_, al_, hacc);                                                       \
  } while (0)

#define Z_EPI(ZACC, BIASP)                                                       \
  do {                                                                           \
    _Pragma("unroll")                                                            \
    for (int ct_ = 0; ct_ < 8; ++ct_) {                                          \
      int col_ = ct_ * 16 + li;                                                  \
      float bv_ = (BIASP)[col_];                                                 \
      _Pragma("unroll")                                                          \
      for (int r_ = 0; r_ < 4; ++r_) {                                           \
        float v_ = (ZACC)[ct_][r_] + bv_;                                        \
        v_ = v_ >= 0.f ? v_ : 0.01f * v_;                                        \
        int row_ = w * 16 + lg * 4 + r_;                                         \
        int byte_ = row_ * 256 + col_ * 2;                                       \
        byte_ ^= (row_ & 7) << 4;                                                \
        unsigned int u_ = __float_as_uint(v_);                                   \
        *(unsigned short*)((char*)z_hi + byte_) = (unsigned short)(u_ >> 16);    \
        float lo_ = v_ - __uint_as_float(u_ & 0xFFFF0000u);                      \
        *(unsigned short*)((char*)z_lo + byte_) = (unsigned short)(__float_as_uint(lo_) >> 16); \
      }                                                                          \
    }                                                                            \
  } while (0)

// phase B: hacc += z @ Win[SLICE*128 .. +127], 4 K-tiles, fully unrolled,
// 1-deep prefetch of the next Win tile.
#define PHASE_B(SLICE)                                                           \
  do {                                                                           \
    const unsigned short* qh0_ = Wt + OFF_WIN_HI + cr0 * 512 + (SLICE) * 128 + c0 * 8; \
    const unsigned short* ql0_ = Wt + OFF_WIN_LO + cr0 * 512 + (SLICE) * 128 + c0 * 8; \
    const unsigned short* qh1_ = Wt + OFF_WIN_HI + cr1 * 512 + (SLICE) * 128 + c0 * 8; \
    const unsigned short* ql1_ = Wt + OFF_WIN_LO + cr1 * 512 + (SLICE) * 128 + c0 * 8; \
    uint4 wA0_ = *(const uint4*)(qh0_), wA1_ = *(const uint4*)(ql0_);            \
    uint4 wA2_ = *(const uint4*)(qh1_), wA3_ = *(const uint4*)(ql1_);            \
    uint4 wB0_, wB1_, wB2_, wB3_;                                                \
    STORE_BT(wA0_, wA1_, wA2_, wA3_);                                            \
    lgkm0_barrier();                                                             \
    wB0_ = *(const uint4*)(qh0_ + 32); wB1_ = *(const uint4*)(ql0_ + 32);        \
    wB2_ = *(const uint4*)(qh1_ + 32); wB3_ = *(const uint4*)(ql1_ + 32);        \
    MFMA_B(0);                                                                   \
    fence_barrier();                                                             \
    STORE_BT(wB0_, wB1_, wB2_, wB3_);                                            \
    lgkm0_barrier();                                                             \
    wA0_ = *(const uint4*)(qh0_ + 64); wA1_ = *(const uint4*)(ql0_ + 64);        \
    wA2_ = *(const uint4*)(qh1_ + 64); wA3_ = *(const uint4*)(ql1_ + 64);        \
    MFMA_B(1);                                                                   \
    fence_barrier();                                                             \
    STORE_BT(wA0_, wA1_, wA2_, wA3_);                                            \
    lgkm0_barrier();                                                             \
    wB0_ = *(const uint4*)(qh0_ + 96); wB1_ = *(const uint4*)(ql0_ + 96);        \
    wB2_ = *(const uint4*)(qh1_ + 96); wB3_ = *(const uint4*)(ql1_ + 96);        \
    MFMA_B(2);                                                                   \
    fence_barrier();                                                             \
    STORE_BT(wB0_, wB1_, wB2_, wB3_);                                            \
    lgkm0_barrier();                                                             \
    MFMA_B(3);                                                                   \
    fence_barrier();                                                             \
  } while (0)

  f32x4 hacc[8];
#pragma unroll
  for (int b = 0; b < 8; ++b) hacc[b] = (f32x4)0.f;

  // ---- big segments: des (s=0), tweet (s=1); K=768 = 24 K-tiles, pipelined ----
#pragma unroll
  for (int s = 0; s < 2; ++s) {
    const int off = (s == 0) ? 785 : 6;
    const unsigned short* wh = Wt + (s == 0 ? OFF_DES_HI : OFF_TW_HI);
    const unsigned short* wl = Wt + (s == 0 ? OFF_DES_LO : OFF_TW_LO);
    const float* bias = (s == 0) ? bdes : btw;

    const float* xr = xrow + off + lg * 8;
    const unsigned short* ph0 = wh + cr0 * 768 + c0 * 8;
    const unsigned short* pl0 = wl + cr0 * 768 + c0 * 8;
    const unsigned short* ph1 = wh + cr1 * 768 + c0 * 8;
    const unsigned short* pl1 = wl + cr1 * 768 + c0 * 8;

    f32x4 zacc[8];
#pragma unroll
    for (int b = 0; b < 8; ++b) zacc[b] = (f32x4)0.f;

    uint4 WA0, WA1, WA2, WA3, WB0, WB1, WB2, WB3;
    f32x4u X0a, X0b, X1a, X1b, X2a, X2b;

    // prologue: W tile 0, X tiles 0..2 (dwordx4 pairs)
    WA0 = *(const uint4*)(ph0); WA1 = *(const uint4*)(pl0);
    WA2 = *(const uint4*)(ph1); WA3 = *(const uint4*)(pl1);
    X0a = *(const f32x4u*)(xr);      X0b = *(const f32x4u*)(xr + 4);
    X1a = *(const f32x4u*)(xr + 32); X1b = *(const f32x4u*)(xr + 36);
    X2a = *(const f32x4u*)(xr + 64); X2b = *(const f32x4u*)(xr + 68);

    for (int base = 0; base < 24; base += 6) {
      TILE(WA0, WA1, WA2, WA3, WB0, WB1, WB2, WB3, X0a, X0b, base + 0);
      TILE(WB0, WB1, WB2, WB3, WA0, WA1, WA2, WA3, X1a, X1b, base + 1);
      TILE(WA0, WA1, WA2, WA3, WB0, WB1, WB2, WB3, X2a, X2b, base + 2);
      TILE(WB0, WB1, WB2, WB3, WA0, WA1, WA2, WA3, X0a, X0b, base + 3);
      TILE(WA0, WA1, WA2, WA3, WB0, WB1, WB2, WB3, X1a, X1b, base + 4);
      TILE(WB0, WB1, WB2, WB3, WA0, WA1, WA2, WA3, X2a, X2b, base + 5);
    }
    Z_EPI(zacc, bias);   // z is wave-private: no barrier needed for z itself
    PHASE_B(s);
  }

  // ---- small segments: num (K=6), cat (K=11); single padded K-tile each ----
#pragma unroll
  for (int u = 0; u < 2; ++u) {
    const int offu = (u == 0) ? 0 : 774;
    const int Ksu = (u == 0) ? 6 : 11;
    const unsigned short* wh = Wt + (u == 0 ? OFF_NUM_HI : OFF_CAT_HI);
    const unsigned short* wl = Wt + (u == 0 ? OFF_NUM_LO : OFF_CAT_LO);
    const float* biasu = (u == 0) ? bnum : bcat;
    const float* xr = xrow + offu + lg * 8;

    uint4 s0 = *(const uint4*)(wh + cr0 * 32 + c0 * 8);
    uint4 s1 = *(const uint4*)(wl + cr0 * 32 + c0 * 8);
    uint4 s2 = *(const uint4*)(wh + cr1 * 32 + c0 * 8);
    uint4 s3 = *(const uint4*)(wl + cr1 * 32 + c0 * 8);
    f32x4u fa = *(const f32x4u*)(xr);
    f32x4u fb = *(const f32x4u*)(xr + 4);
#pragma unroll
    for (int j = 0; j < 4; ++j) {
      if (lg * 8 + j >= Ksu) fa[j] = 0.f;
      if (lg * 8 + 4 + j >= Ksu) fb[j] = 0.f;
    }

    f32x4 zacc[8];
#pragma unroll
    for (int b = 0; b < 8; ++b) zacc[b] = (f32x4)0.f;

    STORE_BT(s0, s1, s2, s3);
    lgkm0_barrier();
    {
      Frag ah_, al_;
      CVT_A2(fa, fb, ah_, al_);
      MFMA8(ah_, al_, zacc);
    }
    fence_barrier();
    Z_EPI(zacc, biasu);
    PHASE_B(u + 2);
  }

  // epilogue: + b_in, PReLU, store
#pragma unroll
  for (int ct = 0; ct < 8; ++ct) {
    int col = ct * 16 + li;
    float bi = bin[col];
    float p = pa[col];
#pragma unroll
    for (int r = 0; r < 4; ++r) {
      int node = node0 + w * 16 + lg * 4 + r;
      if (node < NN) {
        float v = hacc[ct][r] + bi;
        v = v >= 0.f ? v : p * v;
        h0[(size_t)node * HD + col] = v;
      }
    }
  }

#undef TILE
#undef MFMA_B
#undef Z_EPI
#undef PHASE_B
}

// ---------------- neighbor-mean gather: aggH_r[dst] = mean_{src in N_r} h[src] --
// Linearity: mean(h[src] @ rel) == mean(h[src]) @ rel, so gather raw h rows
// (51MB working set, L3-resident) instead of materialized messages.
__global__ __launch_bounds__(256) void k_gather(
    const float* __restrict__ h, float* __restrict__ aggH,
    const int* __restrict__ row_ptr, const int* __restrict__ cnt2,
    const int* __restrict__ entries) {
  int i = blockIdx.x * 4 + (threadIdx.x >> 6);
  int l = threadIdx.x & 63;
  if (i >= NN) return;
  int rs = row_ptr[i], re = row_ptr[i + 1];
  int c0 = cnt2[i], c1 = cnt2[NN + i];
  float inv0 = 1.f / (float)(c0 > 0 ? c0 : 1);
  float inv1 = 1.f / (float)(c1 > 0 ? c1 : 1);
  float a0 = 0, a1 = 0, b0 = 0, b1 = 0;
  int e = rs;
  for (; e + 1 < re; e += 2) {
    int ent0 = entries[e], ent1 = entries[e + 1];
    const float2* r0 = (const float2*)(h + (size_t)(ent0 & 0xFFFFF) * HD);
    const float2* r1 = (const float2*)(h + (size_t)(ent1 & 0xFFFFF) * HD);
    float2 v0 = r0[l], v1 = r1[l];
    if (ent0 >> 20) { b0 += v0.x; b1 += v0.y; } else { a0 += v0.x; a1 += v0.y; }
    if (ent1 >> 20) { b0 += v1.x; b1 += v1.y; } else { a0 += v1.x; a1 += v1.y; }
  }
  if (e < re) {
    int ent = entries[e];
    const float2* r0 = (const float2*)(h + (size_t)(ent & 0xFFFFF) * HD);
    float2 v0 = r0[l];
    if (ent >> 20) { b0 += v0.x; b1 += v0.y; } else { a0 += v0.x; a1 += v0.y; }
  }
  float2* p0 = (float2*)(aggH + (size_t)i * HD);
  float2* p1 = (float2*)(aggH + (size_t)NN * HD + (size_t)i * HD);
  p0[l] = make_float2(a0 * inv0, a1 * inv0);
  p1[l] = make_float2(b0 * inv1, b1 * inv1);
}

// ---------------- fused layer GEMM: out = [h|aggH0|aggH1] @ [root;rel0;rel1] + b --
// Single K=384 GEMM (linearity fusion). 64 rows/block, 4 waves x (16 rows x
// 128 cols), 4 blocks/CU (16KB LDS). Proven proj phase-A skeleton: ping-pong W
// staging, depth-3 A prefetch, raw barriers. No mh materialization, no io RMW.
__global__ __launch_bounds__(256, 4) void k_rgemm2(
    const float* __restrict__ hin, const float* __restrict__ aggH,
    const unsigned short* __restrict__ wl_hi, const unsigned short* __restrict__ wl_lo,
    const float* __restrict__ bias, float* __restrict__ outp) {
  __shared__ unsigned short bt_hi[128 * 32], bt_lo[128 * 32];   // 8KB + 8KB

  const int t = threadIdx.x;
  const int node0 = blockIdx.x * 64;
  const int w = t >> 6, lane = t & 63;
  const int li = lane & 15, lg = lane >> 4;

  const int cr0 = t >> 2, c0 = t & 3;
  const int cr1 = cr0 + 64;
  const unsigned stb0 = cr0 * 64 + ((c0 ^ ((cr0 >> 1) & 3)) << 4);
  const unsigned stb1 = cr1 * 64 + ((c0 ^ ((cr1 >> 1) & 3)) << 4);

  const int rowA = w * 16 + li;
  int nodeA = node0 + rowA;
  int ndA = nodeA < NN ? nodeA : NN - 1;
  const float* a0p = hin + (size_t)ndA * HD + lg * 8;
  const float* a1p = aggH + (size_t)ndA * HD + lg * 8;
  const float* a2p = aggH + (size_t)NN * HD + (size_t)ndA * HD + lg * 8;

// W site pointers: sub-region (kt>>2)*16384, within-region k = (kt&3)*32
#define W2H(KT, CR) (wl_hi + ((KT) >> 2) * 16384 + (CR) * 128 + ((KT) & 3) * 32 + c0 * 8)
#define W2L(KT, CR) (wl_lo + ((KT) >> 2) * 16384 + (CR) * 128 + ((KT) & 3) * 32 + c0 * 8)

#define TILE2(WC0, WC1, WC2, WC3, WN0, WN1, WN2, WN3, XA, XB, T)                 \
  do {                                                                           \
    STORE_BT(WC0, WC1, WC2, WC3);                                                \
    lgkm0_barrier();                                                             \
    Frag ah_, al_;                                                               \
    CVT_A2(XA, XB, ah_, al_);                                                    \
    {                                                                            \
      int kn_ = (T) + 1; if (kn_ > 11) kn_ = 11;                                 \
      WN0 = *(const uint4*)W2H(kn_, cr0); WN1 = *(const uint4*)W2L(kn_, cr0);    \
      WN2 = *(const uint4*)W2H(kn_, cr1); WN3 = *(const uint4*)W2L(kn_, cr1);    \
      int kx_ = (T) + 3; if (kx_ > 11) kx_ = 11;                                 \
      const float* ap_ = (kx_ < 4) ? a0p : (kx_ < 8) ? a1p : a2p;                \
      XA = *(const f32x4u*)(ap_ + (kx_ & 3) * 32);                               \
      XB = *(const f32x4u*)(ap_ + (kx_ & 3) * 32 + 4);                           \
    }                                                                            \
    MFMA8(ah_, al_, acc);                                                        \
    fence_barrier();                                                             \
  } while (0)

  f32x4 acc[8];
#pragma unroll
  for (int b = 0; b < 8; ++b) acc[b] = (f32x4)0.f;

  uint4 WA0, WA1, WA2, WA3, WB0, WB1, WB2, WB3;
  f32x4u X0a, X0b, X1a, X1b, X2a, X2b;

  // prologue: W tile 0, A tiles 0..2
  WA0 = *(const uint4*)W2H(0, cr0); WA1 = *(const uint4*)W2L(0, cr0);
  WA2 = *(const uint4*)W2H(0, cr1); WA3 = *(const uint4*)W2L(0, cr1);
  X0a = *(const f32x4u*)(a0p);      X0b = *(const f32x4u*)(a0p + 4);
  X1a = *(const f32x4u*)(a0p + 32); X1b = *(const f32x4u*)(a0p + 36);
  X2a = *(const f32x4u*)(a0p + 64); X2b = *(const f32x4u*)(a0p + 68);

  TILE2(WA0, WA1, WA2, WA3, WB0, WB1, WB2, WB3, X0a, X0b, 0);
  TILE2(WB0, WB1, WB2, WB3, WA0, WA1, WA2, WA3, X1a, X1b, 1);
  TILE2(WA0, WA1, WA2, WA3, WB0, WB1, WB2, WB3, X2a, X2b, 2);
  TILE2(WB0, WB1, WB2, WB3, WA0, WA1, WA2, WA3, X0a, X0b, 3);
  TILE2(WA0, WA1, WA2, WA3, WB0, WB1, WB2, WB3, X1a, X1b, 4);
  TILE2(WB0, WB1, WB2, WB3, WA0, WA1, WA2, WA3, X2a, X2b, 5);
  TILE2(WA0, WA1, WA2, WA3, WB0, WB1, WB2, WB3, X0a, X0b, 6);
  TILE2(WB0, WB1, WB2, WB3, WA0, WA1, WA2, WA3, X1a, X1b, 7);
  TILE2(WA0, WA1, WA2, WA3, WB0, WB1, WB2, WB3, X2a, X2b, 8);
  TILE2(WB0, WB1, WB2, WB3, WA0, WA1, WA2, WA3, X0a, X0b, 9);
  TILE2(WA0, WA1, WA2, WA3, WB0, WB1, WB2, WB3, X1a, X1b, 10);
  TILE2(WB0, WB1, WB2, WB3, WA0, WA1, WA2, WA3, X2a, X2b, 11);

  // epilogue: + bias, store
#pragma unroll
  for (int ct = 0; ct < 8; ++ct) {
    int col = ct * 16 + li;
    float bv = bias[col];
#pragma unroll
    for (int r = 0; r < 4; ++r) {
      int node = node0 + w * 16 + lg * 4 + r;
      if (node < NN) outp[(size_t)node * HD + col] = acc[ct][r] + bv;
    }
  }

#undef W2H
#undef W2L
#undef TILE2
}

extern "C" void kernel_launch(void* const* d_in, const int* in_sizes, int n_in,
                              void* d_out, int out_size, void* d_ws, size_t ws_size,
                              hipStream_t stream) {
  const float* x    = (const float*)d_in[0];
  const int* ei     = (const int*)d_in[1];
  const int* et     = (const int*)d_in[2];
  const float* Wdes = (const float*)d_in[3];
  const float* bdes = (const float*)d_in[4];
  const float* Wtw  = (const float*)d_in[5];
  const float* btw  = (const float*)d_in[6];
  const float* Wnum = (const float*)d_in[7];
  const float* bnum = (const float*)d_in[8];
  const float* Wcat = (const float*)d_in[9];
  const float* bcat = (const float*)d_in[10];
  const float* Win  = (const float*)d_in[11];
  const float* bin  = (const float*)d_in[12];
  const float* pa   = (const float*)d_in[13];
  const float* root1 = (const float*)d_in[14];
  const float* rel1  = (const float*)d_in[15];
  const float* bias1 = (const float*)d_in[16];
  const float* root2 = (const float*)d_in[17];
  const float* rel2  = (const float*)d_in[18];
  const float* bias2 = (const float*)d_in[19];
  const float* Wcls  = (const float*)d_in[20];
  const float* bcls  = (const float*)d_in[21];
  float* out = (float*)d_out;

  char* p = (char*)d_ws;
  float* aggH = (float*)p;    p += (size_t)2 * NN * HD * 4;   // 102.4 MB
  float* hB = (float*)p;      p += (size_t)NN * HD * 4;       // 51.2 MB
  int* row_ptr = (int*)p;     p += ((size_t)NN + 4) * 4;
  int* cnt2 = (int*)p;        p += (size_t)2 * NN * 4;
  int* fillpos = (int*)p;     p += (size_t)NN * 4;
  int* entries = (int*)p;     p += (size_t)EE * 4;
  int* bsum = (int*)p;        p += 512;
  float* bfused = (float*)p;  p += 512;
  unsigned short* Wt = (unsigned short*)p;  p += (size_t)WT_SITES * 2 * 2;

  // weight pre-convert (independent of everything else)
  k_prepw<<<(WT_SITES + 255) / 256, 256, 0, stream>>>(
      Wdes, Wtw, Wnum, Wcat, Win, root1, rel1, root2, rel2, Wcls, Wt);
  // classifier fusion: overwrite OFF_L2 with [root2;rel2]@Wcls, bfused = b2@Wcls+bcls
  k_fusew<<<385, 128, 0, stream>>>(root2, rel2, Wcls, bias2, bcls, Wt, bfused);

  // CSR build
  hipMemsetAsync(cnt2, 0, (size_t)3 * NN * 4, stream);  // cnt2 + fillpos
  k_count<<<EE / 256, 256, 0, stream>>>(ei, et, cnt2);
  int nb = (NN + 1023) / 1024;
  k_scan1<<<nb, 256, 0, stream>>>(cnt2, row_ptr, bsum);
  k_scan2<<<1, 128, 0, stream>>>(bsum, nb);
  k_scan3<<<(NN + 1 + 255) / 256, 256, 0, stream>>>(row_ptr, bsum);
  k_fill<<<EE / 256, 256, 0, stream>>>(ei, et, row_ptr, fillpos, entries);

  const int nblk = (NN + 63) / 64;  // 1563
  // h0 -> d_out
  k_proj2<<<nblk, 256, 0, stream>>>(x, bdes, btw, bnum, bcat, bin, pa, Wt, out);
  // layer 1: gather neighbor means of h0, then fused K=384 GEMM -> hB
  k_gather<<<NN / 4, 256, 0, stream>>>(out, aggH, row_ptr, cnt2, entries);
  k_rgemm2<<<nblk, 256, 0, stream>>>(out, aggH, Wt + OFF_L1_HI, Wt + OFF_L1_LO,
                                     bias1, hB);
  // layer 2 + classifier (algebraically fused): out = [hB|agg] @ (W2@Wcls) + bfused
  k_gather<<<NN / 4, 256, 0, stream>>>(hB, aggH, row_ptr, cnt2, entries);
  k_rgemm2<<<nblk, 256, 0, stream>>>(hB, aggH, Wt + OFF_L2_HI, Wt + OFF_L2_LO,
                                     bfused, out);
}

// Round 11
// 896.418 us; speedup vs baseline: 1.4820x; 1.0554x over previous
//
#include <hip/hip_runtime.h>
#include <cstdint>
#include <cstddef>

#define NN 100000
#define EE 1600000
#define XDIM 1553
#define HD 128

typedef __attribute__((ext_vector_type(8))) short short8;
typedef __attribute__((ext_vector_type(4))) float f32x4;
// unaligned-capable 4-float vector: hardware allows 4B-aligned dwordx4
typedef float f32x4u __attribute__((vector_size(16), aligned(4)));

union Frag { unsigned int u[4]; short8 s; uint4 v; };

// weight area offsets (ushort units); hi/lo are separate regions
#define OFF_DES_HI 0
#define OFF_DES_LO 98304
#define OFF_TW_HI  196608
#define OFF_TW_LO  294912
#define OFF_NUM_HI 393216
#define OFF_NUM_LO 397312
#define OFF_CAT_HI 401408
#define OFF_CAT_LO 405504
#define OFF_WIN_HI 409600
#define OFF_WIN_LO 475136
#define OFF_L1_HI  540672
#define OFF_L1_LO  589824
#define OFF_L2_HI  638976
#define OFF_L2_LO  688128
#define OFF_CLS_HI 737280
#define OFF_CLS_LO 753664
#define WT_SITES   385024   // (col,k) sites; each writes hi+lo

#define PREPW_BLOCKS 1504   // WT_SITES / 256
#define COUNT_BLOCKS 6250   // EE / 256
#define PROJ_NBLK    1563   // (NN + 63) / 64
#define FILL_BLOCKS  6250   // EE / 256

// hi = trunc-bf16(f), lo = trunc-bf16(f - hi). Packed: 2 elems -> 1 u32 via v_perm.
__device__ __forceinline__ void cvt_pair(float f0, float f1,
                                         unsigned int& hi, unsigned int& lo) {
  unsigned int u0 = __float_as_uint(f0), u1 = __float_as_uint(f1);
  hi = __builtin_amdgcn_perm(u1, u0, 0x07060302u);
  float l0 = f0 - __uint_as_float(u0 & 0xFFFF0000u);
  float l1 = f1 - __uint_as_float(u1 & 0xFFFF0000u);
  lo = __builtin_amdgcn_perm(__float_as_uint(l1), __float_as_uint(l0), 0x07060302u);
}

// raw barriers: no vmcnt drain (prefetched global loads ride across);
// lgkm0 variant publishes ds_writes before the barrier.
__device__ __forceinline__ void fence_barrier() {
  asm volatile("" ::: "memory");
  __builtin_amdgcn_s_barrier();
  asm volatile("" ::: "memory");
}
__device__ __forceinline__ void lgkm0_barrier() {
  asm volatile("s_waitcnt lgkmcnt(0)" ::: "memory");
  __builtin_amdgcn_s_barrier();
  asm volatile("" ::: "memory");
}

// ---------------- setup: weight pre-convert/transpose + edge count (fused) ------
// prepw (blocks 0..1503) and count (blocks 1504..) touch disjoint outputs and
// different pipes (uncoalesced reads vs atomics) -> co-scheduling hides the
// shorter under the longer.
__global__ __launch_bounds__(256) void k_setup(
    const float* __restrict__ Wdes, const float* __restrict__ Wtw,
    const float* __restrict__ Wnum, const float* __restrict__ Wcat,
    const float* __restrict__ Win,  const float* __restrict__ root1,
    const float* __restrict__ rel1, const float* __restrict__ root2,
    const float* __restrict__ rel2, const float* __restrict__ Wcls,
    unsigned short* __restrict__ Wt,
    const int* __restrict__ ei, const int* __restrict__ et,
    int* __restrict__ cnt2) {
  if (blockIdx.x >= PREPW_BLOCKS) {
    int e = (blockIdx.x - PREPW_BLOCKS) * 256 + threadIdx.x;
    if (e < EE) atomicAdd(&cnt2[et[e] * NN + ei[EE + e]], 1);
    return;
  }
  int id = blockIdx.x * 256 + threadIdx.x;
  if (id >= WT_SITES) return;
  const float* src; int K, Kpad, dhi, dlo, local;
  if (id < 98304)       { src=Wdes;        K=768; Kpad=768; dhi=OFF_DES_HI;       dlo=OFF_DES_LO;       local=id; }
  else if (id < 196608) { src=Wtw;         K=768; Kpad=768; dhi=OFF_TW_HI;        dlo=OFF_TW_LO;        local=id-98304; }
  else if (id < 200704) { src=Wnum;        K=6;   Kpad=32;  dhi=OFF_NUM_HI;       dlo=OFF_NUM_LO;       local=id-196608; }
  else if (id < 204800) { src=Wcat;        K=11;  Kpad=32;  dhi=OFF_CAT_HI;       dlo=OFF_CAT_LO;       local=id-200704; }
  else if (id < 270336) { src=Win;         K=512; Kpad=512; dhi=OFF_WIN_HI;       dlo=OFF_WIN_LO;       local=id-204800; }
  else if (id < 286720) { src=root1;       K=128; Kpad=128; dhi=OFF_L1_HI;        dlo=OFF_L1_LO;        local=id-270336; }
  else if (id < 303104) { src=rel1;        K=128; Kpad=128; dhi=OFF_L1_HI+16384;  dlo=OFF_L1_LO+16384;  local=id-286720; }
  else if (id < 319488) { src=rel1+16384;  K=128; Kpad=128; dhi=OFF_L1_HI+32768;  dlo=OFF_L1_LO+32768;  local=id-303104; }
  else if (id < 335872) { src=root2;       K=128; Kpad=128; dhi=OFF_L2_HI;        dlo=OFF_L2_LO;        local=id-319488; }
  else if (id < 352256) { src=rel2;        K=128; Kpad=128; dhi=OFF_L2_HI+16384;  dlo=OFF_L2_LO+16384;  local=id-335872; }
  else if (id < 368640) { src=rel2+16384;  K=128; Kpad=128; dhi=OFF_L2_HI+32768;  dlo=OFF_L2_LO+32768;  local=id-352256; }
  else                  { src=Wcls;        K=128; Kpad=128; dhi=OFF_CLS_HI;       dlo=OFF_CLS_LO;       local=id-368640; }
  int col = local / Kpad;
  int k = local - col * Kpad;
  float v = (k < K) ? src[(size_t)k * 128 + col] : 0.f;
  unsigned int u = __float_as_uint(v);
  float lo = v - __uint_as_float(u & 0xFFFF0000u);
  Wt[dhi + col * Kpad + k] = (unsigned short)(u >> 16);
  Wt[dlo + col * Kpad + k] = (unsigned short)(__float_as_uint(lo) >> 16);
}

// ---------------- classifier fusion: Wfused = [root2;rel2] @ Wcls (K-stacked) ----
// out = h2 @ Wcls + bcls and h2 = [h|agg0|agg1] @ W2 + b2 (no nonlinearity
// between) => out = [h|agg0|agg1] @ (W2@Wcls) + (b2@Wcls + bcls).
// Overwrites the OFF_L2 region (setup ran before us on the same stream).
// blockIdx 0..383 = weight rows; block 384 = fused bias.
__global__ __launch_bounds__(128) void k_fusew(
    const float* __restrict__ root2, const float* __restrict__ rel2,
    const float* __restrict__ Wcls,  const float* __restrict__ bias2,
    const float* __restrict__ bcls,  unsigned short* __restrict__ Wt,
    float* __restrict__ bfused) {
  int k = blockIdx.x;
  int c = threadIdx.x;
  const float* wrow;
  if (k < 128)      wrow = root2 + (size_t)k * 128;
  else if (k < 256) wrow = rel2 + (size_t)(k - 128) * 128;
  else if (k < 384) wrow = rel2 + 16384 + (size_t)(k - 256) * 128;
  else              wrow = bias2;
  float s = 0.f;
  for (int j = 0; j < 128; ++j) s += wrow[j] * Wcls[(size_t)j * 128 + c];
  if (k == 384) { bfused[c] = s + bcls[c]; return; }
  unsigned int u = __float_as_uint(s);
  float lo = s - __uint_as_float(u & 0xFFFF0000u);
  int sub = k >> 7, kl = k & 127;
  Wt[OFF_L2_HI + sub * 16384 + c * 128 + kl] = (unsigned short)(u >> 16);
  Wt[OFF_L2_LO + sub * 16384 + c * 128 + kl] = (unsigned short)(__float_as_uint(lo) >> 16);
}

// ---------------- CSR scans ----------------
__global__ __launch_bounds__(256) void k_scan1(const int* __restrict__ cnt2,
                                               int* __restrict__ row_ptr,
                                               int* __restrict__ bsum) {
  __shared__ int sums[256];
  int t = threadIdx.x;
  int base = blockIdx.x * 1024 + t * 4;
  int v[4]; int s = 0;
#pragma unroll
  for (int j = 0; j < 4; ++j) {
    int idx = base + j;
    v[j] = (idx < NN) ? (cnt2[idx] + cnt2[NN + idx]) : 0;
    s += v[j];
  }
  sums[t] = s;
  __syncthreads();
  for (int d = 1; d < 256; d <<= 1) {
    int val = (t >= d) ? sums[t - d] : 0;
    __syncthreads();
    sums[t] += val;
    __syncthreads();
  }
  int excl = sums[t] - s;
  if (t == 255) bsum[blockIdx.x] = sums[t];
  int run = excl;
#pragma unroll
  for (int j = 0; j < 4; ++j) {
    int idx = base + j;
    if (idx < NN) row_ptr[idx] = run;
    run += v[j];
  }
}

__global__ __launch_bounds__(128) void k_scan2(int* __restrict__ bsum, int nb) {
  __shared__ int s[128];
  int t = threadIdx.x;
  int v = (t < nb) ? bsum[t] : 0;
  s[t] = v;
  __syncthreads();
  for (int d = 1; d < 128; d <<= 1) {
    int val = (t >= d) ? s[t - d] : 0;
    __syncthreads();
    s[t] += val;
    __syncthreads();
  }
  if (t < nb) bsum[t] = s[t] - v;
}

__global__ __launch_bounds__(256) void k_scan3(int* __restrict__ row_ptr,
                                               const int* __restrict__ bsum) {
  int idx = blockIdx.x * 256 + threadIdx.x;
  if (idx < NN) row_ptr[idx] += bsum[idx >> 10];
  if (idx == NN) row_ptr[NN] = EE;
}

// ---------------- fused projection + CSR fill (MFMA, split-bf16, raw barriers) ---
// Blocks 0..1562: 64 nodes/block, 4 waves, wave = 16 rows x 128 cols, 3 blocks/CU
// (84 VGPR no-spill). X pipeline depth-3; raw barriers (no vmcnt drain).
// Blocks >= 1563: CSR fill (needs only row_ptr; independent of proj) — hides in
// proj's idle VMEM/LSU cycles (proj is latency-bound: HBM 14%, MFMA 16%).
__global__ __launch_bounds__(256, 3) void k_proj2(
    const float* __restrict__ x,
    const float* __restrict__ bdes, const float* __restrict__ btw,
    const float* __restrict__ bnum, const float* __restrict__ bcat,
    const float* __restrict__ bin,  const float* __restrict__ pa,
    const unsigned short* __restrict__ Wt, float* __restrict__ h0,
    const int* __restrict__ ei, const int* __restrict__ et,
    const int* __restrict__ row_ptr, int* __restrict__ fillpos,
    int* __restrict__ entries) {
  __shared__ unsigned short bt_hi[128 * 32], bt_lo[128 * 32];   // 8KB + 8KB
  __shared__ unsigned short z_hi[64 * 128], z_lo[64 * 128];     // 16KB + 16KB

  if (blockIdx.x >= PROJ_NBLK) {
    int e = (blockIdx.x - PROJ_NBLK) * 256 + threadIdx.x;
    if (e < EE) {
      int src = ei[e];
      int dst = ei[EE + e];
      int r = et[e];
      int pos = atomicAdd(&fillpos[dst], 1);
      entries[row_ptr[dst] + pos] = src | (r << 20);
    }
    return;
  }

  const int t = threadIdx.x;
  const int node0 = blockIdx.x * 64;
  const int w = t >> 6, lane = t & 63;
  const int li = lane & 15, lg = lane >> 4;

  // B-staging constants (loop-invariant per thread)
  const int cr0 = t >> 2, c0 = t & 3;
  const int cr1 = cr0 + 64;
  const unsigned stb0 = cr0 * 64 + ((c0 ^ ((cr0 >> 1) & 3)) << 4);
  const unsigned stb1 = cr1 * 64 + ((c0 ^ ((cr1 >> 1) & 3)) << 4);

  // one A-row per (wave, li)
  const int rowA = w * 16 + li;
  int nodeA = node0 + rowA;
  int ndA = nodeA < NN ? nodeA : NN - 1;
  const float* xrow = x + (size_t)ndA * XDIM;

#define STORE_BT(SH0, SL0, SH1, SL1)              \
  do {                                            \
    *(uint4*)((char*)bt_hi + stb0) = (SH0);       \
    *(uint4*)((char*)bt_lo + stb0) = (SL0);       \
    *(uint4*)((char*)bt_hi + stb1) = (SH1);       \
    *(uint4*)((char*)bt_lo + stb1) = (SL1);       \
  } while (0)

#define CVT_A2(FA, FB, AH, AL)                                                   \
  do {                                                                           \
    cvt_pair((FA)[0], (FA)[1], (AH).u[0], (AL).u[0]);                            \
    cvt_pair((FA)[2], (FA)[3], (AH).u[1], (AL).u[1]);                            \
    cvt_pair((FB)[0], (FB)[1], (AH).u[2], (AL).u[2]);                            \
    cvt_pair((FB)[2], (FB)[3], (AH).u[3], (AL).u[3]);                            \
  } while (0)

#define MFMA8(AH, AL, ACC)                                                       \
  do {                                                                           \
    _Pragma("unroll")                                                            \
    for (int ct_ = 0; ct_ < 8; ++ct_) {                                          \
      int colrow_ = ct_ * 16 + li;                                               \
      int byte_ = colrow_ * 64 + (lg << 4);                                      \
      byte_ ^= ((colrow_ >> 1) & 3) << 4;                                        \
      Frag bh_, bl_;                                                             \
      bh_.v = *(const uint4*)((char*)bt_hi + byte_);                             \
      bl_.v = *(const uint4*)((char*)bt_lo + byte_);                             \
      (ACC)[ct_] = __builtin_amdgcn_mfma_f32_16x16x32_bf16((AH).s, bl_.s, (ACC)[ct_], 0, 0, 0); \
      (ACC)[ct_] = __builtin_amdgcn_mfma_f32_16x16x32_bf16((AL).s, bh_.s, (ACC)[ct_], 0, 0, 0); \
      (ACC)[ct_] = __builtin_amdgcn_mfma_f32_16x16x32_bf16((AH).s, bh_.s, (ACC)[ct_], 0, 0, 0); \
    }                                                                            \
  } while (0)

// one K-tile of phase A: store W tile (cur), barrier, convert X, prefetch
// W(T+1, into next buf) + X(T+3, dwordx4 pair back into same X bufs), MFMA, barrier.
#define TILE(WC0, WC1, WC2, WC3, WN0, WN1, WN2, WN3, XA, XB, T)                  \
  do {                                                                           \
    STORE_BT(WC0, WC1, WC2, WC3);                                                \
    lgkm0_barrier();                                                             \
    Frag ah_, al_;                                                               \
    CVT_A2(XA, XB, ah_, al_);                                                    \
    {                                                                            \
      const int kw_ = ((T) + 1) * 32;                                            \
      WN0 = *(const uint4*)(ph0 + kw_); WN1 = *(const uint4*)(pl0 + kw_);        \
      WN2 = *(const uint4*)(ph1 + kw_); WN3 = *(const uint4*)(pl1 + kw_);        \
      int kx_ = (T) + 3; if (kx_ > 23) kx_ = 23; kx_ *= 32;                      \
      XA = *(const f32x4u*)(xr + kx_);                                           \
      XB = *(const f32x4u*)(xr + kx_ + 4);                                       \
    }                                                                            \
    MFMA8(ah_, al_, zacc);                                                       \
    fence_barrier();                                                             \
  } while (0)

#define MFMA_B(KT)                                                               \
  do {                                                                           \
    Frag ah_, al_;                                                               \
    int byte_ = rowA * 256 + (((KT) * 32 + lg * 8) << 1);                        \
    byte_ ^= (rowA & 7) << 4;                                                    \
    ah_.v = *(const uint4*)((char*)z_hi + byte_);                                \
    al_.v = *(const uint4*)((char*)z_lo + byte_);                                \
    MFMA8(ah_, al_, hacc);                                                       \
  } while (0)

#define Z_EPI(ZACC, BIASP)                                                       \
  do {                                                                           \
    _Pragma("unroll")                                                            \
    for (int ct_ = 0; ct_ < 8; ++ct_) {                                          \
      int col_ = ct_ * 16 + li;                                                  \
      float bv_ = (BIASP)[col_];                                                 \
      _Pragma("unroll")                                                          \
      for (int r_ = 0; r_ < 4; ++r_) {                                           \
        float v_ = (ZACC)[ct_][r_] + bv_;                                        \
        v_ = v_ >= 0.f ? v_ : 0.01f * v_;                                        \
        int row_ = w * 16 + lg * 4 + r_;                                         \
        int byte_ = row_ * 256 + col_ * 2;                                       \
        byte_ ^= (row_ & 7) << 4;                                                \
        unsigned int u_ = __float_as_uint(v_);                                   \
        *(unsigned short*)((char*)z_hi + byte_) = (unsigned short)(u_ >> 16);    \
        float lo_ = v_ - __uint_as_float(u_ & 0xFFFF0000u);                      \
        *(unsigned short*)((char*)z_lo + byte_) = (unsigned short)(__float_as_uint(lo_) >> 16); \
      }                                                                          \
    }                                                                            \
  } while (0)

// phase B: hacc += z @ Win[SLICE*128 .. +127], 4 K-tiles, fully unrolled,
// 1-deep prefetch of the next Win tile.
#define PHASE_B(SLICE)                                                           \
  do {                                                                           \
    const unsigned short* qh0_ = Wt + OFF_WIN_HI + cr0 * 512 + (SLICE) * 128 + c0 * 8; \
    const unsigned short* ql0_ = Wt + OFF_WIN_LO + cr0 * 512 + (SLICE) * 128 + c0 * 8; \
    const unsigned short* qh1_ = Wt + OFF_WIN_HI + cr1 * 512 + (SLICE) * 128 + c0 * 8; \
    const unsigned short* ql1_ = Wt + OFF_WIN_LO + cr1 * 512 + (SLICE) * 128 + c0 * 8; \
    uint4 wA0_ = *(const uint4*)(qh0_), wA1_ = *(const uint4*)(ql0_);            \
    uint4 wA2_ = *(const uint4*)(qh1_), wA3_ = *(const uint4*)(ql1_);            \
    uint4 wB0_, wB1_, wB2_, wB3_;                                                \
    STORE_BT(wA0_, wA1_, wA2_, wA3_);                                            \
    lgkm0_barrier();                                                             \
    wB0_ = *(const uint4*)(qh0_ + 32); wB1_ = *(const uint4*)(ql0_ + 32);        \
    wB2_ = *(const uint4*)(qh1_ + 32); wB3_ = *(const uint4*)(ql1_ + 32);        \
    MFMA_B(0);                                                                   \
    fence_barrier();                                                             \
    STORE_BT(wB0_, wB1_, wB2_, wB3_);                                            \
    lgkm0_barrier();                                                             \
    wA0_ = *(const uint4*)(qh0_ + 64); wA1_ = *(const uint4*)(ql0_ + 64);        \
    wA2_ = *(const uint4*)(qh1_ + 64); wA3_ = *(const uint4*)(ql1_ + 64);        \
    MFMA_B(1);                                                                   \
    fence_barrier();                                                             \
    STORE_BT(wA0_, wA1_, wA2_, wA3_);                                            \
    lgkm0_barrier();                                                             \
    wB0_ = *(const uint4*)(qh0_ + 96); wB1_ = *(const uint4*)(ql0_ + 96);        \
    wB2_ = *(const uint4*)(qh1_ + 96); wB3_ = *(const uint4*)(ql1_ + 96);        \
    MFMA_B(2);                                                                   \
    fence_barrier();                                                             \
    STORE_BT(wB0_, wB1_, wB2_, wB3_);                                            \
    lgkm0_barrier();                                                             \
    MFMA_B(3);                                                                   \
    fence_barrier();                                                             \
  } while (0)

  f32x4 hacc[8];
#pragma unroll
  for (int b = 0; b < 8; ++b) hacc[b] = (f32x4)0.f;

  // ---- big segments: des (s=0), tweet (s=1); K=768 = 24 K-tiles, pipelined ----
#pragma unroll
  for (int s = 0; s < 2; ++s) {
    const int off = (s == 0) ? 785 : 6;
    const unsigned short* wh = Wt + (s == 0 ? OFF_DES_HI : OFF_TW_HI);
    const unsigned short* wl = Wt + (s == 0 ? OFF_DES_LO : OFF_TW_LO);
    const float* bias = (s == 0) ? bdes : btw;

    const float* xr = xrow + off + lg * 8;
    const unsigned short* ph0 = wh + cr0 * 768 + c0 * 8;
    const unsigned short* pl0 = wl + cr0 * 768 + c0 * 8;
    const unsigned short* ph1 = wh + cr1 * 768 + c0 * 8;
    const unsigned short* pl1 = wl + cr1 * 768 + c0 * 8;

    f32x4 zacc[8];
#pragma unroll
    for (int b = 0; b < 8; ++b) zacc[b] = (f32x4)0.f;

    uint4 WA0, WA1, WA2, WA3, WB0, WB1, WB2, WB3;
    f32x4u X0a, X0b, X1a, X1b, X2a, X2b;

    // prologue: W tile 0, X tiles 0..2 (dwordx4 pairs)
    WA0 = *(const uint4*)(ph0); WA1 = *(const uint4*)(pl0);
    WA2 = *(const uint4*)(ph1); WA3 = *(const uint4*)(pl1);
    X0a = *(const f32x4u*)(xr);      X0b = *(const f32x4u*)(xr + 4);
    X1a = *(const f32x4u*)(xr + 32); X1b = *(const f32x4u*)(xr + 36);
    X2a = *(const f32x4u*)(xr + 64); X2b = *(const f32x4u*)(xr + 68);

    for (int base = 0; base < 24; base += 6) {
      TILE(WA0, WA1, WA2, WA3, WB0, WB1, WB2, WB3, X0a, X0b, base + 0);
      TILE(WB0, WB1, WB2, WB3, WA0, WA1, WA2, WA3, X1a, X1b, base + 1);
      TILE(WA0, WA1, WA2, WA3, WB0, WB1, WB2, WB3, X2a, X2b, base + 2);
      TILE(WB0, WB1, WB2, WB3, WA0, WA1, WA2, WA3, X0a, X0b, base + 3);
      TILE(WA0, WA1, WA2, WA3, WB0, WB1, WB2, WB3, X1a, X1b, base + 4);
      TILE(WB0, WB1, WB2, WB3, WA0, WA1, WA2, WA3, X2a, X2b, base + 5);
    }
    Z_EPI(zacc, bias);   // z is wave-private: no barrier needed for z itself
    PHASE_B(s);
  }

  // ---- small segments: num (K=6), cat (K=11); single padded K-tile each ----
#pragma unroll
  for (int u = 0; u < 2; ++u) {
    const int offu = (u == 0) ? 0 : 774;
    const int Ksu = (u == 0) ? 6 : 11;
    const unsigned short* wh = Wt + (u == 0 ? OFF_NUM_HI : OFF_CAT_HI);
    const unsigned short* wl = Wt + (u == 0 ? OFF_NUM_LO : OFF_CAT_LO);
    const float* biasu = (u == 0) ? bnum : bcat;
    const float* xr = xrow + offu + lg * 8;

    uint4 s0 = *(const uint4*)(wh + cr0 * 32 + c0 * 8);
    uint4 s1 = *(const uint4*)(wl + cr0 * 32 + c0 * 8);
    uint4 s2 = *(const uint4*)(wh + cr1 * 32 + c0 * 8);
    uint4 s3 = *(const uint4*)(wl + cr1 * 32 + c0 * 8);
    f32x4u fa = *(const f32x4u*)(xr);
    f32x4u fb = *(const f32x4u*)(xr + 4);
#pragma unroll
    for (int j = 0; j < 4; ++j) {
      if (lg * 8 + j >= Ksu) fa[j] = 0.f;
      if (lg * 8 + 4 + j >= Ksu) fb[j] = 0.f;
    }

    f32x4 zacc[8];
#pragma unroll
    for (int b = 0; b < 8; ++b) zacc[b] = (f32x4)0.f;

    STORE_BT(s0, s1, s2, s3);
    lgkm0_barrier();
    {
      Frag ah_, al_;
      CVT_A2(fa, fb, ah_, al_);
      MFMA8(ah_, al_, zacc);
    }
    fence_barrier();
    Z_EPI(zacc, biasu);
    PHASE_B(u + 2);
  }

  // epilogue: + b_in, PReLU, store
#pragma unroll
  for (int ct = 0; ct < 8; ++ct) {
    int col = ct * 16 + li;
    float bi = bin[col];
    float p = pa[col];
#pragma unroll
    for (int r = 0; r < 4; ++r) {
      int node = node0 + w * 16 + lg * 4 + r;
      if (node < NN) {
        float v = hacc[ct][r] + bi;
        v = v >= 0.f ? v : p * v;
        h0[(size_t)node * HD + col] = v;
      }
    }
  }

#undef TILE
#undef MFMA_B
#undef Z_EPI
#undef PHASE_B
}

// ---------------- neighbor-mean gather: aggH_r[dst] = mean_{src in N_r} h[src] --
// Linearity: mean(h[src] @ rel) == mean(h[src]) @ rel, so gather raw h rows
// (51MB working set, L3-resident). 4-edge unroll: 4 independent row loads in
// flight; accumulation order strictly e-increasing (bit-identical to 2-unroll).
__global__ __launch_bounds__(256) void k_gather(
    const float* __restrict__ h, float* __restrict__ aggH,
    const int* __restrict__ row_ptr, const int* __restrict__ cnt2,
    const int* __restrict__ entries) {
  int i = blockIdx.x * 4 + (threadIdx.x >> 6);
  int l = threadIdx.x & 63;
  if (i >= NN) return;
  int rs = row_ptr[i], re = row_ptr[i + 1];
  int c0 = cnt2[i], c1 = cnt2[NN + i];
  float inv0 = 1.f / (float)(c0 > 0 ? c0 : 1);
  float inv1 = 1.f / (float)(c1 > 0 ? c1 : 1);
  float a0 = 0, a1 = 0, b0 = 0, b1 = 0;
  int e = rs;
  for (; e + 3 < re; e += 4) {
    int ent0 = entries[e], ent1 = entries[e + 1];
    int ent2 = entries[e + 2], ent3 = entries[e + 3];
    const float2* r0 = (const float2*)(h + (size_t)(ent0 & 0xFFFFF) * HD);
    const float2* r1 = (const float2*)(h + (size_t)(ent1 & 0xFFFFF) * HD);
    const float2* r2 = (const float2*)(h + (size_t)(ent2 & 0xFFFFF) * HD);
    const float2* r3 = (const float2*)(h + (size_t)(ent3 & 0xFFFFF) * HD);
    float2 v0 = r0[l], v1 = r1[l], v2 = r2[l], v3 = r3[l];
    if (ent0 >> 20) { b0 += v0.x; b1 += v0.y; } else { a0 += v0.x; a1 += v0.y; }
    if (ent1 >> 20) { b0 += v1.x; b1 += v1.y; } else { a0 += v1.x; a1 += v1.y; }
    if (ent2 >> 20) { b0 += v2.x; b1 += v2.y; } else { a0 += v2.x; a1 += v2.y; }
    if (ent3 >> 20) { b0 += v3.x; b1 += v3.y; } else { a0 += v3.x; a1 += v3.y; }
  }
  for (; e < re; ++e) {
    int ent = entries[e];
    const float2* r0 = (const float2*)(h + (size_t)(ent & 0xFFFFF) * HD);
    float2 v0 = r0[l];
    if (ent >> 20) { b0 += v0.x; b1 += v0.y; } else { a0 += v0.x; a1 += v0.y; }
  }
  float2* p0 = (float2*)(aggH + (size_t)i * HD);
  float2* p1 = (float2*)(aggH + (size_t)NN * HD + (size_t)i * HD);
  p0[l] = make_float2(a0 * inv0, a1 * inv0);
  p1[l] = make_float2(b0 * inv1, b1 * inv1);
}

// ---------------- fused layer GEMM: out = [h|aggH0|aggH1] @ [root;rel0;rel1] + b --
// Single K=384 GEMM (linearity fusion). 64 rows/block, 4 waves x (16 rows x
// 128 cols), 4 blocks/CU (16KB LDS). Proven proj phase-A skeleton: ping-pong W
// staging, depth-3 A prefetch, raw barriers. No mh materialization, no io RMW.
__global__ __launch_bounds__(256, 4) void k_rgemm2(
    const float* __restrict__ hin, const float* __restrict__ aggH,
    const unsigned short* __restrict__ wl_hi, const unsigned short* __restrict__ wl_lo,
    const float* __restrict__ bias, float* __restrict__ outp) {
  __shared__ unsigned short bt_hi[128 * 32], bt_lo[128 * 32];   // 8KB + 8KB

  const int t = threadIdx.x;
  const int node0 = blockIdx.x * 64;
  const int w = t >> 6, lane = t & 63;
  const int li = lane & 15, lg = lane >> 4;

  const int cr0 = t >> 2, c0 = t & 3;
  const int cr1 = cr0 + 64;
  const unsigned stb0 = cr0 * 64 + ((c0 ^ ((cr0 >> 1) & 3)) << 4);
  const unsigned stb1 = cr1 * 64 + ((c0 ^ ((cr1 >> 1) & 3)) << 4);

  const int rowA = w * 16 + li;
  int nodeA = node0 + rowA;
  int ndA = nodeA < NN ? nodeA : NN - 1;
  const float* a0p = hin + (size_t)ndA * HD + lg * 8;
  const float* a1p = aggH + (size_t)ndA * HD + lg * 8;
  const float* a2p = aggH + (size_t)NN * HD + (size_t)ndA * HD + lg * 8;

// W site pointers: sub-region (kt>>2)*16384, within-region k = (kt&3)*32
#define W2H(KT, CR) (wl_hi + ((KT) >> 2) * 16384 + (CR) * 128 + ((KT) & 3) * 32 + c0 * 8)
#define W2L(KT, CR) (wl_lo + ((KT) >> 2) * 16384 + (CR) * 128 + ((KT) & 3) * 32 + c0 * 8)

#define TILE2(WC0, WC1, WC2, WC3, WN0, WN1, WN2, WN3, XA, XB, T)                 \
  do {                                                                           \
    STORE_BT(WC0, WC1, WC2, WC3);                                                \
    lgkm0_barrier();                                                             \
    Frag ah_, al_;                                                               \
    CVT_A2(XA, XB, ah_, al_);                                                    \
    {                                                                            \
      int kn_ = (T) + 1; if (kn_ > 11) kn_ = 11;                                 \
      WN0 = *(const uint4*)W2H(kn_, cr0); WN1 = *(const uint4*)W2L(kn_, cr0);    \
      WN2 = *(const uint4*)W2H(kn_, cr1); WN3 = *(const uint4*)W2L(kn_, cr1);    \
      int kx_ = (T) + 3; if (kx_ > 11) kx_ = 11;                                 \
      const float* ap_ = (kx_ < 4) ? a0p : (kx_ < 8) ? a1p : a2p;                \
      XA = *(const f32x4u*)(ap_ + (kx_ & 3) * 32);                               \
      XB = *(const f32x4u*)(ap_ + (kx_ & 3) * 32 + 4);                           \
    }                                                                            \
    MFMA8(ah_, al_, acc);                                                        \
    fence_barrier();                                                             \
  } while (0)

  f32x4 acc[8];
#pragma unroll
  for (int b = 0; b < 8; ++b) acc[b] = (f32x4)0.f;

  uint4 WA0, WA1, WA2, WA3, WB0, WB1, WB2, WB3;
  f32x4u X0a, X0b, X1a, X1b, X2a, X2b;

  // prologue: W tile 0, A tiles 0..2
  WA0 = *(const uint4*)W2H(0, cr0); WA1 = *(const uint4*)W2L(0, cr0);
  WA2 = *(const uint4*)W2H(0, cr1); WA3 = *(const uint4*)W2L(0, cr1);
  X0a = *(const f32x4u*)(a0p);      X0b = *(const f32x4u*)(a0p + 4);
  X1a = *(const f32x4u*)(a0p + 32); X1b = *(const f32x4u*)(a0p + 36);
  X2a = *(const f32x4u*)(a0p + 64); X2b = *(const f32x4u*)(a0p + 68);

  TILE2(WA0, WA1, WA2, WA3, WB0, WB1, WB2, WB3, X0a, X0b, 0);
  TILE2(WB0, WB1, WB2, WB3, WA0, WA1, WA2, WA3, X1a, X1b, 1);
  TILE2(WA0, WA1, WA2, WA3, WB0, WB1, WB2, WB3, X2a, X2b, 2);
  TILE2(WB0, WB1, WB2, WB3, WA0, WA1, WA2, WA3, X0a, X0b, 3);
  TILE2(WA0, WA1, WA2, WA3, WB0, WB1, WB2, WB3, X1a, X1b, 4);
  TILE2(WB0, WB1, WB2, WB3, WA0, WA1, WA2, WA3, X2a, X2b, 5);
  TILE2(WA0, WA1, WA2, WA3, WB0, WB1, WB2, WB3, X0a, X0b, 6);
  TILE2(WB0, WB1, WB2, WB3, WA0, WA1, WA2, WA3, X1a, X1b, 7);
  TILE2(WA0, WA1, WA2, WA3, WB0, WB1, WB2, WB3, X2a, X2b, 8);
  TILE2(WB0, WB1, WB2, WB3, WA0, WA1, WA2, WA3, X0a, X0b, 9);
  TILE2(WA0, WA1, WA2, WA3, WB0, WB1, WB2, WB3, X1a, X1b, 10);
  TILE2(WB0, WB1, WB2, WB3, WA0, WA1, WA2, WA3, X2a, X2b, 11);

  // epilogue: + bias, store
#pragma unroll
  for (int ct = 0; ct < 8; ++ct) {
    int col = ct * 16 + li;
    float bv = bias[col];
#pragma unroll
    for (int r = 0; r < 4; ++r) {
      int node = node0 + w * 16 + lg * 4 + r;
      if (node < NN) outp[(size_t)node * HD + col] = acc[ct][r] + bv;
    }
  }

#undef W2H
#undef W2L
#undef TILE2
}

extern "C" void kernel_launch(void* const* d_in, const int* in_sizes, int n_in,
                              void* d_out, int out_size, void* d_ws, size_t ws_size,
                              hipStream_t stream) {
  const float* x    = (const float*)d_in[0];
  const int* ei     = (const int*)d_in[1];
  const int* et     = (const int*)d_in[2];
  const float* Wdes = (const float*)d_in[3];
  const float* bdes = (const float*)d_in[4];
  const float* Wtw  = (const float*)d_in[5];
  const float* btw  = (const float*)d_in[6];
  const float* Wnum = (const float*)d_in[7];
  const float* bnum = (const float*)d_in[8];
  const float* Wcat = (const float*)d_in[9];
  const float* bcat = (const float*)d_in[10];
  const float* Win  = (const float*)d_in[11];
  const float* bin  = (const float*)d_in[12];
  const float* pa   = (const float*)d_in[13];
  const float* root1 = (const float*)d_in[14];
  const float* rel1  = (const float*)d_in[15];
  const float* bias1 = (const float*)d_in[16];
  const float* root2 = (const float*)d_in[17];
  const float* rel2  = (const float*)d_in[18];
  const float* bias2 = (const float*)d_in[19];
  const float* Wcls  = (const float*)d_in[20];
  const float* bcls  = (const float*)d_in[21];
  float* out = (float*)d_out;

  char* p = (char*)d_ws;
  float* aggH = (float*)p;    p += (size_t)2 * NN * HD * 4;   // 102.4 MB
  float* hB = (float*)p;      p += (size_t)NN * HD * 4;       // 51.2 MB
  int* row_ptr = (int*)p;     p += ((size_t)NN + 4) * 4;
  int* cnt2 = (int*)p;        p += (size_t)2 * NN * 4;
  int* fillpos = (int*)p;     p += (size_t)NN * 4;
  int* entries = (int*)p;     p += (size_t)EE * 4;
  int* bsum = (int*)p;        p += 512;
  float* bfused = (float*)p;  p += 512;
  unsigned short* Wt = (unsigned short*)p;  p += (size_t)WT_SITES * 2 * 2;

  // zero counters first (cnt2 + fillpos)
  (void)hipMemsetAsync(cnt2, 0, (size_t)3 * NN * 4, stream);
  // setup: weight pre-convert (blocks 0..1503) + edge count (blocks 1504..) fused
  k_setup<<<PREPW_BLOCKS + COUNT_BLOCKS, 256, 0, stream>>>(
      Wdes, Wtw, Wnum, Wcat, Win, root1, rel1, root2, rel2, Wcls, Wt,
      ei, et, cnt2);
  // classifier fusion: overwrite OFF_L2 with [root2;rel2]@Wcls, bfused = b2@Wcls+bcls
  k_fusew<<<385, 128, 0, stream>>>(root2, rel2, Wcls, bias2, bcls, Wt, bfused);

  // CSR scans
  int nb = (NN + 1023) / 1024;
  k_scan1<<<nb, 256, 0, stream>>>(cnt2, row_ptr, bsum);
  k_scan2<<<1, 128, 0, stream>>>(bsum, nb);
  k_scan3<<<(NN + 1 + 255) / 256, 256, 0, stream>>>(row_ptr, bsum);

  // h0 -> d_out, with CSR fill fused in (blocks >= PROJ_NBLK)
  k_proj2<<<PROJ_NBLK + FILL_BLOCKS, 256, 0, stream>>>(
      x, bdes, btw, bnum, bcat, bin, pa, Wt, out,
      ei, et, row_ptr, fillpos, entries);
  // layer 1: gather neighbor means of h0, then fused K=384 GEMM -> hB
  k_gather<<<NN / 4, 256, 0, stream>>>(out, aggH, row_ptr, cnt2, entries);
  k_rgemm2<<<PROJ_NBLK, 256, 0, stream>>>(out, aggH, Wt + OFF_L1_HI, Wt + OFF_L1_LO,
                                          bias1, hB);
  // layer 2 + classifier (algebraically fused): out = [hB|agg] @ (W2@Wcls) + bfused
  k_gather<<<NN / 4, 256, 0, stream>>>(hB, aggH, row_ptr, cnt2, entries);
  k_rgemm2<<<PROJ_NBLK, 256, 0, stream>>>(hB, aggH, Wt + OFF_L2_HI, Wt + OFF_L2_LO,
                                          bfused, out);
}

// Round 12
// 866.955 us; speedup vs baseline: 1.5324x; 1.0340x over previous
//
#include <hip/hip_runtime.h>
#include <cstdint>
#include <cstddef>

#define NN 100000
#define EE 1600000
#define XDIM 1553
#define HD 128

typedef __attribute__((ext_vector_type(8))) short short8;
typedef __attribute__((ext_vector_type(4))) float f32x4;
// unaligned-capable 4-float vector: hardware allows 4B-aligned dwordx4
typedef float f32x4u __attribute__((vector_size(16), aligned(4)));

union Frag { unsigned int u[4]; short8 s; uint4 v; };

// weight area offsets (ushort units); hi/lo are separate regions
#define OFF_DES_HI 0
#define OFF_DES_LO 98304
#define OFF_TW_HI  196608
#define OFF_TW_LO  294912
#define OFF_NUM_HI 393216
#define OFF_NUM_LO 397312
#define OFF_CAT_HI 401408
#define OFF_CAT_LO 405504
#define OFF_WIN_HI 409600
#define OFF_WIN_LO 475136
#define OFF_L1_HI  540672
#define OFF_L1_LO  589824
#define OFF_L2_HI  638976
#define OFF_L2_LO  688128
#define OFF_CLS_HI 737280
#define OFF_CLS_LO 753664
#define WT_SITES   385024   // (col,k) sites; each writes hi+lo

#define PREPW_BLOCKS 1504   // WT_SITES / 256
#define COUNT_BLOCKS 6250   // EE / 256
#define PROJ_NBLK    1563   // (NN + 63) / 64
#define FILL_BLOCKS  6250   // EE / 256

// hi = trunc-bf16(f), lo = trunc-bf16(f - hi). Packed: 2 elems -> 1 u32 via v_perm.
__device__ __forceinline__ void cvt_pair(float f0, float f1,
                                         unsigned int& hi, unsigned int& lo) {
  unsigned int u0 = __float_as_uint(f0), u1 = __float_as_uint(f1);
  hi = __builtin_amdgcn_perm(u1, u0, 0x07060302u);
  float l0 = f0 - __uint_as_float(u0 & 0xFFFF0000u);
  float l1 = f1 - __uint_as_float(u1 & 0xFFFF0000u);
  lo = __builtin_amdgcn_perm(__float_as_uint(l1), __float_as_uint(l0), 0x07060302u);
}

// round-to-nearest-even bf16 (for the gather-side low-precision h copy)
__device__ __forceinline__ unsigned short bf16_rne(float f) {
  unsigned int u = __float_as_uint(f);
  return (unsigned short)((u + 0x7FFFu + ((u >> 16) & 1u)) >> 16);
}

// raw barriers: no vmcnt drain (prefetched global loads ride across);
// lgkm0 variant publishes ds_writes before the barrier.
__device__ __forceinline__ void fence_barrier() {
  asm volatile("" ::: "memory");
  __builtin_amdgcn_s_barrier();
  asm volatile("" ::: "memory");
}
__device__ __forceinline__ void lgkm0_barrier() {
  asm volatile("s_waitcnt lgkmcnt(0)" ::: "memory");
  __builtin_amdgcn_s_barrier();
  asm volatile("" ::: "memory");
}

// ---------------- setup: weight pre-convert/transpose + edge count (fused) ------
__global__ __launch_bounds__(256) void k_setup(
    const float* __restrict__ Wdes, const float* __restrict__ Wtw,
    const float* __restrict__ Wnum, const float* __restrict__ Wcat,
    const float* __restrict__ Win,  const float* __restrict__ root1,
    const float* __restrict__ rel1, const float* __restrict__ root2,
    const float* __restrict__ rel2, const float* __restrict__ Wcls,
    unsigned short* __restrict__ Wt,
    const int* __restrict__ ei, const int* __restrict__ et,
    int* __restrict__ cnt2) {
  if (blockIdx.x >= PREPW_BLOCKS) {
    int e = (blockIdx.x - PREPW_BLOCKS) * 256 + threadIdx.x;
    if (e < EE) atomicAdd(&cnt2[et[e] * NN + ei[EE + e]], 1);
    return;
  }
  int id = blockIdx.x * 256 + threadIdx.x;
  if (id >= WT_SITES) return;
  const float* src; int K, Kpad, dhi, dlo, local;
  if (id < 98304)       { src=Wdes;        K=768; Kpad=768; dhi=OFF_DES_HI;       dlo=OFF_DES_LO;       local=id; }
  else if (id < 196608) { src=Wtw;         K=768; Kpad=768; dhi=OFF_TW_HI;        dlo=OFF_TW_LO;        local=id-98304; }
  else if (id < 200704) { src=Wnum;        K=6;   Kpad=32;  dhi=OFF_NUM_HI;       dlo=OFF_NUM_LO;       local=id-196608; }
  else if (id < 204800) { src=Wcat;        K=11;  Kpad=32;  dhi=OFF_CAT_HI;       dlo=OFF_CAT_LO;       local=id-200704; }
  else if (id < 270336) { src=Win;         K=512; Kpad=512; dhi=OFF_WIN_HI;       dlo=OFF_WIN_LO;       local=id-204800; }
  else if (id < 286720) { src=root1;       K=128; Kpad=128; dhi=OFF_L1_HI;        dlo=OFF_L1_LO;        local=id-270336; }
  else if (id < 303104) { src=rel1;        K=128; Kpad=128; dhi=OFF_L1_HI+16384;  dlo=OFF_L1_LO+16384;  local=id-286720; }
  else if (id < 319488) { src=rel1+16384;  K=128; Kpad=128; dhi=OFF_L1_HI+32768;  dlo=OFF_L1_LO+32768;  local=id-303104; }
  else if (id < 335872) { src=root2;       K=128; Kpad=128; dhi=OFF_L2_HI;        dlo=OFF_L2_LO;        local=id-319488; }
  else if (id < 352256) { src=rel2;        K=128; Kpad=128; dhi=OFF_L2_HI+16384;  dlo=OFF_L2_LO+16384;  local=id-335872; }
  else if (id < 368640) { src=rel2+16384;  K=128; Kpad=128; dhi=OFF_L2_HI+32768;  dlo=OFF_L2_LO+32768;  local=id-352256; }
  else                  { src=Wcls;        K=128; Kpad=128; dhi=OFF_CLS_HI;       dlo=OFF_CLS_LO;       local=id-368640; }
  int col = local / Kpad;
  int k = local - col * Kpad;
  float v = (k < K) ? src[(size_t)k * 128 + col] : 0.f;
  unsigned int u = __float_as_uint(v);
  float lo = v - __uint_as_float(u & 0xFFFF0000u);
  Wt[dhi + col * Kpad + k] = (unsigned short)(u >> 16);
  Wt[dlo + col * Kpad + k] = (unsigned short)(__float_as_uint(lo) >> 16);
}

// ---------------- classifier fusion: Wfused = [root2;rel2] @ Wcls (K-stacked) ----
__global__ __launch_bounds__(128) void k_fusew(
    const float* __restrict__ root2, const float* __restrict__ rel2,
    const float* __restrict__ Wcls,  const float* __restrict__ bias2,
    const float* __restrict__ bcls,  unsigned short* __restrict__ Wt,
    float* __restrict__ bfused) {
  int k = blockIdx.x;
  int c = threadIdx.x;
  const float* wrow;
  if (k < 128)      wrow = root2 + (size_t)k * 128;
  else if (k < 256) wrow = rel2 + (size_t)(k - 128) * 128;
  else if (k < 384) wrow = rel2 + 16384 + (size_t)(k - 256) * 128;
  else              wrow = bias2;
  float s = 0.f;
  for (int j = 0; j < 128; ++j) s += wrow[j] * Wcls[(size_t)j * 128 + c];
  if (k == 384) { bfused[c] = s + bcls[c]; return; }
  unsigned int u = __float_as_uint(s);
  float lo = s - __uint_as_float(u & 0xFFFF0000u);
  int sub = k >> 7, kl = k & 127;
  Wt[OFF_L2_HI + sub * 16384 + c * 128 + kl] = (unsigned short)(u >> 16);
  Wt[OFF_L2_LO + sub * 16384 + c * 128 + kl] = (unsigned short)(__float_as_uint(lo) >> 16);
}

// ---------------- CSR scans ----------------
__global__ __launch_bounds__(256) void k_scan1(const int* __restrict__ cnt2,
                                               int* __restrict__ row_ptr,
                                               int* __restrict__ bsum) {
  __shared__ int sums[256];
  int t = threadIdx.x;
  int base = blockIdx.x * 1024 + t * 4;
  int v[4]; int s = 0;
#pragma unroll
  for (int j = 0; j < 4; ++j) {
    int idx = base + j;
    v[j] = (idx < NN) ? (cnt2[idx] + cnt2[NN + idx]) : 0;
    s += v[j];
  }
  sums[t] = s;
  __syncthreads();
  for (int d = 1; d < 256; d <<= 1) {
    int val = (t >= d) ? sums[t - d] : 0;
    __syncthreads();
    sums[t] += val;
    __syncthreads();
  }
  int excl = sums[t] - s;
  if (t == 255) bsum[blockIdx.x] = sums[t];
  int run = excl;
#pragma unroll
  for (int j = 0; j < 4; ++j) {
    int idx = base + j;
    if (idx < NN) row_ptr[idx] = run;
    run += v[j];
  }
}

__global__ __launch_bounds__(128) void k_scan2(int* __restrict__ bsum, int nb) {
  __shared__ int s[128];
  int t = threadIdx.x;
  int v = (t < nb) ? bsum[t] : 0;
  s[t] = v;
  __syncthreads();
  for (int d = 1; d < 128; d <<= 1) {
    int val = (t >= d) ? s[t - d] : 0;
    __syncthreads();
    s[t] += val;
    __syncthreads();
  }
  if (t < nb) bsum[t] = s[t] - v;
}

__global__ __launch_bounds__(256) void k_scan3(int* __restrict__ row_ptr,
                                               const int* __restrict__ bsum) {
  int idx = blockIdx.x * 256 + threadIdx.x;
  if (idx < NN) row_ptr[idx] += bsum[idx >> 10];
  if (idx == NN) row_ptr[NN] = EE;
}

// ---------------- fused projection + CSR fill (MFMA, split-bf16, raw barriers) ---
// Blocks 0..1562: 64 nodes/block, 4 waves, wave = 16 rows x 128 cols, 3 blocks/CU.
// Blocks >= 1563: CSR fill. Epilogue also emits h16 (RNE bf16 copy of h0) for the
// L3-BW-bound gather (halves its per-edge bytes).
__global__ __launch_bounds__(256, 3) void k_proj2(
    const float* __restrict__ x,
    const float* __restrict__ bdes, const float* __restrict__ btw,
    const float* __restrict__ bnum, const float* __restrict__ bcat,
    const float* __restrict__ bin,  const float* __restrict__ pa,
    const unsigned short* __restrict__ Wt, float* __restrict__ h0,
    unsigned short* __restrict__ h16,
    const int* __restrict__ ei, const int* __restrict__ et,
    const int* __restrict__ row_ptr, int* __restrict__ fillpos,
    int* __restrict__ entries) {
  __shared__ unsigned short bt_hi[128 * 32], bt_lo[128 * 32];   // 8KB + 8KB
  __shared__ unsigned short z_hi[64 * 128], z_lo[64 * 128];     // 16KB + 16KB

  if (blockIdx.x >= PROJ_NBLK) {
    int e = (blockIdx.x - PROJ_NBLK) * 256 + threadIdx.x;
    if (e < EE) {
      int src = ei[e];
      int dst = ei[EE + e];
      int r = et[e];
      int pos = atomicAdd(&fillpos[dst], 1);
      entries[row_ptr[dst] + pos] = src | (r << 20);
    }
    return;
  }

  const int t = threadIdx.x;
  const int node0 = blockIdx.x * 64;
  const int w = t >> 6, lane = t & 63;
  const int li = lane & 15, lg = lane >> 4;

  // B-staging constants (loop-invariant per thread)
  const int cr0 = t >> 2, c0 = t & 3;
  const int cr1 = cr0 + 64;
  const unsigned stb0 = cr0 * 64 + ((c0 ^ ((cr0 >> 1) & 3)) << 4);
  const unsigned stb1 = cr1 * 64 + ((c0 ^ ((cr1 >> 1) & 3)) << 4);

  // one A-row per (wave, li)
  const int rowA = w * 16 + li;
  int nodeA = node0 + rowA;
  int ndA = nodeA < NN ? nodeA : NN - 1;
  const float* xrow = x + (size_t)ndA * XDIM;

#define STORE_BT(SH0, SL0, SH1, SL1)              \
  do {                                            \
    *(uint4*)((char*)bt_hi + stb0) = (SH0);       \
    *(uint4*)((char*)bt_lo + stb0) = (SL0);       \
    *(uint4*)((char*)bt_hi + stb1) = (SH1);       \
    *(uint4*)((char*)bt_lo + stb1) = (SL1);       \
  } while (0)

#define CVT_A2(FA, FB, AH, AL)                                                   \
  do {                                                                           \
    cvt_pair((FA)[0], (FA)[1], (AH).u[0], (AL).u[0]);                            \
    cvt_pair((FA)[2], (FA)[3], (AH).u[1], (AL).u[1]);                            \
    cvt_pair((FB)[0], (FB)[1], (AH).u[2], (AL).u[2]);                            \
    cvt_pair((FB)[2], (FB)[3], (AH).u[3], (AL).u[3]);                            \
  } while (0)

#define MFMA8(AH, AL, ACC)                                                       \
  do {                                                                           \
    _Pragma("unroll")                                                            \
    for (int ct_ = 0; ct_ < 8; ++ct_) {                                          \
      int colrow_ = ct_ * 16 + li;                                               \
      int byte_ = colrow_ * 64 + (lg << 4);                                      \
      byte_ ^= ((colrow_ >> 1) & 3) << 4;                                        \
      Frag bh_, bl_;                                                             \
      bh_.v = *(const uint4*)((char*)bt_hi + byte_);                             \
      bl_.v = *(const uint4*)((char*)bt_lo + byte_);                             \
      (ACC)[ct_] = __builtin_amdgcn_mfma_f32_16x16x32_bf16((AH).s, bl_.s, (ACC)[ct_], 0, 0, 0); \
      (ACC)[ct_] = __builtin_amdgcn_mfma_f32_16x16x32_bf16((AL).s, bh_.s, (ACC)[ct_], 0, 0, 0); \
      (ACC)[ct_] = __builtin_amdgcn_mfma_f32_16x16x32_bf16((AH).s, bh_.s, (ACC)[ct_], 0, 0, 0); \
    }                                                                            \
  } while (0)

// one K-tile of phase A: store W tile (cur), barrier, convert X, prefetch
// W(T+1, into next buf) + X(T+3, dwordx4 pair back into same X bufs), MFMA, barrier.
#define TILE(WC0, WC1, WC2, WC3, WN0, WN1, WN2, WN3, XA, XB, T)                  \
  do {                                                                           \
    STORE_BT(WC0, WC1, WC2, WC3);                                                \
    lgkm0_barrier();                                                             \
    Frag ah_, al_;                                                               \
    CVT_A2(XA, XB, ah_, al_);                                                    \
    {                                                                            \
      const int kw_ = ((T) + 1) * 32;                                            \
      WN0 = *(const uint4*)(ph0 + kw_); WN1 = *(const uint4*)(pl0 + kw_);        \
      WN2 = *(const uint4*)(ph1 + kw_); WN3 = *(const uint4*)(pl1 + kw_);        \
      int kx_ = (T) + 3; if (kx_ > 23) kx_ = 23; kx_ *= 32;                      \
      XA = *(const f32x4u*)(xr + kx_);                                           \
      XB = *(const f32x4u*)(xr + kx_ + 4);                                       \
    }                                                                            \
    MFMA8(ah_, al_, zacc);                                                       \
    fence_barrier();                                                             \
  } while (0)

#define MFMA_B(KT)                                                               \
  do {                                                                           \
    Frag ah_, al_;                                                               \
    int byte_ = rowA * 256 + (((KT) * 32 + lg * 8) << 1);                        \
    byte_ ^= (rowA & 7) << 4;                                                    \
    ah_.v = *(const uint4*)((char*)z_hi + byte_);                                \
    al_.v = *(const uint4*)((char*)z_lo + byte_);                                \
    MFMA8(ah_, al_, hacc);                                                       \
  } while (0)

#define Z_EPI(ZACC, BIASP)                                                       \
  do {                                                                           \
    _Pragma("unroll")                                                            \
    for (int ct_ = 0; ct_ < 8; ++ct_) {                                          \
      int col_ = ct_ * 16 + li;                                                  \
      float bv_ = (BIASP)[col_];                                                 \
      _Pragma("unroll")                                                          \
      for (int r_ = 0; r_ < 4; ++r_) {                                           \
        float v_ = (ZACC)[ct_][r_] + bv_;                                        \
        v_ = v_ >= 0.f ? v_ : 0.01f * v_;                                        \
        int row_ = w * 16 + lg * 4 + r_;                                         \
        int byte_ = row_ * 256 + col_ * 2;                                       \
        byte_ ^= (row_ & 7) << 4;                                                \
        unsigned int u_ = __float_as_uint(v_);                                   \
        *(unsigned short*)((char*)z_hi + byte_) = (unsigned short)(u_ >> 16);    \
        float lo_ = v_ - __uint_as_float(u_ & 0xFFFF0000u);                      \
        *(unsigned short*)((char*)z_lo + byte_) = (unsigned short)(__float_as_uint(lo_) >> 16); \
      }                                                                          \
    }                                                                            \
  } while (0)

// phase B: hacc += z @ Win[SLICE*128 .. +127], 4 K-tiles, fully unrolled,
// 1-deep prefetch of the next Win tile.
#define PHASE_B(SLICE)                                                           \
  do {                                                                           \
    const unsigned short* qh0_ = Wt + OFF_WIN_HI + cr0 * 512 + (SLICE) * 128 + c0 * 8; \
    const unsigned short* ql0_ = Wt + OFF_WIN_LO + cr0 * 512 + (SLICE) * 128 + c0 * 8; \
    const unsigned short* qh1_ = Wt + OFF_WIN_HI + cr1 * 512 + (SLICE) * 128 + c0 * 8; \
    const unsigned short* ql1_ = Wt + OFF_WIN_LO + cr1 * 512 + (SLICE) * 128 + c0 * 8; \
    uint4 wA0_ = *(const uint4*)(qh0_), wA1_ = *(const uint4*)(ql0_);            \
    uint4 wA2_ = *(const uint4*)(qh1_), wA3_ = *(const uint4*)(ql1_);            \
    uint4 wB0_, wB1_, wB2_, wB3_;                                                \
    STORE_BT(wA0_, wA1_, wA2_, wA3_);                                            \
    lgkm0_barrier();                                                             \
    wB0_ = *(const uint4*)(qh0_ + 32); wB1_ = *(const uint4*)(ql0_ + 32);        \
    wB2_ = *(const uint4*)(qh1_ + 32); wB3_ = *(const uint4*)(ql1_ + 32);        \
    MFMA_B(0);                                                                   \
    fence_barrier();                                                             \
    STORE_BT(wB0_, wB1_, wB2_, wB3_);                                            \
    lgkm0_barrier();                                                             \
    wA0_ = *(const uint4*)(qh0_ + 64); wA1_ = *(const uint4*)(ql0_ + 64);        \
    wA2_ = *(const uint4*)(qh1_ + 64); wA3_ = *(const uint4*)(ql1_ + 64);        \
    MFMA_B(1);                                                                   \
    fence_barrier();                                                             \
    STORE_BT(wA0_, wA1_, wA2_, wA3_);                                            \
    lgkm0_barrier();                                                             \
    wB0_ = *(const uint4*)(qh0_ + 96); wB1_ = *(const uint4*)(ql0_ + 96);        \
    wB2_ = *(const uint4*)(qh1_ + 96); wB3_ = *(const uint4*)(ql1_ + 96);        \
    MFMA_B(2);                                                                   \
    fence_barrier();                                                             \
    STORE_BT(wB0_, wB1_, wB2_, wB3_);                                            \
    lgkm0_barrier();                                                             \
    MFMA_B(3);                                                                   \
    fence_barrier();                                                             \
  } while (0)

  f32x4 hacc[8];
#pragma unroll
  for (int b = 0; b < 8; ++b) hacc[b] = (f32x4)0.f;

  // ---- big segments: des (s=0), tweet (s=1); K=768 = 24 K-tiles, pipelined ----
#pragma unroll
  for (int s = 0; s < 2; ++s) {
    const int off = (s == 0) ? 785 : 6;
    const unsigned short* wh = Wt + (s == 0 ? OFF_DES_HI : OFF_TW_HI);
    const unsigned short* wl = Wt + (s == 0 ? OFF_DES_LO : OFF_TW_LO);
    const float* bias = (s == 0) ? bdes : btw;

    const float* xr = xrow + off + lg * 8;
    const unsigned short* ph0 = wh + cr0 * 768 + c0 * 8;
    const unsigned short* pl0 = wl + cr0 * 768 + c0 * 8;
    const unsigned short* ph1 = wh + cr1 * 768 + c0 * 8;
    const unsigned short* pl1 = wl + cr1 * 768 + c0 * 8;

    f32x4 zacc[8];
#pragma unroll
    for (int b = 0; b < 8; ++b) zacc[b] = (f32x4)0.f;

    uint4 WA0, WA1, WA2, WA3, WB0, WB1, WB2, WB3;
    f32x4u X0a, X0b, X1a, X1b, X2a, X2b;

    // prologue: W tile 0, X tiles 0..2 (dwordx4 pairs)
    WA0 = *(const uint4*)(ph0); WA1 = *(const uint4*)(pl0);
    WA2 = *(const uint4*)(ph1); WA3 = *(const uint4*)(pl1);
    X0a = *(const f32x4u*)(xr);      X0b = *(const f32x4u*)(xr + 4);
    X1a = *(const f32x4u*)(xr + 32); X1b = *(const f32x4u*)(xr + 36);
    X2a = *(const f32x4u*)(xr + 64); X2b = *(const f32x4u*)(xr + 68);

    for (int base = 0; base < 24; base += 6) {
      TILE(WA0, WA1, WA2, WA3, WB0, WB1, WB2, WB3, X0a, X0b, base + 0);
      TILE(WB0, WB1, WB2, WB3, WA0, WA1, WA2, WA3, X1a, X1b, base + 1);
      TILE(WA0, WA1, WA2, WA3, WB0, WB1, WB2, WB3, X2a, X2b, base + 2);
      TILE(WB0, WB1, WB2, WB3, WA0, WA1, WA2, WA3, X0a, X0b, base + 3);
      TILE(WA0, WA1, WA2, WA3, WB0, WB1, WB2, WB3, X1a, X1b, base + 4);
      TILE(WB0, WB1, WB2, WB3, WA0, WA1, WA2, WA3, X2a, X2b, base + 5);
    }
    Z_EPI(zacc, bias);   // z is wave-private: no barrier needed for z itself
    PHASE_B(s);
  }

  // ---- small segments: num (K=6), cat (K=11); single padded K-tile each ----
#pragma unroll
  for (int u = 0; u < 2; ++u) {
    const int offu = (u == 0) ? 0 : 774;
    const int Ksu = (u == 0) ? 6 : 11;
    const unsigned short* wh = Wt + (u == 0 ? OFF_NUM_HI : OFF_CAT_HI);
    const unsigned short* wl = Wt + (u == 0 ? OFF_NUM_LO : OFF_CAT_LO);
    const float* biasu = (u == 0) ? bnum : bcat;
    const float* xr = xrow + offu + lg * 8;

    uint4 s0 = *(const uint4*)(wh + cr0 * 32 + c0 * 8);
    uint4 s1 = *(const uint4*)(wl + cr0 * 32 + c0 * 8);
    uint4 s2 = *(const uint4*)(wh + cr1 * 32 + c0 * 8);
    uint4 s3 = *(const uint4*)(wl + cr1 * 32 + c0 * 8);
    f32x4u fa = *(const f32x4u*)(xr);
    f32x4u fb = *(const f32x4u*)(xr + 4);
#pragma unroll
    for (int j = 0; j < 4; ++j) {
      if (lg * 8 + j >= Ksu) fa[j] = 0.f;
      if (lg * 8 + 4 + j >= Ksu) fb[j] = 0.f;
    }

    f32x4 zacc[8];
#pragma unroll
    for (int b = 0; b < 8; ++b) zacc[b] = (f32x4)0.f;

    STORE_BT(s0, s1, s2, s3);
    lgkm0_barrier();
    {
      Frag ah_, al_;
      CVT_A2(fa, fb, ah_, al_);
      MFMA8(ah_, al_, zacc);
    }
    fence_barrier();
    Z_EPI(zacc, biasu);
    PHASE_B(u + 2);
  }

  // epilogue: + b_in, PReLU, store (f32 + RNE-bf16 copy for the gather)
#pragma unroll
  for (int ct = 0; ct < 8; ++ct) {
    int col = ct * 16 + li;
    float bi = bin[col];
    float p = pa[col];
#pragma unroll
    for (int r = 0; r < 4; ++r) {
      int node = node0 + w * 16 + lg * 4 + r;
      if (node < NN) {
        float v = hacc[ct][r] + bi;
        v = v >= 0.f ? v : p * v;
        h0[(size_t)node * HD + col] = v;
        h16[(size_t)node * HD + col] = bf16_rne(v);
      }
    }
  }

#undef TILE
#undef MFMA_B
#undef Z_EPI
#undef PHASE_B
}

// ---------------- neighbor-mean gather (bf16 source): halved L3 bytes -----------
// Gather is L3-BW-bound (EE x row bytes). Reading the RNE-bf16 h copy halves the
// per-edge bytes: lane l loads one packed u32 = cols {2l, 2l+1}. Accumulation is
// f32, same edge order as before.
__global__ __launch_bounds__(256) void k_gather(
    const unsigned short* __restrict__ h16, float* __restrict__ aggH,
    const int* __restrict__ row_ptr, const int* __restrict__ cnt2,
    const int* __restrict__ entries) {
  int i = blockIdx.x * 4 + (threadIdx.x >> 6);
  int l = threadIdx.x & 63;
  if (i >= NN) return;
  int rs = row_ptr[i], re = row_ptr[i + 1];
  int c0 = cnt2[i], c1 = cnt2[NN + i];
  float inv0 = 1.f / (float)(c0 > 0 ? c0 : 1);
  float inv1 = 1.f / (float)(c1 > 0 ? c1 : 1);
  float a0 = 0, a1 = 0, b0 = 0, b1 = 0;
  int e = rs;
  for (; e + 3 < re; e += 4) {
    int ent0 = entries[e], ent1 = entries[e + 1];
    int ent2 = entries[e + 2], ent3 = entries[e + 3];
    unsigned int p0 = ((const unsigned int*)(h16 + (size_t)(ent0 & 0xFFFFF) * HD))[l];
    unsigned int p1 = ((const unsigned int*)(h16 + (size_t)(ent1 & 0xFFFFF) * HD))[l];
    unsigned int p2 = ((const unsigned int*)(h16 + (size_t)(ent2 & 0xFFFFF) * HD))[l];
    unsigned int p3 = ((const unsigned int*)(h16 + (size_t)(ent3 & 0xFFFFF) * HD))[l];
    float v0x = __uint_as_float(p0 << 16), v0y = __uint_as_float(p0 & 0xFFFF0000u);
    float v1x = __uint_as_float(p1 << 16), v1y = __uint_as_float(p1 & 0xFFFF0000u);
    float v2x = __uint_as_float(p2 << 16), v2y = __uint_as_float(p2 & 0xFFFF0000u);
    float v3x = __uint_as_float(p3 << 16), v3y = __uint_as_float(p3 & 0xFFFF0000u);
    if (ent0 >> 20) { b0 += v0x; b1 += v0y; } else { a0 += v0x; a1 += v0y; }
    if (ent1 >> 20) { b0 += v1x; b1 += v1y; } else { a0 += v1x; a1 += v1y; }
    if (ent2 >> 20) { b0 += v2x; b1 += v2y; } else { a0 += v2x; a1 += v2y; }
    if (ent3 >> 20) { b0 += v3x; b1 += v3y; } else { a0 += v3x; a1 += v3y; }
  }
  for (; e < re; ++e) {
    int ent = entries[e];
    unsigned int p0 = ((const unsigned int*)(h16 + (size_t)(ent & 0xFFFFF) * HD))[l];
    float v0x = __uint_as_float(p0 << 16), v0y = __uint_as_float(p0 & 0xFFFF0000u);
    if (ent >> 20) { b0 += v0x; b1 += v0y; } else { a0 += v0x; a1 += v0y; }
  }
  float2* p0w = (float2*)(aggH + (size_t)i * HD);
  float2* p1w = (float2*)(aggH + (size_t)NN * HD + (size_t)i * HD);
  p0w[l] = make_float2(a0 * inv0, a1 * inv0);
  p1w[l] = make_float2(b0 * inv1, b1 * inv1);
}

// ---------------- fused layer GEMM: out = [h|aggH0|aggH1] @ [root;rel0;rel1] + b --
// Single K=384 GEMM. Optionally emits the bf16 copy of its output (for the next
// layer's gather); pass h16out=nullptr for the final (classifier-fused) layer.
__global__ __launch_bounds__(256, 4) void k_rgemm2(
    const float* __restrict__ hin, const float* __restrict__ aggH,
    const unsigned short* __restrict__ wl_hi, const unsigned short* __restrict__ wl_lo,
    const float* __restrict__ bias, float* __restrict__ outp,
    unsigned short* __restrict__ h16out) {
  __shared__ unsigned short bt_hi[128 * 32], bt_lo[128 * 32];   // 8KB + 8KB

  const int t = threadIdx.x;
  const int node0 = blockIdx.x * 64;
  const int w = t >> 6, lane = t & 63;
  const int li = lane & 15, lg = lane >> 4;

  const int cr0 = t >> 2, c0 = t & 3;
  const int cr1 = cr0 + 64;
  const unsigned stb0 = cr0 * 64 + ((c0 ^ ((cr0 >> 1) & 3)) << 4);
  const unsigned stb1 = cr1 * 64 + ((c0 ^ ((cr1 >> 1) & 3)) << 4);

  const int rowA = w * 16 + li;
  int nodeA = node0 + rowA;
  int ndA = nodeA < NN ? nodeA : NN - 1;
  const float* a0p = hin + (size_t)ndA * HD + lg * 8;
  const float* a1p = aggH + (size_t)ndA * HD + lg * 8;
  const float* a2p = aggH + (size_t)NN * HD + (size_t)ndA * HD + lg * 8;

// W site pointers: sub-region (kt>>2)*16384, within-region k = (kt&3)*32
#define W2H(KT, CR) (wl_hi + ((KT) >> 2) * 16384 + (CR) * 128 + ((KT) & 3) * 32 + c0 * 8)
#define W2L(KT, CR) (wl_lo + ((KT) >> 2) * 16384 + (CR) * 128 + ((KT) & 3) * 32 + c0 * 8)

#define TILE2(WC0, WC1, WC2, WC3, WN0, WN1, WN2, WN3, XA, XB, T)                 \
  do {                                                                           \
    STORE_BT(WC0, WC1, WC2, WC3);                                                \
    lgkm0_barrier();                                                             \
    Frag ah_, al_;                                                               \
    CVT_A2(XA, XB, ah_, al_);                                                    \
    {                                                                            \
      int kn_ = (T) + 1; if (kn_ > 11) kn_ = 11;                                 \
      WN0 = *(const uint4*)W2H(kn_, cr0); WN1 = *(const uint4*)W2L(kn_, cr0);    \
      WN2 = *(const uint4*)W2H(kn_, cr1); WN3 = *(const uint4*)W2L(kn_, cr1);    \
      int kx_ = (T) + 3; if (kx_ > 11) kx_ = 11;                                 \
      const float* ap_ = (kx_ < 4) ? a0p : (kx_ < 8) ? a1p : a2p;                \
      XA = *(const f32x4u*)(ap_ + (kx_ & 3) * 32);                               \
      XB = *(const f32x4u*)(ap_ + (kx_ & 3) * 32 + 4);                           \
    }                                                                            \
    MFMA8(ah_, al_, acc);                                                        \
    fence_barrier();                                                             \
  } while (0)

  f32x4 acc[8];
#pragma unroll
  for (int b = 0; b < 8; ++b) acc[b] = (f32x4)0.f;

  uint4 WA0, WA1, WA2, WA3, WB0, WB1, WB2, WB3;
  f32x4u X0a, X0b, X1a, X1b, X2a, X2b;

  // prologue: W tile 0, A tiles 0..2
  WA0 = *(const uint4*)W2H(0, cr0); WA1 = *(const uint4*)W2L(0, cr0);
  WA2 = *(const uint4*)W2H(0, cr1); WA3 = *(const uint4*)W2L(0, cr1);
  X0a = *(const f32x4u*)(a0p);      X0b = *(const f32x4u*)(a0p + 4);
  X1a = *(const f32x4u*)(a0p + 32); X1b = *(const f32x4u*)(a0p + 36);
  X2a = *(const f32x4u*)(a0p + 64); X2b = *(const f32x4u*)(a0p + 68);

  TILE2(WA0, WA1, WA2, WA3, WB0, WB1, WB2, WB3, X0a, X0b, 0);
  TILE2(WB0, WB1, WB2, WB3, WA0, WA1, WA2, WA3, X1a, X1b, 1);
  TILE2(WA0, WA1, WA2, WA3, WB0, WB1, WB2, WB3, X2a, X2b, 2);
  TILE2(WB0, WB1, WB2, WB3, WA0, WA1, WA2, WA3, X0a, X0b, 3);
  TILE2(WA0, WA1, WA2, WA3, WB0, WB1, WB2, WB3, X1a, X1b, 4);
  TILE2(WB0, WB1, WB2, WB3, WA0, WA1, WA2, WA3, X2a, X2b, 5);
  TILE2(WA0, WA1, WA2, WA3, WB0, WB1, WB2, WB3, X0a, X0b, 6);
  TILE2(WB0, WB1, WB2, WB3, WA0, WA1, WA2, WA3, X1a, X1b, 7);
  TILE2(WA0, WA1, WA2, WA3, WB0, WB1, WB2, WB3, X2a, X2b, 8);
  TILE2(WB0, WB1, WB2, WB3, WA0, WA1, WA2, WA3, X0a, X0b, 9);
  TILE2(WA0, WA1, WA2, WA3, WB0, WB1, WB2, WB3, X1a, X1b, 10);
  TILE2(WB0, WB1, WB2, WB3, WA0, WA1, WA2, WA3, X2a, X2b, 11);

  // epilogue: + bias, store (and optional bf16 copy)
#pragma unroll
  for (int ct = 0; ct < 8; ++ct) {
    int col = ct * 16 + li;
    float bv = bias[col];
#pragma unroll
    for (int r = 0; r < 4; ++r) {
      int node = node0 + w * 16 + lg * 4 + r;
      if (node < NN) {
        float v = acc[ct][r] + bv;
        outp[(size_t)node * HD + col] = v;
        if (h16out) h16out[(size_t)node * HD + col] = bf16_rne(v);
      }
    }
  }

#undef W2H
#undef W2L
#undef TILE2
}

extern "C" void kernel_launch(void* const* d_in, const int* in_sizes, int n_in,
                              void* d_out, int out_size, void* d_ws, size_t ws_size,
                              hipStream_t stream) {
  const float* x    = (const float*)d_in[0];
  const int* ei     = (const int*)d_in[1];
  const int* et     = (const int*)d_in[2];
  const float* Wdes = (const float*)d_in[3];
  const float* bdes = (const float*)d_in[4];
  const float* Wtw  = (const float*)d_in[5];
  const float* btw  = (const float*)d_in[6];
  const float* Wnum = (const float*)d_in[7];
  const float* bnum = (const float*)d_in[8];
  const float* Wcat = (const float*)d_in[9];
  const float* bcat = (const float*)d_in[10];
  const float* Win  = (const float*)d_in[11];
  const float* bin  = (const float*)d_in[12];
  const float* pa   = (const float*)d_in[13];
  const float* root1 = (const float*)d_in[14];
  const float* rel1  = (const float*)d_in[15];
  const float* bias1 = (const float*)d_in[16];
  const float* root2 = (const float*)d_in[17];
  const float* rel2  = (const float*)d_in[18];
  const float* bias2 = (const float*)d_in[19];
  const float* Wcls  = (const float*)d_in[20];
  const float* bcls  = (const float*)d_in[21];
  float* out = (float*)d_out;

  char* p = (char*)d_ws;
  float* aggH = (float*)p;    p += (size_t)2 * NN * HD * 4;   // 102.4 MB
  float* hB = (float*)p;      p += (size_t)NN * HD * 4;       // 51.2 MB
  int* row_ptr = (int*)p;     p += ((size_t)NN + 4) * 4;
  int* cnt2 = (int*)p;        p += (size_t)2 * NN * 4;
  int* fillpos = (int*)p;     p += (size_t)NN * 4;
  int* entries = (int*)p;     p += (size_t)EE * 4;
  int* bsum = (int*)p;        p += 512;
  float* bfused = (float*)p;  p += 512;
  unsigned short* h16 = (unsigned short*)p; p += (size_t)NN * HD * 2;  // 25.6 MB
  unsigned short* Wt = (unsigned short*)p;  p += (size_t)WT_SITES * 2 * 2;

  // zero counters first (cnt2 + fillpos)
  (void)hipMemsetAsync(cnt2, 0, (size_t)3 * NN * 4, stream);
  // setup: weight pre-convert (blocks 0..1503) + edge count (blocks 1504..) fused
  k_setup<<<PREPW_BLOCKS + COUNT_BLOCKS, 256, 0, stream>>>(
      Wdes, Wtw, Wnum, Wcat, Win, root1, rel1, root2, rel2, Wcls, Wt,
      ei, et, cnt2);
  // classifier fusion: overwrite OFF_L2 with [root2;rel2]@Wcls, bfused = b2@Wcls+bcls
  k_fusew<<<385, 128, 0, stream>>>(root2, rel2, Wcls, bias2, bcls, Wt, bfused);

  // CSR scans
  int nb = (NN + 1023) / 1024;
  k_scan1<<<nb, 256, 0, stream>>>(cnt2, row_ptr, bsum);
  k_scan2<<<1, 128, 0, stream>>>(bsum, nb);
  k_scan3<<<(NN + 1 + 255) / 256, 256, 0, stream>>>(row_ptr, bsum);

  // h0 -> d_out (+ h16 bf16 copy), with CSR fill fused in (blocks >= PROJ_NBLK)
  k_proj2<<<PROJ_NBLK + FILL_BLOCKS, 256, 0, stream>>>(
      x, bdes, btw, bnum, bcat, bin, pa, Wt, out, h16,
      ei, et, row_ptr, fillpos, entries);
  // layer 1: gather neighbor means (bf16 source), then fused K=384 GEMM -> hB
  // (rgemm2 also refreshes h16 from hB for the layer-2 gather)
  k_gather<<<NN / 4, 256, 0, stream>>>(h16, aggH, row_ptr, cnt2, entries);
  k_rgemm2<<<PROJ_NBLK, 256, 0, stream>>>(out, aggH, Wt + OFF_L1_HI, Wt + OFF_L1_LO,
                                          bias1, hB, h16);
  // layer 2 + classifier (algebraically fused): out = [hB|agg] @ (W2@Wcls) + bfused
  k_gather<<<NN / 4, 256, 0, stream>>>(h16, aggH, row_ptr, cnt2, entries);
  k_rgemm2<<<PROJ_NBLK, 256, 0, stream>>>(hB, aggH, Wt + OFF_L2_HI, Wt + OFF_L2_LO,
                                          bfused, out, (unsigned short*)nullptr);
}

// Round 13
// 841.785 us; speedup vs baseline: 1.5782x; 1.0299x over previous
//
#include <hip/hip_runtime.h>
#include <cstdint>
#include <cstddef>

#define NN 100000
#define EE 1600000
#define XDIM 1553
#define HD 128

typedef __attribute__((ext_vector_type(8))) short short8;
typedef __attribute__((ext_vector_type(4))) float f32x4;
// unaligned-capable 4-float vector: hardware allows 4B-aligned dwordx4
typedef float f32x4u __attribute__((vector_size(16), aligned(4)));

union Frag { unsigned int u[4]; short8 s; uint4 v; };

// weight area offsets (ushort units); hi/lo are separate regions
#define OFF_DES_HI 0
#define OFF_DES_LO 98304
#define OFF_TW_HI  196608
#define OFF_TW_LO  294912
#define OFF_NUM_HI 393216
#define OFF_NUM_LO 397312
#define OFF_CAT_HI 401408
#define OFF_CAT_LO 405504
#define OFF_WIN_HI 409600
#define OFF_WIN_LO 475136
#define OFF_L1_HI  540672
#define OFF_L1_LO  589824
#define OFF_L2_HI  638976
#define OFF_L2_LO  688128
#define OFF_CLS_HI 737280
#define OFF_CLS_LO 753664
#define WT_SITES   385024   // (col,k) sites; each writes hi+lo

#define PREPW_BLOCKS 1504   // WT_SITES / 256
#define COUNT_BLOCKS 6250   // EE / 256
#define NBLK64       1563   // (NN + 63) / 64   (rgemm2 grid)
#define PROJ128_NBLK 782    // (NN + 127) / 128 (proj grid)
#define FILL_BLOCKS  6250   // EE / 256

// hi = trunc-bf16(f), lo = trunc-bf16(f - hi). Packed: 2 elems -> 1 u32 via v_perm.
__device__ __forceinline__ void cvt_pair(float f0, float f1,
                                         unsigned int& hi, unsigned int& lo) {
  unsigned int u0 = __float_as_uint(f0), u1 = __float_as_uint(f1);
  hi = __builtin_amdgcn_perm(u1, u0, 0x07060302u);
  float l0 = f0 - __uint_as_float(u0 & 0xFFFF0000u);
  float l1 = f1 - __uint_as_float(u1 & 0xFFFF0000u);
  lo = __builtin_amdgcn_perm(__float_as_uint(l1), __float_as_uint(l0), 0x07060302u);
}

// round-to-nearest-even bf16 (for the gather-side low-precision h copy)
__device__ __forceinline__ unsigned short bf16_rne(float f) {
  unsigned int u = __float_as_uint(f);
  return (unsigned short)((u + 0x7FFFu + ((u >> 16) & 1u)) >> 16);
}

// raw barriers: no vmcnt drain (prefetched global loads ride across);
// lgkm0 variant publishes ds_writes before the barrier.
__device__ __forceinline__ void fence_barrier() {
  asm volatile("" ::: "memory");
  __builtin_amdgcn_s_barrier();
  asm volatile("" ::: "memory");
}
__device__ __forceinline__ void lgkm0_barrier() {
  asm volatile("s_waitcnt lgkmcnt(0)" ::: "memory");
  __builtin_amdgcn_s_barrier();
  asm volatile("" ::: "memory");
}

// ---------------- setup: weight pre-convert/transpose + edge count (fused) ------
__global__ __launch_bounds__(256) void k_setup(
    const float* __restrict__ Wdes, const float* __restrict__ Wtw,
    const float* __restrict__ Wnum, const float* __restrict__ Wcat,
    const float* __restrict__ Win,  const float* __restrict__ root1,
    const float* __restrict__ rel1, const float* __restrict__ root2,
    const float* __restrict__ rel2, const float* __restrict__ Wcls,
    unsigned short* __restrict__ Wt,
    const int* __restrict__ ei, const int* __restrict__ et,
    int* __restrict__ cnt2) {
  if (blockIdx.x >= PREPW_BLOCKS) {
    int e = (blockIdx.x - PREPW_BLOCKS) * 256 + threadIdx.x;
    if (e < EE) atomicAdd(&cnt2[et[e] * NN + ei[EE + e]], 1);
    return;
  }
  int id = blockIdx.x * 256 + threadIdx.x;
  if (id >= WT_SITES) return;
  const float* src; int K, Kpad, dhi, dlo, local;
  if (id < 98304)       { src=Wdes;        K=768; Kpad=768; dhi=OFF_DES_HI;       dlo=OFF_DES_LO;       local=id; }
  else if (id < 196608) { src=Wtw;         K=768; Kpad=768; dhi=OFF_TW_HI;        dlo=OFF_TW_LO;        local=id-98304; }
  else if (id < 200704) { src=Wnum;        K=6;   Kpad=32;  dhi=OFF_NUM_HI;       dlo=OFF_NUM_LO;       local=id-196608; }
  else if (id < 204800) { src=Wcat;        K=11;  Kpad=32;  dhi=OFF_CAT_HI;       dlo=OFF_CAT_LO;       local=id-200704; }
  else if (id < 270336) { src=Win;         K=512; Kpad=512; dhi=OFF_WIN_HI;       dlo=OFF_WIN_LO;       local=id-204800; }
  else if (id < 286720) { src=root1;       K=128; Kpad=128; dhi=OFF_L1_HI;        dlo=OFF_L1_LO;        local=id-270336; }
  else if (id < 303104) { src=rel1;        K=128; Kpad=128; dhi=OFF_L1_HI+16384;  dlo=OFF_L1_LO+16384;  local=id-286720; }
  else if (id < 319488) { src=rel1+16384;  K=128; Kpad=128; dhi=OFF_L1_HI+32768;  dlo=OFF_L1_LO+32768;  local=id-303104; }
  else if (id < 335872) { src=root2;       K=128; Kpad=128; dhi=OFF_L2_HI;        dlo=OFF_L2_LO;        local=id-319488; }
  else if (id < 352256) { src=rel2;        K=128; Kpad=128; dhi=OFF_L2_HI+16384;  dlo=OFF_L2_LO+16384;  local=id-335872; }
  else if (id < 368640) { src=rel2+16384;  K=128; Kpad=128; dhi=OFF_L2_HI+32768;  dlo=OFF_L2_LO+32768;  local=id-352256; }
  else                  { src=Wcls;        K=128; Kpad=128; dhi=OFF_CLS_HI;       dlo=OFF_CLS_LO;       local=id-368640; }
  int col = local / Kpad;
  int k = local - col * Kpad;
  float v = (k < K) ? src[(size_t)k * 128 + col] : 0.f;
  unsigned int u = __float_as_uint(v);
  float lo = v - __uint_as_float(u & 0xFFFF0000u);
  Wt[dhi + col * Kpad + k] = (unsigned short)(u >> 16);
  Wt[dlo + col * Kpad + k] = (unsigned short)(__float_as_uint(lo) >> 16);
}

// ---------------- classifier fusion: Wfused = [root2;rel2] @ Wcls (K-stacked) ----
__global__ __launch_bounds__(128) void k_fusew(
    const float* __restrict__ root2, const float* __restrict__ rel2,
    const float* __restrict__ Wcls,  const float* __restrict__ bias2,
    const float* __restrict__ bcls,  unsigned short* __restrict__ Wt,
    float* __restrict__ bfused) {
  int k = blockIdx.x;
  int c = threadIdx.x;
  const float* wrow;
  if (k < 128)      wrow = root2 + (size_t)k * 128;
  else if (k < 256) wrow = rel2 + (size_t)(k - 128) * 128;
  else if (k < 384) wrow = rel2 + 16384 + (size_t)(k - 256) * 128;
  else              wrow = bias2;
  float s = 0.f;
  for (int j = 0; j < 128; ++j) s += wrow[j] * Wcls[(size_t)j * 128 + c];
  if (k == 384) { bfused[c] = s + bcls[c]; return; }
  unsigned int u = __float_as_uint(s);
  float lo = s - __uint_as_float(u & 0xFFFF0000u);
  int sub = k >> 7, kl = k & 127;
  Wt[OFF_L2_HI + sub * 16384 + c * 128 + kl] = (unsigned short)(u >> 16);
  Wt[OFF_L2_LO + sub * 16384 + c * 128 + kl] = (unsigned short)(__float_as_uint(lo) >> 16);
}

// ---------------- CSR scans ----------------
__global__ __launch_bounds__(256) void k_scan1(const int* __restrict__ cnt2,
                                               int* __restrict__ row_ptr,
                                               int* __restrict__ bsum) {
  __shared__ int sums[256];
  int t = threadIdx.x;
  int base = blockIdx.x * 1024 + t * 4;
  int v[4]; int s = 0;
#pragma unroll
  for (int j = 0; j < 4; ++j) {
    int idx = base + j;
    v[j] = (idx < NN) ? (cnt2[idx] + cnt2[NN + idx]) : 0;
    s += v[j];
  }
  sums[t] = s;
  __syncthreads();
  for (int d = 1; d < 256; d <<= 1) {
    int val = (t >= d) ? sums[t - d] : 0;
    __syncthreads();
    sums[t] += val;
    __syncthreads();
  }
  int excl = sums[t] - s;
  if (t == 255) bsum[blockIdx.x] = sums[t];
  int run = excl;
#pragma unroll
  for (int j = 0; j < 4; ++j) {
    int idx = base + j;
    if (idx < NN) row_ptr[idx] = run;
    run += v[j];
  }
}

__global__ __launch_bounds__(128) void k_scan2(int* __restrict__ bsum, int nb) {
  __shared__ int s[128];
  int t = threadIdx.x;
  int v = (t < nb) ? bsum[t] : 0;
  s[t] = v;
  __syncthreads();
  for (int d = 1; d < 128; d <<= 1) {
    int val = (t >= d) ? s[t - d] : 0;
    __syncthreads();
    s[t] += val;
    __syncthreads();
  }
  if (t < nb) bsum[t] = s[t] - v;
}

__global__ __launch_bounds__(256) void k_scan3(int* __restrict__ row_ptr,
                                               const int* __restrict__ bsum) {
  int idx = blockIdx.x * 256 + threadIdx.x;
  if (idx < NN) row_ptr[idx] += bsum[idx >> 10];
  if (idx == NN) row_ptr[NN] = EE;
}

// ---------------- fused projection + CSR fill (MFMA, split-bf16, raw barriers) ---
// Blocks 0..781: 128 nodes/block, 4 waves, wave = 32 rows (2 subs) x 128 cols.
// LDS B-read bytes per row HALVE vs 16-row waves (the dominant cost). Register
// budget trimmed to fit gfx950's unified 256 VGPR+AGPR cap for 2 waves/SIMD:
// zacc+hacc = 128 AGPR; X prefetch depth-2 (not 3); W ping-pong. LDS 80KB ->
// 2 blocks/CU. Blocks >= 782: CSR fill. Epilogue emits h0 (f32) + h16 (bf16).
__global__ __launch_bounds__(256, 2) void k_proj2(
    const float* __restrict__ x,
    const float* __restrict__ bdes, const float* __restrict__ btw,
    const float* __restrict__ bnum, const float* __restrict__ bcat,
    const float* __restrict__ bin,  const float* __restrict__ pa,
    const unsigned short* __restrict__ Wt, float* __restrict__ h0,
    unsigned short* __restrict__ h16,
    const int* __restrict__ ei, const int* __restrict__ et,
    const int* __restrict__ row_ptr, int* __restrict__ fillpos,
    int* __restrict__ entries) {
  __shared__ unsigned short bt_hi[128 * 32], bt_lo[128 * 32];   // 8KB + 8KB
  __shared__ unsigned short z_hi[128 * 128], z_lo[128 * 128];   // 32KB + 32KB

  if (blockIdx.x >= PROJ128_NBLK) {
    int e = (blockIdx.x - PROJ128_NBLK) * 256 + threadIdx.x;
    if (e < EE) {
      int src = ei[e];
      int dst = ei[EE + e];
      int r = et[e];
      int pos = atomicAdd(&fillpos[dst], 1);
      entries[row_ptr[dst] + pos] = src | (r << 20);
    }
    return;
  }

  const int t = threadIdx.x;
  const int node0 = blockIdx.x * 128;
  const int w = t >> 6, lane = t & 63;
  const int li = lane & 15, lg = lane >> 4;

  // B-staging constants (loop-invariant per thread)
  const int cr0 = t >> 2, c0 = t & 3;
  const int cr1 = cr0 + 64;
  const unsigned stb0 = cr0 * 64 + ((c0 ^ ((cr0 >> 1) & 3)) << 4);
  const unsigned stb1 = cr1 * 64 + ((c0 ^ ((cr1 >> 1) & 3)) << 4);

  // two A-rows per (wave, li): sub0 = w*32+li, sub1 = +16
  const int rowA0 = w * 32 + li;
  const int rowA1 = rowA0 + 16;
  int nodeA0 = node0 + rowA0; int nd0 = nodeA0 < NN ? nodeA0 : NN - 1;
  int nodeA1 = node0 + rowA1; int nd1 = nodeA1 < NN ? nodeA1 : NN - 1;
  const float* xrow0 = x + (size_t)nd0 * XDIM;
  const float* xrow1 = x + (size_t)nd1 * XDIM;

#define STORE_BT(SH0, SL0, SH1, SL1)              \
  do {                                            \
    *(uint4*)((char*)bt_hi + stb0) = (SH0);       \
    *(uint4*)((char*)bt_lo + stb0) = (SL0);       \
    *(uint4*)((char*)bt_hi + stb1) = (SH1);       \
    *(uint4*)((char*)bt_lo + stb1) = (SL1);       \
  } while (0)

#define CVT_A2(FA, FB, AH, AL)                                                   \
  do {                                                                           \
    cvt_pair((FA)[0], (FA)[1], (AH).u[0], (AL).u[0]);                            \
    cvt_pair((FA)[2], (FA)[3], (AH).u[1], (AL).u[1]);                            \
    cvt_pair((FB)[0], (FB)[1], (AH).u[2], (AL).u[2]);                            \
    cvt_pair((FB)[2], (FB)[3], (AH).u[3], (AL).u[3]);                            \
  } while (0)

// 8 col-tiles; B frags read ONCE, used by both subs (the whole point).
#define MFMA8_2(A0H, A0L, A1H, A1L, ACC)                                         \
  do {                                                                           \
    _Pragma("unroll")                                                            \
    for (int ct_ = 0; ct_ < 8; ++ct_) {                                          \
      int colrow_ = ct_ * 16 + li;                                               \
      int byte_ = colrow_ * 64 + (lg << 4);                                      \
      byte_ ^= ((colrow_ >> 1) & 3) << 4;                                        \
      Frag bh_, bl_;                                                             \
      bh_.v = *(const uint4*)((char*)bt_hi + byte_);                             \
      bl_.v = *(const uint4*)((char*)bt_lo + byte_);                             \
      (ACC)[0][ct_] = __builtin_amdgcn_mfma_f32_16x16x32_bf16((A0H).s, bl_.s, (ACC)[0][ct_], 0, 0, 0); \
      (ACC)[0][ct_] = __builtin_amdgcn_mfma_f32_16x16x32_bf16((A0L).s, bh_.s, (ACC)[0][ct_], 0, 0, 0); \
      (ACC)[0][ct_] = __builtin_amdgcn_mfma_f32_16x16x32_bf16((A0H).s, bh_.s, (ACC)[0][ct_], 0, 0, 0); \
      (ACC)[1][ct_] = __builtin_amdgcn_mfma_f32_16x16x32_bf16((A1H).s, bl_.s, (ACC)[1][ct_], 0, 0, 0); \
      (ACC)[1][ct_] = __builtin_amdgcn_mfma_f32_16x16x32_bf16((A1L).s, bh_.s, (ACC)[1][ct_], 0, 0, 0); \
      (ACC)[1][ct_] = __builtin_amdgcn_mfma_f32_16x16x32_bf16((A1H).s, bh_.s, (ACC)[1][ct_], 0, 0, 0); \
    }                                                                            \
  } while (0)

// one K-tile of phase A: store W tile (cur), barrier, convert X (both subs),
// prefetch W(T+1, next buf) + X(T+2, back into the same X bufs), MFMA, barrier.
#define TILE(WC0, WC1, WC2, WC3, WN0, WN1, WN2, WN3, XA0, XB0, XA1, XB1, T)      \
  do {                                                                           \
    STORE_BT(WC0, WC1, WC2, WC3);                                                \
    lgkm0_barrier();                                                             \
    Frag a0h_, a0l_, a1h_, a1l_;                                                 \
    CVT_A2(XA0, XB0, a0h_, a0l_);                                                \
    CVT_A2(XA1, XB1, a1h_, a1l_);                                                \
    {                                                                            \
      const int kw_ = ((T) + 1) * 32;                                            \
      WN0 = *(const uint4*)(ph0 + kw_); WN1 = *(const uint4*)(pl0 + kw_);        \
      WN2 = *(const uint4*)(ph1 + kw_); WN3 = *(const uint4*)(pl1 + kw_);        \
      int kx_ = (T) + 2; if (kx_ > 23) kx_ = 23; kx_ *= 32;                      \
      XA0 = *(const f32x4u*)(xr0 + kx_);                                         \
      XB0 = *(const f32x4u*)(xr0 + kx_ + 4);                                     \
      XA1 = *(const f32x4u*)(xr1 + kx_);                                         \
      XB1 = *(const f32x4u*)(xr1 + kx_ + 4);                                     \
    }                                                                            \
    MFMA8_2(a0h_, a0l_, a1h_, a1l_, zacc);                                       \
    fence_barrier();                                                             \
  } while (0)

#define MFMA_B(KT)                                                               \
  do {                                                                           \
    Frag a0h_, a0l_, a1h_, a1l_;                                                 \
    {                                                                            \
      int byte0_ = rowA0 * 256 + (((KT) * 32 + lg * 8) << 1);                    \
      byte0_ ^= (rowA0 & 7) << 4;                                                \
      a0h_.v = *(const uint4*)((char*)z_hi + byte0_);                            \
      a0l_.v = *(const uint4*)((char*)z_lo + byte0_);                            \
      int byte1_ = rowA1 * 256 + (((KT) * 32 + lg * 8) << 1);                    \
      byte1_ ^= (rowA1 & 7) << 4;                                                \
      a1h_.v = *(const uint4*)((char*)z_hi + byte1_);                            \
      a1l_.v = *(const uint4*)((char*)z_lo + byte1_);                            \
    }                                                                            \
    MFMA8_2(a0h_, a0l_, a1h_, a1l_, hacc);                                       \
  } while (0)

#define Z_EPI(ZACC, BIASP)                                                       \
  do {                                                                           \
    _Pragma("unroll")                                                            \
    for (int ct_ = 0; ct_ < 8; ++ct_) {                                          \
      int col_ = ct_ * 16 + li;                                                  \
      float bv_ = (BIASP)[col_];                                                 \
      _Pragma("unroll")                                                          \
      for (int sub_ = 0; sub_ < 2; ++sub_) {                                     \
        _Pragma("unroll")                                                        \
        for (int r_ = 0; r_ < 4; ++r_) {                                         \
          float v_ = (ZACC)[sub_][ct_][r_] + bv_;                                \
          v_ = v_ >= 0.f ? v_ : 0.01f * v_;                                      \
          int row_ = w * 32 + sub_ * 16 + lg * 4 + r_;                           \
          int byte_ = row_ * 256 + col_ * 2;                                     \
          byte_ ^= (row_ & 7) << 4;                                              \
          unsigned int u_ = __float_as_uint(v_);                                 \
          *(unsigned short*)((char*)z_hi + byte_) = (unsigned short)(u_ >> 16);  \
          float lo_ = v_ - __uint_as_float(u_ & 0xFFFF0000u);                    \
          *(unsigned short*)((char*)z_lo + byte_) = (unsigned short)(__float_as_uint(lo_) >> 16); \
        }                                                                        \
      }                                                                          \
    }                                                                            \
  } while (0)

// phase B: hacc += z @ Win[SLICE*128 .. +127], 4 K-tiles, fully unrolled,
// 1-deep prefetch of the next Win tile.
#define PHASE_B(SLICE)                                                           \
  do {                                                                           \
    const unsigned short* qh0_ = Wt + OFF_WIN_HI + cr0 * 512 + (SLICE) * 128 + c0 * 8; \
    const unsigned short* ql0_ = Wt + OFF_WIN_LO + cr0 * 512 + (SLICE) * 128 + c0 * 8; \
    const unsigned short* qh1_ = Wt + OFF_WIN_HI + cr1 * 512 + (SLICE) * 128 + c0 * 8; \
    const unsigned short* ql1_ = Wt + OFF_WIN_LO + cr1 * 512 + (SLICE) * 128 + c0 * 8; \
    uint4 wA0_ = *(const uint4*)(qh0_), wA1_ = *(const uint4*)(ql0_);            \
    uint4 wA2_ = *(const uint4*)(qh1_), wA3_ = *(const uint4*)(ql1_);            \
    uint4 wB0_, wB1_, wB2_, wB3_;                                                \
    STORE_BT(wA0_, wA1_, wA2_, wA3_);                                            \
    lgkm0_barrier();                                                             \
    wB0_ = *(const uint4*)(qh0_ + 32); wB1_ = *(const uint4*)(ql0_ + 32);        \
    wB2_ = *(const uint4*)(qh1_ + 32); wB3_ = *(const uint4*)(ql1_ + 32);        \
    MFMA_B(0);                                                                   \
    fence_barrier();                                                             \
    STORE_BT(wB0_, wB1_, wB2_, wB3_);                                            \
    lgkm0_barrier();                                                             \
    wA0_ = *(const uint4*)(qh0_ + 64); wA1_ = *(const uint4*)(ql0_ + 64);        \
    wA2_ = *(const uint4*)(qh1_ + 64); wA3_ = *(const uint4*)(ql1_ + 64);        \
    MFMA_B(1);                                                                   \
    fence_barrier();                                                             \
    STORE_BT(wA0_, wA1_, wA2_, wA3_);                                            \
    lgkm0_barrier();                                                             \
    wB0_ = *(const uint4*)(qh0_ + 96); wB1_ = *(const uint4*)(ql0_ + 96);        \
    wB2_ = *(const uint4*)(qh1_ + 96); wB3_ = *(const uint4*)(ql1_ + 96);        \
    MFMA_B(2);                                                                   \
    fence_barrier();                                                             \
    STORE_BT(wB0_, wB1_, wB2_, wB3_);                                            \
    lgkm0_barrier();                                                             \
    MFMA_B(3);                                                                   \
    fence_barrier();                                                             \
  } while (0)

  f32x4 hacc[2][8];
#pragma unroll
  for (int a = 0; a < 2; ++a)
#pragma unroll
    for (int b = 0; b < 8; ++b) hacc[a][b] = (f32x4)0.f;

  // ---- big segments: des (s=0), tweet (s=1); K=768 = 24 K-tiles, pipelined ----
#pragma unroll
  for (int s = 0; s < 2; ++s) {
    const int off = (s == 0) ? 785 : 6;
    const unsigned short* wh = Wt + (s == 0 ? OFF_DES_HI : OFF_TW_HI);
    const unsigned short* wl = Wt + (s == 0 ? OFF_DES_LO : OFF_TW_LO);
    const float* bias = (s == 0) ? bdes : btw;

    const float* xr0 = xrow0 + off + lg * 8;
    const float* xr1 = xrow1 + off + lg * 8;
    const unsigned short* ph0 = wh + cr0 * 768 + c0 * 8;
    const unsigned short* pl0 = wl + cr0 * 768 + c0 * 8;
    const unsigned short* ph1 = wh + cr1 * 768 + c0 * 8;
    const unsigned short* pl1 = wl + cr1 * 768 + c0 * 8;

    f32x4 zacc[2][8];
#pragma unroll
    for (int a = 0; a < 2; ++a)
#pragma unroll
      for (int b = 0; b < 8; ++b) zacc[a][b] = (f32x4)0.f;

    uint4 WA0, WA1, WA2, WA3, WB0, WB1, WB2, WB3;
    f32x4u X0a0, X0b0, X0a1, X0b1, X1a0, X1b0, X1a1, X1b1;

    // prologue: W tile 0, X tiles 0..1 (depth-2 ping-pong)
    WA0 = *(const uint4*)(ph0); WA1 = *(const uint4*)(pl0);
    WA2 = *(const uint4*)(ph1); WA3 = *(const uint4*)(pl1);
    X0a0 = *(const f32x4u*)(xr0);      X0b0 = *(const f32x4u*)(xr0 + 4);
    X0a1 = *(const f32x4u*)(xr1);      X0b1 = *(const f32x4u*)(xr1 + 4);
    X1a0 = *(const f32x4u*)(xr0 + 32); X1b0 = *(const f32x4u*)(xr0 + 36);
    X1a1 = *(const f32x4u*)(xr1 + 32); X1b1 = *(const f32x4u*)(xr1 + 36);

    for (int base = 0; base < 24; base += 2) {
      TILE(WA0, WA1, WA2, WA3, WB0, WB1, WB2, WB3, X0a0, X0b0, X0a1, X0b1, base + 0);
      TILE(WB0, WB1, WB2, WB3, WA0, WA1, WA2, WA3, X1a0, X1b0, X1a1, X1b1, base + 1);
    }
    Z_EPI(zacc, bias);   // z slots are wave-private
    PHASE_B(s);
  }

  // ---- small segments: num (K=6), cat (K=11); single padded K-tile each ----
#pragma unroll
  for (int u = 0; u < 2; ++u) {
    const int offu = (u == 0) ? 0 : 774;
    const int Ksu = (u == 0) ? 6 : 11;
    const unsigned short* wh = Wt + (u == 0 ? OFF_NUM_HI : OFF_CAT_HI);
    const unsigned short* wl = Wt + (u == 0 ? OFF_NUM_LO : OFF_CAT_LO);
    const float* biasu = (u == 0) ? bnum : bcat;
    const float* xr0 = xrow0 + offu + lg * 8;
    const float* xr1 = xrow1 + offu + lg * 8;

    uint4 s0 = *(const uint4*)(wh + cr0 * 32 + c0 * 8);
    uint4 s1 = *(const uint4*)(wl + cr0 * 32 + c0 * 8);
    uint4 s2 = *(const uint4*)(wh + cr1 * 32 + c0 * 8);
    uint4 s3 = *(const uint4*)(wl + cr1 * 32 + c0 * 8);
    f32x4u fa0 = *(const f32x4u*)(xr0);
    f32x4u fb0 = *(const f32x4u*)(xr0 + 4);
    f32x4u fa1 = *(const f32x4u*)(xr1);
    f32x4u fb1 = *(const f32x4u*)(xr1 + 4);
#pragma unroll
    for (int j = 0; j < 4; ++j) {
      if (lg * 8 + j >= Ksu) { fa0[j] = 0.f; fa1[j] = 0.f; }
      if (lg * 8 + 4 + j >= Ksu) { fb0[j] = 0.f; fb1[j] = 0.f; }
    }

    f32x4 zacc[2][8];
#pragma unroll
    for (int a = 0; a < 2; ++a)
#pragma unroll
      for (int b = 0; b < 8; ++b) zacc[a][b] = (f32x4)0.f;

    STORE_BT(s0, s1, s2, s3);
    lgkm0_barrier();
    {
      Frag a0h_, a0l_, a1h_, a1l_;
      CVT_A2(fa0, fb0, a0h_, a0l_);
      CVT_A2(fa1, fb1, a1h_, a1l_);
      MFMA8_2(a0h_, a0l_, a1h_, a1l_, zacc);
    }
    fence_barrier();
    Z_EPI(zacc, biasu);
    PHASE_B(u + 2);
  }

  // epilogue: + b_in, PReLU, store (f32 + RNE-bf16 copy for the gather)
#pragma unroll
  for (int ct = 0; ct < 8; ++ct) {
    int col = ct * 16 + li;
    float bi = bin[col];
    float p = pa[col];
#pragma unroll
    for (int sub = 0; sub < 2; ++sub) {
#pragma unroll
      for (int r = 0; r < 4; ++r) {
        int node = node0 + w * 32 + sub * 16 + lg * 4 + r;
        if (node < NN) {
          float v = hacc[sub][ct][r] + bi;
          v = v >= 0.f ? v : p * v;
          h0[(size_t)node * HD + col] = v;
          h16[(size_t)node * HD + col] = bf16_rne(v);
        }
      }
    }
  }

#undef TILE
#undef MFMA_B
#undef Z_EPI
#undef PHASE_B
#undef MFMA8_2
}

// ---------------- neighbor-mean gather (bf16 source): halved L3 bytes -----------
__global__ __launch_bounds__(256) void k_gather(
    const unsigned short* __restrict__ h16, float* __restrict__ aggH,
    const int* __restrict__ row_ptr, const int* __restrict__ cnt2,
    const int* __restrict__ entries) {
  int i = blockIdx.x * 4 + (threadIdx.x >> 6);
  int l = threadIdx.x & 63;
  if (i >= NN) return;
  int rs = row_ptr[i], re = row_ptr[i + 1];
  int c0 = cnt2[i], c1 = cnt2[NN + i];
  float inv0 = 1.f / (float)(c0 > 0 ? c0 : 1);
  float inv1 = 1.f / (float)(c1 > 0 ? c1 : 1);
  float a0 = 0, a1 = 0, b0 = 0, b1 = 0;
  int e = rs;
  for (; e + 3 < re; e += 4) {
    int ent0 = entries[e], ent1 = entries[e + 1];
    int ent2 = entries[e + 2], ent3 = entries[e + 3];
    unsigned int p0 = ((const unsigned int*)(h16 + (size_t)(ent0 & 0xFFFFF) * HD))[l];
    unsigned int p1 = ((const unsigned int*)(h16 + (size_t)(ent1 & 0xFFFFF) * HD))[l];
    unsigned int p2 = ((const unsigned int*)(h16 + (size_t)(ent2 & 0xFFFFF) * HD))[l];
    unsigned int p3 = ((const unsigned int*)(h16 + (size_t)(ent3 & 0xFFFFF) * HD))[l];
    float v0x = __uint_as_float(p0 << 16), v0y = __uint_as_float(p0 & 0xFFFF0000u);
    float v1x = __uint_as_float(p1 << 16), v1y = __uint_as_float(p1 & 0xFFFF0000u);
    float v2x = __uint_as_float(p2 << 16), v2y = __uint_as_float(p2 & 0xFFFF0000u);
    float v3x = __uint_as_float(p3 << 16), v3y = __uint_as_float(p3 & 0xFFFF0000u);
    if (ent0 >> 20) { b0 += v0x; b1 += v0y; } else { a0 += v0x; a1 += v0y; }
    if (ent1 >> 20) { b0 += v1x; b1 += v1y; } else { a0 += v1x; a1 += v1y; }
    if (ent2 >> 20) { b0 += v2x; b1 += v2y; } else { a0 += v2x; a1 += v2y; }
    if (ent3 >> 20) { b0 += v3x; b1 += v3y; } else { a0 += v3x; a1 += v3y; }
  }
  for (; e < re; ++e) {
    int ent = entries[e];
    unsigned int p0 = ((const unsigned int*)(h16 + (size_t)(ent & 0xFFFFF) * HD))[l];
    float v0x = __uint_as_float(p0 << 16), v0y = __uint_as_float(p0 & 0xFFFF0000u);
    if (ent >> 20) { b0 += v0x; b1 += v0y; } else { a0 += v0x; a1 += v0y; }
  }
  float2* p0w = (float2*)(aggH + (size_t)i * HD);
  float2* p1w = (float2*)(aggH + (size_t)NN * HD + (size_t)i * HD);
  p0w[l] = make_float2(a0 * inv0, a1 * inv0);
  p1w[l] = make_float2(b0 * inv1, b1 * inv1);
}

// ---------------- fused layer GEMM: out = [h|aggH0|aggH1] @ [root;rel0;rel1] + b --
__global__ __launch_bounds__(256, 4) void k_rgemm2(
    const float* __restrict__ hin, const float* __restrict__ aggH,
    const unsigned short* __restrict__ wl_hi, const unsigned short* __restrict__ wl_lo,
    const float* __restrict__ bias, float* __restrict__ outp,
    unsigned short* __restrict__ h16out) {
  __shared__ unsigned short bt_hi[128 * 32], bt_lo[128 * 32];   // 8KB + 8KB

  const int t = threadIdx.x;
  const int node0 = blockIdx.x * 64;
  const int w = t >> 6, lane = t & 63;
  const int li = lane & 15, lg = lane >> 4;

  const int cr0 = t >> 2, c0 = t & 3;
  const int cr1 = cr0 + 64;
  const unsigned stb0 = cr0 * 64 + ((c0 ^ ((cr0 >> 1) & 3)) << 4);
  const unsigned stb1 = cr1 * 64 + ((c0 ^ ((cr1 >> 1) & 3)) << 4);

  const int rowA = w * 16 + li;
  int nodeA = node0 + rowA;
  int ndA = nodeA < NN ? nodeA : NN - 1;
  const float* a0p = hin + (size_t)ndA * HD + lg * 8;
  const float* a1p = aggH + (size_t)ndA * HD + lg * 8;
  const float* a2p = aggH + (size_t)NN * HD + (size_t)ndA * HD + lg * 8;

#define STORE_BT(SH0, SL0, SH1, SL1)              \
  do {                                            \
    *(uint4*)((char*)bt_hi + stb0) = (SH0);       \
    *(uint4*)((char*)bt_lo + stb0) = (SL0);       \
    *(uint4*)((char*)bt_hi + stb1) = (SH1);       \
    *(uint4*)((char*)bt_lo + stb1) = (SL1);       \
  } while (0)

#define CVT_A2(FA, FB, AH, AL)                                                   \
  do {                                                                           \
    cvt_pair((FA)[0], (FA)[1], (AH).u[0], (AL).u[0]);                            \
    cvt_pair((FA)[2], (FA)[3], (AH).u[1], (AL).u[1]);                            \
    cvt_pair((FB)[0], (FB)[1], (AH).u[2], (AL).u[2]);                            \
    cvt_pair((FB)[2], (FB)[3], (AH).u[3], (AL).u[3]);                            \
  } while (0)

#define MFMA8(AH, AL, ACC)                                                       \
  do {                                                                           \
    _Pragma("unroll")                                                            \
    for (int ct_ = 0; ct_ < 8; ++ct_) {                                          \
      int colrow_ = ct_ * 16 + li;                                               \
      int byte_ = colrow_ * 64 + (lg << 4);                                      \
      byte_ ^= ((colrow_ >> 1) & 3) << 4;                                        \
      Frag bh_, bl_;                                                             \
      bh_.v = *(const uint4*)((char*)bt_hi + byte_);                             \
      bl_.v = *(const uint4*)((char*)bt_lo + byte_);                             \
      (ACC)[ct_] = __builtin_amdgcn_mfma_f32_16x16x32_bf16((AH).s, bl_.s, (ACC)[ct_], 0, 0, 0); \
      (ACC)[ct_] = __builtin_amdgcn_mfma_f32_16x16x32_bf16((AL).s, bh_.s, (ACC)[ct_], 0, 0, 0); \
      (ACC)[ct_] = __builtin_amdgcn_mfma_f32_16x16x32_bf16((AH).s, bh_.s, (ACC)[ct_], 0, 0, 0); \
    }                                                                            \
  } while (0)

#define W2H(KT, CR) (wl_hi + ((KT) >> 2) * 16384 + (CR) * 128 + ((KT) & 3) * 32 + c0 * 8)
#define W2L(KT, CR) (wl_lo + ((KT) >> 2) * 16384 + (CR) * 128 + ((KT) & 3) * 32 + c0 * 8)

#define TILE2(WC0, WC1, WC2, WC3, WN0, WN1, WN2, WN3, XA, XB, T)                 \
  do {                                                                           \
    STORE_BT(WC0, WC1, WC2, WC3);                                                \
    lgkm0_barrier();                                                             \
    Frag ah_, al_;                                                               \
    CVT_A2(XA, XB, ah_, al_);                                                    \
    {                                                                            \
      int kn_ = (T) + 1; if (kn_ > 11) kn_ = 11;                                 \
      WN0 = *(const uint4*)W2H(kn_, cr0); WN1 = *(const uint4*)W2L(kn_, cr0);    \
      WN2 = *(const uint4*)W2H(kn_, cr1); WN3 = *(const uint4*)W2L(kn_, cr1);    \
      int kx_ = (T) + 3; if (kx_ > 11) kx_ = 11;                                 \
      const float* ap_ = (kx_ < 4) ? a0p : (kx_ < 8) ? a1p : a2p;                \
      XA = *(const f32x4u*)(ap_ + (kx_ & 3) * 32);                               \
      XB = *(const f32x4u*)(ap_ + (kx_ & 3) * 32 + 4);                           \
    }                                                                            \
    MFMA8(ah_, al_, acc);                                                        \
    fence_barrier();                                                             \
  } while (0)

  f32x4 acc[8];
#pragma unroll
  for (int b = 0; b < 8; ++b) acc[b] = (f32x4)0.f;

  uint4 WA0, WA1, WA2, WA3, WB0, WB1, WB2, WB3;
  f32x4u X0a, X0b, X1a, X1b, X2a, X2b;

  // prologue: W tile 0, A tiles 0..2
  WA0 = *(const uint4*)W2H(0, cr0); WA1 = *(const uint4*)W2L(0, cr0);
  WA2 = *(const uint4*)W2H(0, cr1); WA3 = *(const uint4*)W2L(0, cr1);
  X0a = *(const f32x4u*)(a0p);      X0b = *(const f32x4u*)(a0p + 4);
  X1a = *(const f32x4u*)(a0p + 32); X1b = *(const f32x4u*)(a0p + 36);
  X2a = *(const f32x4u*)(a0p + 64); X2b = *(const f32x4u*)(a0p + 68);

  TILE2(WA0, WA1, WA2, WA3, WB0, WB1, WB2, WB3, X0a, X0b, 0);
  TILE2(WB0, WB1, WB2, WB3, WA0, WA1, WA2, WA3, X1a, X1b, 1);
  TILE2(WA0, WA1, WA2, WA3, WB0, WB1, WB2, WB3, X2a, X2b, 2);
  TILE2(WB0, WB1, WB2, WB3, WA0, WA1, WA2, WA3, X0a, X0b, 3);
  TILE2(WA0, WA1, WA2, WA3, WB0, WB1, WB2, WB3, X1a, X1b, 4);
  TILE2(WB0, WB1, WB2, WB3, WA0, WA1, WA2, WA3, X2a, X2b, 5);
  TILE2(WA0, WA1, WA2, WA3, WB0, WB1, WB2, WB3, X0a, X0b, 6);
  TILE2(WB0, WB1, WB2, WB3, WA0, WA1, WA2, WA3, X1a, X1b, 7);
  TILE2(WA0, WA1, WA2, WA3, WB0, WB1, WB2, WB3, X2a, X2b, 8);
  TILE2(WB0, WB1, WB2, WB3, WA0, WA1, WA2, WA3, X0a, X0b, 9);
  TILE2(WA0, WA1, WA2, WA3, WB0, WB1, WB2, WB3, X1a, X1b, 10);
  TILE2(WB0, WB1, WB2, WB3, WA0, WA1, WA2, WA3, X2a, X2b, 11);

  // epilogue: + bias, store (and optional bf16 copy)
#pragma unroll
  for (int ct = 0; ct < 8; ++ct) {
    int col = ct * 16 + li;
    float bv = bias[col];
#pragma unroll
    for (int r = 0; r < 4; ++r) {
      int node = node0 + w * 16 + lg * 4 + r;
      if (node < NN) {
        float v = acc[ct][r] + bv;
        outp[(size_t)node * HD + col] = v;
        if (h16out) h16out[(size_t)node * HD + col] = bf16_rne(v);
      }
    }
  }

#undef W2H
#undef W2L
#undef TILE2
#undef MFMA8
#undef CVT_A2
#undef STORE_BT
}

extern "C" void kernel_launch(void* const* d_in, const int* in_sizes, int n_in,
                              void* d_out, int out_size, void* d_ws, size_t ws_size,
                              hipStream_t stream) {
  const float* x    = (const float*)d_in[0];
  const int* ei     = (const int*)d_in[1];
  const int* et     = (const int*)d_in[2];
  const float* Wdes = (const float*)d_in[3];
  const float* bdes = (const float*)d_in[4];
  const float* Wtw  = (const float*)d_in[5];
  const float* btw  = (const float*)d_in[6];
  const float* Wnum = (const float*)d_in[7];
  const float* bnum = (const float*)d_in[8];
  const float* Wcat = (const float*)d_in[9];
  const float* bcat = (const float*)d_in[10];
  const float* Win  = (const float*)d_in[11];
  const float* bin  = (const float*)d_in[12];
  const float* pa   = (const float*)d_in[13];
  const float* root1 = (const float*)d_in[14];
  const float* rel1  = (const float*)d_in[15];
  const float* bias1 = (const float*)d_in[16];
  const float* root2 = (const float*)d_in[17];
  const float* rel2  = (const float*)d_in[18];
  const float* bias2 = (const float*)d_in[19];
  const float* Wcls  = (const float*)d_in[20];
  const float* bcls  = (const float*)d_in[21];
  float* out = (float*)d_out;

  char* p = (char*)d_ws;
  float* aggH = (float*)p;    p += (size_t)2 * NN * HD * 4;   // 102.4 MB
  float* hB = (float*)p;      p += (size_t)NN * HD * 4;       // 51.2 MB
  int* row_ptr = (int*)p;     p += ((size_t)NN + 4) * 4;
  int* cnt2 = (int*)p;        p += (size_t)2 * NN * 4;
  int* fillpos = (int*)p;     p += (size_t)NN * 4;
  int* entries = (int*)p;     p += (size_t)EE * 4;
  int* bsum = (int*)p;        p += 512;
  float* bfused = (float*)p;  p += 512;
  unsigned short* h16 = (unsigned short*)p; p += (size_t)NN * HD * 2;  // 25.6 MB
  unsigned short* Wt = (unsigned short*)p;  p += (size_t)WT_SITES * 2 * 2;

  // zero counters first (cnt2 + fillpos)
  (void)hipMemsetAsync(cnt2, 0, (size_t)3 * NN * 4, stream);
  // setup: weight pre-convert (blocks 0..1503) + edge count (blocks 1504..) fused
  k_setup<<<PREPW_BLOCKS + COUNT_BLOCKS, 256, 0, stream>>>(
      Wdes, Wtw, Wnum, Wcat, Win, root1, rel1, root2, rel2, Wcls, Wt,
      ei, et, cnt2);
  // classifier fusion: overwrite OFF_L2 with [root2;rel2]@Wcls, bfused = b2@Wcls+bcls
  k_fusew<<<385, 128, 0, stream>>>(root2, rel2, Wcls, bias2, bcls, Wt, bfused);

  // CSR scans
  int nb = (NN + 1023) / 1024;
  k_scan1<<<nb, 256, 0, stream>>>(cnt2, row_ptr, bsum);
  k_scan2<<<1, 128, 0, stream>>>(bsum, nb);
  k_scan3<<<(NN + 1 + 255) / 256, 256, 0, stream>>>(row_ptr, bsum);

  // h0 -> d_out (+ h16 bf16 copy), with CSR fill fused in (blocks >= PROJ128_NBLK)
  k_proj2<<<PROJ128_NBLK + FILL_BLOCKS, 256, 0, stream>>>(
      x, bdes, btw, bnum, bcat, bin, pa, Wt, out, h16,
      ei, et, row_ptr, fillpos, entries);
  // layer 1: gather neighbor means (bf16 source), then fused K=384 GEMM -> hB
  k_gather<<<NN / 4, 256, 0, stream>>>(h16, aggH, row_ptr, cnt2, entries);
  k_rgemm2<<<NBLK64, 256, 0, stream>>>(out, aggH, Wt + OFF_L1_HI, Wt + OFF_L1_LO,
                                       bias1, hB, h16);
  // layer 2 + classifier (algebraically fused): out = [hB|agg] @ (W2@Wcls) + bfused
  k_gather<<<NN / 4, 256, 0, stream>>>(h16, aggH, row_ptr, cnt2, entries);
  k_rgemm2<<<NBLK64, 256, 0, stream>>>(hB, aggH, Wt + OFF_L2_HI, Wt + OFF_L2_LO,
                                       bfused, out, (unsigned short*)nullptr);
}

// Round 14
// 807.795 us; speedup vs baseline: 1.6446x; 1.0421x over previous
//
#include <hip/hip_runtime.h>
#include <cstdint>
#include <cstddef>

#define NN 100000
#define EE 1600000
#define XDIM 1553
#define HD 128

typedef __attribute__((ext_vector_type(8))) short short8;
typedef __attribute__((ext_vector_type(4))) float f32x4;
// unaligned-capable 4-float vector: hardware allows 4B-aligned dwordx4
typedef float f32x4u __attribute__((vector_size(16), aligned(4)));

union Frag { unsigned int u[4]; short8 s; uint4 v; };

// weight area offsets (ushort units); hi/lo are separate regions
#define OFF_DES_HI 0
#define OFF_DES_LO 98304
#define OFF_TW_HI  196608
#define OFF_TW_LO  294912
#define OFF_NUM_HI 393216
#define OFF_NUM_LO 397312
#define OFF_CAT_HI 401408
#define OFF_CAT_LO 405504
#define OFF_WIN_HI 409600
#define OFF_WIN_LO 475136
#define OFF_L1_HI  540672
#define OFF_L1_LO  589824
#define OFF_L2_HI  638976
#define OFF_L2_LO  688128
#define OFF_CLS_HI 737280
#define OFF_CLS_LO 753664
#define WT_SITES   385024   // (col,k) sites; each writes hi+lo

#define PREPW_BLOCKS 1504   // WT_SITES / 256
#define COUNT_BLOCKS 6250   // EE / 256
#define NBLK64       1563   // (NN + 63) / 64   (rgemm2 grid)
#define PROJ128_NBLK 782    // (NN + 127) / 128 (proj grid)
#define FILL_BLOCKS  6250   // EE / 256

// hi = trunc-bf16(f), lo = trunc-bf16(f - hi). Packed: 2 elems -> 1 u32 via v_perm.
__device__ __forceinline__ void cvt_pair(float f0, float f1,
                                         unsigned int& hi, unsigned int& lo) {
  unsigned int u0 = __float_as_uint(f0), u1 = __float_as_uint(f1);
  hi = __builtin_amdgcn_perm(u1, u0, 0x07060302u);
  float l0 = f0 - __uint_as_float(u0 & 0xFFFF0000u);
  float l1 = f1 - __uint_as_float(u1 & 0xFFFF0000u);
  lo = __builtin_amdgcn_perm(__float_as_uint(l1), __float_as_uint(l0), 0x07060302u);
}

// round-to-nearest-even bf16
__device__ __forceinline__ unsigned short bf16_rne(float f) {
  unsigned int u = __float_as_uint(f);
  return (unsigned short)((u + 0x7FFFu + ((u >> 16) & 1u)) >> 16);
}

// raw barriers: no vmcnt drain (prefetched global loads ride across);
// lgkm0 variant publishes ds_writes before the barrier.
__device__ __forceinline__ void fence_barrier() {
  asm volatile("" ::: "memory");
  __builtin_amdgcn_s_barrier();
  asm volatile("" ::: "memory");
}
__device__ __forceinline__ void lgkm0_barrier() {
  asm volatile("s_waitcnt lgkmcnt(0)" ::: "memory");
  __builtin_amdgcn_s_barrier();
  asm volatile("" ::: "memory");
}

// ---------------- setup: weight pre-convert/transpose + edge count (fused) ------
__global__ __launch_bounds__(256) void k_setup(
    const float* __restrict__ Wdes, const float* __restrict__ Wtw,
    const float* __restrict__ Wnum, const float* __restrict__ Wcat,
    const float* __restrict__ Win,  const float* __restrict__ root1,
    const float* __restrict__ rel1, const float* __restrict__ root2,
    const float* __restrict__ rel2, const float* __restrict__ Wcls,
    unsigned short* __restrict__ Wt,
    const int* __restrict__ ei, const int* __restrict__ et,
    int* __restrict__ cnt2) {
  if (blockIdx.x >= PREPW_BLOCKS) {
    int e = (blockIdx.x - PREPW_BLOCKS) * 256 + threadIdx.x;
    if (e < EE) atomicAdd(&cnt2[et[e] * NN + ei[EE + e]], 1);
    return;
  }
  int id = blockIdx.x * 256 + threadIdx.x;
  if (id >= WT_SITES) return;
  const float* src; int K, Kpad, dhi, dlo, local;
  if (id < 98304)       { src=Wdes;        K=768; Kpad=768; dhi=OFF_DES_HI;       dlo=OFF_DES_LO;       local=id; }
  else if (id < 196608) { src=Wtw;         K=768; Kpad=768; dhi=OFF_TW_HI;        dlo=OFF_TW_LO;        local=id-98304; }
  else if (id < 200704) { src=Wnum;        K=6;   Kpad=32;  dhi=OFF_NUM_HI;       dlo=OFF_NUM_LO;       local=id-196608; }
  else if (id < 204800) { src=Wcat;        K=11;  Kpad=32;  dhi=OFF_CAT_HI;       dlo=OFF_CAT_LO;       local=id-200704; }
  else if (id < 270336) { src=Win;         K=512; Kpad=512; dhi=OFF_WIN_HI;       dlo=OFF_WIN_LO;       local=id-204800; }
  else if (id < 286720) { src=root1;       K=128; Kpad=128; dhi=OFF_L1_HI;        dlo=OFF_L1_LO;        local=id-270336; }
  else if (id < 303104) { src=rel1;        K=128; Kpad=128; dhi=OFF_L1_HI+16384;  dlo=OFF_L1_LO+16384;  local=id-286720; }
  else if (id < 319488) { src=rel1+16384;  K=128; Kpad=128; dhi=OFF_L1_HI+32768;  dlo=OFF_L1_LO+32768;  local=id-303104; }
  else if (id < 335872) { src=root2;       K=128; Kpad=128; dhi=OFF_L2_HI;        dlo=OFF_L2_LO;        local=id-319488; }
  else if (id < 352256) { src=rel2;        K=128; Kpad=128; dhi=OFF_L2_HI+16384;  dlo=OFF_L2_LO+16384;  local=id-335872; }
  else if (id < 368640) { src=rel2+16384;  K=128; Kpad=128; dhi=OFF_L2_HI+32768;  dlo=OFF_L2_LO+32768;  local=id-352256; }
  else                  { src=Wcls;        K=128; Kpad=128; dhi=OFF_CLS_HI;       dlo=OFF_CLS_LO;       local=id-368640; }
  int col = local / Kpad;
  int k = local - col * Kpad;
  float v = (k < K) ? src[(size_t)k * 128 + col] : 0.f;
  unsigned int u = __float_as_uint(v);
  float lo = v - __uint_as_float(u & 0xFFFF0000u);
  Wt[dhi + col * Kpad + k] = (unsigned short)(u >> 16);
  Wt[dlo + col * Kpad + k] = (unsigned short)(__float_as_uint(lo) >> 16);
}

// ---------------- classifier fusion: Wfused = [root2;rel2] @ Wcls (K-stacked) ----
__global__ __launch_bounds__(128) void k_fusew(
    const float* __restrict__ root2, const float* __restrict__ rel2,
    const float* __restrict__ Wcls,  const float* __restrict__ bias2,
    const float* __restrict__ bcls,  unsigned short* __restrict__ Wt,
    float* __restrict__ bfused) {
  int k = blockIdx.x;
  int c = threadIdx.x;
  const float* wrow;
  if (k < 128)      wrow = root2 + (size_t)k * 128;
  else if (k < 256) wrow = rel2 + (size_t)(k - 128) * 128;
  else if (k < 384) wrow = rel2 + 16384 + (size_t)(k - 256) * 128;
  else              wrow = bias2;
  float s = 0.f;
  for (int j = 0; j < 128; ++j) s += wrow[j] * Wcls[(size_t)j * 128 + c];
  if (k == 384) { bfused[c] = s + bcls[c]; return; }
  unsigned int u = __float_as_uint(s);
  float lo = s - __uint_as_float(u & 0xFFFF0000u);
  int sub = k >> 7, kl = k & 127;
  Wt[OFF_L2_HI + sub * 16384 + c * 128 + kl] = (unsigned short)(u >> 16);
  Wt[OFF_L2_LO + sub * 16384 + c * 128 + kl] = (unsigned short)(__float_as_uint(lo) >> 16);
}

// ---------------- CSR scans ----------------
__global__ __launch_bounds__(256) void k_scan1(const int* __restrict__ cnt2,
                                               int* __restrict__ row_ptr,
                                               int* __restrict__ bsum) {
  __shared__ int sums[256];
  int t = threadIdx.x;
  int base = blockIdx.x * 1024 + t * 4;
  int v[4]; int s = 0;
#pragma unroll
  for (int j = 0; j < 4; ++j) {
    int idx = base + j;
    v[j] = (idx < NN) ? (cnt2[idx] + cnt2[NN + idx]) : 0;
    s += v[j];
  }
  sums[t] = s;
  __syncthreads();
  for (int d = 1; d < 256; d <<= 1) {
    int val = (t >= d) ? sums[t - d] : 0;
    __syncthreads();
    sums[t] += val;
    __syncthreads();
  }
  int excl = sums[t] - s;
  if (t == 255) bsum[blockIdx.x] = sums[t];
  int run = excl;
#pragma unroll
  for (int j = 0; j < 4; ++j) {
    int idx = base + j;
    if (idx < NN) row_ptr[idx] = run;
    run += v[j];
  }
}

__global__ __launch_bounds__(128) void k_scan2(int* __restrict__ bsum, int nb) {
  __shared__ int s[128];
  int t = threadIdx.x;
  int v = (t < nb) ? bsum[t] : 0;
  s[t] = v;
  __syncthreads();
  for (int d = 1; d < 128; d <<= 1) {
    int val = (t >= d) ? s[t - d] : 0;
    __syncthreads();
    s[t] += val;
    __syncthreads();
  }
  if (t < nb) bsum[t] = s[t] - v;
}

__global__ __launch_bounds__(256) void k_scan3(int* __restrict__ row_ptr,
                                               const int* __restrict__ bsum) {
  int idx = blockIdx.x * 256 + threadIdx.x;
  if (idx < NN) row_ptr[idx] += bsum[idx >> 10];
  if (idx == NN) row_ptr[NN] = EE;
}

// ---------------- fused projection + CSR fill (MFMA, split-bf16, raw barriers) ---
// Blocks 0..781: 128 nodes/block, 4 waves, wave = 32 rows (2 subs) x 128 cols.
// Blocks >= 782: CSR fill. Epilogue emits h0 (f32) + h16 (bf16).
__global__ __launch_bounds__(256, 2) void k_proj2(
    const float* __restrict__ x,
    const float* __restrict__ bdes, const float* __restrict__ btw,
    const float* __restrict__ bnum, const float* __restrict__ bcat,
    const float* __restrict__ bin,  const float* __restrict__ pa,
    const unsigned short* __restrict__ Wt, float* __restrict__ h0,
    unsigned short* __restrict__ h16,
    const int* __restrict__ ei, const int* __restrict__ et,
    const int* __restrict__ row_ptr, int* __restrict__ fillpos,
    int* __restrict__ entries) {
  __shared__ unsigned short bt_hi[128 * 32], bt_lo[128 * 32];   // 8KB + 8KB
  __shared__ unsigned short z_hi[128 * 128], z_lo[128 * 128];   // 32KB + 32KB

  if (blockIdx.x >= PROJ128_NBLK) {
    int e = (blockIdx.x - PROJ128_NBLK) * 256 + threadIdx.x;
    if (e < EE) {
      int src = ei[e];
      int dst = ei[EE + e];
      int r = et[e];
      int pos = atomicAdd(&fillpos[dst], 1);
      entries[row_ptr[dst] + pos] = src | (r << 20);
    }
    return;
  }

  const int t = threadIdx.x;
  const int node0 = blockIdx.x * 128;
  const int w = t >> 6, lane = t & 63;
  const int li = lane & 15, lg = lane >> 4;

  // B-staging constants (loop-invariant per thread)
  const int cr0 = t >> 2, c0 = t & 3;
  const int cr1 = cr0 + 64;
  const unsigned stb0 = cr0 * 64 + ((c0 ^ ((cr0 >> 1) & 3)) << 4);
  const unsigned stb1 = cr1 * 64 + ((c0 ^ ((cr1 >> 1) & 3)) << 4);

  // two A-rows per (wave, li): sub0 = w*32+li, sub1 = +16
  const int rowA0 = w * 32 + li;
  const int rowA1 = rowA0 + 16;
  int nodeA0 = node0 + rowA0; int nd0 = nodeA0 < NN ? nodeA0 : NN - 1;
  int nodeA1 = node0 + rowA1; int nd1 = nodeA1 < NN ? nodeA1 : NN - 1;
  const float* xrow0 = x + (size_t)nd0 * XDIM;
  const float* xrow1 = x + (size_t)nd1 * XDIM;

#define STORE_BT(SH0, SL0, SH1, SL1)              \
  do {                                            \
    *(uint4*)((char*)bt_hi + stb0) = (SH0);       \
    *(uint4*)((char*)bt_lo + stb0) = (SL0);       \
    *(uint4*)((char*)bt_hi + stb1) = (SH1);       \
    *(uint4*)((char*)bt_lo + stb1) = (SL1);       \
  } while (0)

#define CVT_A2(FA, FB, AH, AL)                                                   \
  do {                                                                           \
    cvt_pair((FA)[0], (FA)[1], (AH).u[0], (AL).u[0]);                            \
    cvt_pair((FA)[2], (FA)[3], (AH).u[1], (AL).u[1]);                            \
    cvt_pair((FB)[0], (FB)[1], (AH).u[2], (AL).u[2]);                            \
    cvt_pair((FB)[2], (FB)[3], (AH).u[3], (AL).u[3]);                            \
  } while (0)

// 8 col-tiles; B frags read ONCE, used by both subs.
#define MFMA8_2(A0H, A0L, A1H, A1L, ACC)                                         \
  do {                                                                           \
    _Pragma("unroll")                                                            \
    for (int ct_ = 0; ct_ < 8; ++ct_) {                                          \
      int colrow_ = ct_ * 16 + li;                                               \
      int byte_ = colrow_ * 64 + (lg << 4);                                      \
      byte_ ^= ((colrow_ >> 1) & 3) << 4;                                        \
      Frag bh_, bl_;                                                             \
      bh_.v = *(const uint4*)((char*)bt_hi + byte_);                             \
      bl_.v = *(const uint4*)((char*)bt_lo + byte_);                             \
      (ACC)[0][ct_] = __builtin_amdgcn_mfma_f32_16x16x32_bf16((A0H).s, bl_.s, (ACC)[0][ct_], 0, 0, 0); \
      (ACC)[0][ct_] = __builtin_amdgcn_mfma_f32_16x16x32_bf16((A0L).s, bh_.s, (ACC)[0][ct_], 0, 0, 0); \
      (ACC)[0][ct_] = __builtin_amdgcn_mfma_f32_16x16x32_bf16((A0H).s, bh_.s, (ACC)[0][ct_], 0, 0, 0); \
      (ACC)[1][ct_] = __builtin_amdgcn_mfma_f32_16x16x32_bf16((A1H).s, bl_.s, (ACC)[1][ct_], 0, 0, 0); \
      (ACC)[1][ct_] = __builtin_amdgcn_mfma_f32_16x16x32_bf16((A1L).s, bh_.s, (ACC)[1][ct_], 0, 0, 0); \
      (ACC)[1][ct_] = __builtin_amdgcn_mfma_f32_16x16x32_bf16((A1H).s, bh_.s, (ACC)[1][ct_], 0, 0, 0); \
    }                                                                            \
  } while (0)

#define TILE(WC0, WC1, WC2, WC3, WN0, WN1, WN2, WN3, XA0, XB0, XA1, XB1, T)      \
  do {                                                                           \
    STORE_BT(WC0, WC1, WC2, WC3);                                                \
    lgkm0_barrier();                                                             \
    Frag a0h_, a0l_, a1h_, a1l_;                                                 \
    CVT_A2(XA0, XB0, a0h_, a0l_);                                                \
    CVT_A2(XA1, XB1, a1h_, a1l_);                                                \
    {                                                                            \
      const int kw_ = ((T) + 1) * 32;                                            \
      WN0 = *(const uint4*)(ph0 + kw_); WN1 = *(const uint4*)(pl0 + kw_);        \
      WN2 = *(const uint4*)(ph1 + kw_); WN3 = *(const uint4*)(pl1 + kw_);        \
      int kx_ = (T) + 2; if (kx_ > 23) kx_ = 23; kx_ *= 32;                      \
      XA0 = *(const f32x4u*)(xr0 + kx_);                                         \
      XB0 = *(const f32x4u*)(xr0 + kx_ + 4);                                     \
      XA1 = *(const f32x4u*)(xr1 + kx_);                                         \
      XB1 = *(const f32x4u*)(xr1 + kx_ + 4);                                     \
    }                                                                            \
    MFMA8_2(a0h_, a0l_, a1h_, a1l_, zacc);                                       \
    fence_barrier();                                                             \
  } while (0)

#define MFMA_B(KT)                                                               \
  do {                                                                           \
    Frag a0h_, a0l_, a1h_, a1l_;                                                 \
    {                                                                            \
      int byte0_ = rowA0 * 256 + (((KT) * 32 + lg * 8) << 1);                    \
      byte0_ ^= (rowA0 & 7) << 4;                                                \
      a0h_.v = *(const uint4*)((char*)z_hi + byte0_);                            \
      a0l_.v = *(const uint4*)((char*)z_lo + byte0_);                            \
      int byte1_ = rowA1 * 256 + (((KT) * 32 + lg * 8) << 1);                    \
      byte1_ ^= (rowA1 & 7) << 4;                                                \
      a1h_.v = *(const uint4*)((char*)z_hi + byte1_);                            \
      a1l_.v = *(const uint4*)((char*)z_lo + byte1_);                            \
    }                                                                            \
    MFMA8_2(a0h_, a0l_, a1h_, a1l_, hacc);                                       \
  } while (0)

#define Z_EPI(ZACC, BIASP)                                                       \
  do {                                                                           \
    _Pragma("unroll")                                                            \
    for (int ct_ = 0; ct_ < 8; ++ct_) {                                          \
      int col_ = ct_ * 16 + li;                                                  \
      float bv_ = (BIASP)[col_];                                                 \
      _Pragma("unroll")                                                          \
      for (int sub_ = 0; sub_ < 2; ++sub_) {                                     \
        _Pragma("unroll")                                                        \
        for (int r_ = 0; r_ < 4; ++r_) {                                         \
          float v_ = (ZACC)[sub_][ct_][r_] + bv_;                                \
          v_ = v_ >= 0.f ? v_ : 0.01f * v_;                                      \
          int row_ = w * 32 + sub_ * 16 + lg * 4 + r_;                           \
          int byte_ = row_ * 256 + col_ * 2;                                     \
          byte_ ^= (row_ & 7) << 4;                                              \
          unsigned int u_ = __float_as_uint(v_);                                 \
          *(unsigned short*)((char*)z_hi + byte_) = (unsigned short)(u_ >> 16);  \
          float lo_ = v_ - __uint_as_float(u_ & 0xFFFF0000u);                    \
          *(unsigned short*)((char*)z_lo + byte_) = (unsigned short)(__float_as_uint(lo_) >> 16); \
        }                                                                        \
      }                                                                          \
    }                                                                            \
  } while (0)

#define PHASE_B(SLICE)                                                           \
  do {                                                                           \
    const unsigned short* qh0_ = Wt + OFF_WIN_HI + cr0 * 512 + (SLICE) * 128 + c0 * 8; \
    const unsigned short* ql0_ = Wt + OFF_WIN_LO + cr0 * 512 + (SLICE) * 128 + c0 * 8; \
    const unsigned short* qh1_ = Wt + OFF_WIN_HI + cr1 * 512 + (SLICE) * 128 + c0 * 8; \
    const unsigned short* ql1_ = Wt + OFF_WIN_LO + cr1 * 512 + (SLICE) * 128 + c0 * 8; \
    uint4 wA0_ = *(const uint4*)(qh0_), wA1_ = *(const uint4*)(ql0_);            \
    uint4 wA2_ = *(const uint4*)(qh1_), wA3_ = *(const uint4*)(ql1_);            \
    uint4 wB0_, wB1_, wB2_, wB3_;                                                \
    STORE_BT(wA0_, wA1_, wA2_, wA3_);                                            \
    lgkm0_barrier();                                                             \
    wB0_ = *(const uint4*)(qh0_ + 32); wB1_ = *(const uint4*)(ql0_ + 32);        \
    wB2_ = *(const uint4*)(qh1_ + 32); wB3_ = *(const uint4*)(ql1_ + 32);        \
    MFMA_B(0);                                                                   \
    fence_barrier();                                                             \
    STORE_BT(wB0_, wB1_, wB2_, wB3_);                                            \
    lgkm0_barrier();                                                             \
    wA0_ = *(const uint4*)(qh0_ + 64); wA1_ = *(const uint4*)(ql0_ + 64);        \
    wA2_ = *(const uint4*)(qh1_ + 64); wA3_ = *(const uint4*)(ql1_ + 64);        \
    MFMA_B(1);                                                                   \
    fence_barrier();                                                             \
    STORE_BT(wA0_, wA1_, wA2_, wA3_);                                            \
    lgkm0_barrier();                                                             \
    wB0_ = *(const uint4*)(qh0_ + 96); wB1_ = *(const uint4*)(ql0_ + 96);        \
    wB2_ = *(const uint4*)(qh1_ + 96); wB3_ = *(const uint4*)(ql1_ + 96);        \
    MFMA_B(2);                                                                   \
    fence_barrier();                                                             \
    STORE_BT(wB0_, wB1_, wB2_, wB3_);                                            \
    lgkm0_barrier();                                                             \
    MFMA_B(3);                                                                   \
    fence_barrier();                                                             \
  } while (0)

  f32x4 hacc[2][8];
#pragma unroll
  for (int a = 0; a < 2; ++a)
#pragma unroll
    for (int b = 0; b < 8; ++b) hacc[a][b] = (f32x4)0.f;

  // ---- big segments: des (s=0), tweet (s=1); K=768 = 24 K-tiles, pipelined ----
#pragma unroll
  for (int s = 0; s < 2; ++s) {
    const int off = (s == 0) ? 785 : 6;
    const unsigned short* wh = Wt + (s == 0 ? OFF_DES_HI : OFF_TW_HI);
    const unsigned short* wl = Wt + (s == 0 ? OFF_DES_LO : OFF_TW_LO);
    const float* bias = (s == 0) ? bdes : btw;

    const float* xr0 = xrow0 + off + lg * 8;
    const float* xr1 = xrow1 + off + lg * 8;
    const unsigned short* ph0 = wh + cr0 * 768 + c0 * 8;
    const unsigned short* pl0 = wl + cr0 * 768 + c0 * 8;
    const unsigned short* ph1 = wh + cr1 * 768 + c0 * 8;
    const unsigned short* pl1 = wl + cr1 * 768 + c0 * 8;

    f32x4 zacc[2][8];
#pragma unroll
    for (int a = 0; a < 2; ++a)
#pragma unroll
      for (int b = 0; b < 8; ++b) zacc[a][b] = (f32x4)0.f;

    uint4 WA0, WA1, WA2, WA3, WB0, WB1, WB2, WB3;
    f32x4u X0a0, X0b0, X0a1, X0b1, X1a0, X1b0, X1a1, X1b1;

    // prologue: W tile 0, X tiles 0..1 (depth-2 ping-pong)
    WA0 = *(const uint4*)(ph0); WA1 = *(const uint4*)(pl0);
    WA2 = *(const uint4*)(ph1); WA3 = *(const uint4*)(pl1);
    X0a0 = *(const f32x4u*)(xr0);      X0b0 = *(const f32x4u*)(xr0 + 4);
    X0a1 = *(const f32x4u*)(xr1);      X0b1 = *(const f32x4u*)(xr1 + 4);
    X1a0 = *(const f32x4u*)(xr0 + 32); X1b0 = *(const f32x4u*)(xr0 + 36);
    X1a1 = *(const f32x4u*)(xr1 + 32); X1b1 = *(const f32x4u*)(xr1 + 36);

    for (int base = 0; base < 24; base += 2) {
      TILE(WA0, WA1, WA2, WA3, WB0, WB1, WB2, WB3, X0a0, X0b0, X0a1, X0b1, base + 0);
      TILE(WB0, WB1, WB2, WB3, WA0, WA1, WA2, WA3, X1a0, X1b0, X1a1, X1b1, base + 1);
    }
    Z_EPI(zacc, bias);   // z slots are wave-private
    PHASE_B(s);
  }

  // ---- small segments: num (K=6), cat (K=11); single padded K-tile each ----
#pragma unroll
  for (int u = 0; u < 2; ++u) {
    const int offu = (u == 0) ? 0 : 774;
    const int Ksu = (u == 0) ? 6 : 11;
    const unsigned short* wh = Wt + (u == 0 ? OFF_NUM_HI : OFF_CAT_HI);
    const unsigned short* wl = Wt + (u == 0 ? OFF_NUM_LO : OFF_CAT_LO);
    const float* biasu = (u == 0) ? bnum : bcat;
    const float* xr0 = xrow0 + offu + lg * 8;
    const float* xr1 = xrow1 + offu + lg * 8;

    uint4 s0 = *(const uint4*)(wh + cr0 * 32 + c0 * 8);
    uint4 s1 = *(const uint4*)(wl + cr0 * 32 + c0 * 8);
    uint4 s2 = *(const uint4*)(wh + cr1 * 32 + c0 * 8);
    uint4 s3 = *(const uint4*)(wl + cr1 * 32 + c0 * 8);
    f32x4u fa0 = *(const f32x4u*)(xr0);
    f32x4u fb0 = *(const f32x4u*)(xr0 + 4);
    f32x4u fa1 = *(const f32x4u*)(xr1);
    f32x4u fb1 = *(const f32x4u*)(xr1 + 4);
#pragma unroll
    for (int j = 0; j < 4; ++j) {
      if (lg * 8 + j >= Ksu) { fa0[j] = 0.f; fa1[j] = 0.f; }
      if (lg * 8 + 4 + j >= Ksu) { fb0[j] = 0.f; fb1[j] = 0.f; }
    }

    f32x4 zacc[2][8];
#pragma unroll
    for (int a = 0; a < 2; ++a)
#pragma unroll
      for (int b = 0; b < 8; ++b) zacc[a][b] = (f32x4)0.f;

    STORE_BT(s0, s1, s2, s3);
    lgkm0_barrier();
    {
      Frag a0h_, a0l_, a1h_, a1l_;
      CVT_A2(fa0, fb0, a0h_, a0l_);
      CVT_A2(fa1, fb1, a1h_, a1l_);
      MFMA8_2(a0h_, a0l_, a1h_, a1l_, zacc);
    }
    fence_barrier();
    Z_EPI(zacc, biasu);
    PHASE_B(u + 2);
  }

  // epilogue: + b_in, PReLU, store (f32 + RNE-bf16 copy for the gather)
#pragma unroll
  for (int ct = 0; ct < 8; ++ct) {
    int col = ct * 16 + li;
    float bi = bin[col];
    float p = pa[col];
#pragma unroll
    for (int sub = 0; sub < 2; ++sub) {
#pragma unroll
      for (int r = 0; r < 4; ++r) {
        int node = node0 + w * 32 + sub * 16 + lg * 4 + r;
        if (node < NN) {
          float v = hacc[sub][ct][r] + bi;
          v = v >= 0.f ? v : p * v;
          h0[(size_t)node * HD + col] = v;
          h16[(size_t)node * HD + col] = bf16_rne(v);
        }
      }
    }
  }

#undef TILE
#undef MFMA_B
#undef Z_EPI
#undef PHASE_B
#undef MFMA8_2
#undef CVT_A2
#undef STORE_BT
}

// ---------------- neighbor-mean gather (bf16 in, bf16 out) ----------------------
// Gather is L3-BW-bound. Reads h16 (u32 = 2 bf16 cols per lane); accumulates f32;
// writes aggH as packed RNE-bf16 (halves aggH traffic; it only feeds bf16 MFMA).
__global__ __launch_bounds__(256) void k_gather(
    const unsigned short* __restrict__ h16, unsigned short* __restrict__ agg16,
    const int* __restrict__ row_ptr, const int* __restrict__ cnt2,
    const int* __restrict__ entries) {
  int i = blockIdx.x * 4 + (threadIdx.x >> 6);
  int l = threadIdx.x & 63;
  if (i >= NN) return;
  int rs = row_ptr[i], re = row_ptr[i + 1];
  int c0 = cnt2[i], c1 = cnt2[NN + i];
  float inv0 = 1.f / (float)(c0 > 0 ? c0 : 1);
  float inv1 = 1.f / (float)(c1 > 0 ? c1 : 1);
  float a0 = 0, a1 = 0, b0 = 0, b1 = 0;
  int e = rs;
  for (; e + 3 < re; e += 4) {
    int ent0 = entries[e], ent1 = entries[e + 1];
    int ent2 = entries[e + 2], ent3 = entries[e + 3];
    unsigned int p0 = ((const unsigned int*)(h16 + (size_t)(ent0 & 0xFFFFF) * HD))[l];
    unsigned int p1 = ((const unsigned int*)(h16 + (size_t)(ent1 & 0xFFFFF) * HD))[l];
    unsigned int p2 = ((const unsigned int*)(h16 + (size_t)(ent2 & 0xFFFFF) * HD))[l];
    unsigned int p3 = ((const unsigned int*)(h16 + (size_t)(ent3 & 0xFFFFF) * HD))[l];
    float v0x = __uint_as_float(p0 << 16), v0y = __uint_as_float(p0 & 0xFFFF0000u);
    float v1x = __uint_as_float(p1 << 16), v1y = __uint_as_float(p1 & 0xFFFF0000u);
    float v2x = __uint_as_float(p2 << 16), v2y = __uint_as_float(p2 & 0xFFFF0000u);
    float v3x = __uint_as_float(p3 << 16), v3y = __uint_as_float(p3 & 0xFFFF0000u);
    if (ent0 >> 20) { b0 += v0x; b1 += v0y; } else { a0 += v0x; a1 += v0y; }
    if (ent1 >> 20) { b0 += v1x; b1 += v1y; } else { a0 += v1x; a1 += v1y; }
    if (ent2 >> 20) { b0 += v2x; b1 += v2y; } else { a0 += v2x; a1 += v2y; }
    if (ent3 >> 20) { b0 += v3x; b1 += v3y; } else { a0 += v3x; a1 += v3y; }
  }
  for (; e < re; ++e) {
    int ent = entries[e];
    unsigned int p0 = ((const unsigned int*)(h16 + (size_t)(ent & 0xFFFFF) * HD))[l];
    float v0x = __uint_as_float(p0 << 16), v0y = __uint_as_float(p0 & 0xFFFF0000u);
    if (ent >> 20) { b0 += v0x; b1 += v0y; } else { a0 += v0x; a1 += v0y; }
  }
  // pack: even col (2l) low half, odd col (2l+1) high half — matches cvt_pair order
  unsigned int* q0 = (unsigned int*)(agg16 + (size_t)i * HD);
  unsigned int* q1 = (unsigned int*)(agg16 + (size_t)NN * HD + (size_t)i * HD);
  q0[l] = (unsigned int)bf16_rne(a0 * inv0) | ((unsigned int)bf16_rne(a1 * inv0) << 16);
  q1[l] = (unsigned int)bf16_rne(b0 * inv1) | ((unsigned int)bf16_rne(b1 * inv1) << 16);
}

// ---------------- fused layer GEMM: out = [h|agg0|agg1] @ [root;rel0;rel1] + b ---
// kt 0-3: hin (f32, split-bf16, 3 MFMAs/tile). kt 4-11: agg16 (bf16 A-operand,
// A_lo = 0 exactly => al*bh MFMA dropped: 2 MFMAs/tile, bit-identical).
__global__ __launch_bounds__(256, 4) void k_rgemm2(
    const float* __restrict__ hin, const unsigned short* __restrict__ agg16,
    const unsigned short* __restrict__ wl_hi, const unsigned short* __restrict__ wl_lo,
    const float* __restrict__ bias, float* __restrict__ outp,
    unsigned short* __restrict__ h16out) {
  __shared__ unsigned short bt_hi[128 * 32], bt_lo[128 * 32];   // 8KB + 8KB

  const int t = threadIdx.x;
  const int node0 = blockIdx.x * 64;
  const int w = t >> 6, lane = t & 63;
  const int li = lane & 15, lg = lane >> 4;

  const int cr0 = t >> 2, c0 = t & 3;
  const int cr1 = cr0 + 64;
  const unsigned stb0 = cr0 * 64 + ((c0 ^ ((cr0 >> 1) & 3)) << 4);
  const unsigned stb1 = cr1 * 64 + ((c0 ^ ((cr1 >> 1) & 3)) << 4);

  const int rowA = w * 16 + li;
  int nodeA = node0 + rowA;
  int ndA = nodeA < NN ? nodeA : NN - 1;
  const float* a0p = hin + (size_t)ndA * HD + lg * 8;
  const unsigned short* g0p = agg16 + (size_t)ndA * HD + lg * 8;
  const unsigned short* g1p = agg16 + (size_t)NN * HD + (size_t)ndA * HD + lg * 8;

#define STORE_BT(SH0, SL0, SH1, SL1)              \
  do {                                            \
    *(uint4*)((char*)bt_hi + stb0) = (SH0);       \
    *(uint4*)((char*)bt_lo + stb0) = (SL0);       \
    *(uint4*)((char*)bt_hi + stb1) = (SH1);       \
    *(uint4*)((char*)bt_lo + stb1) = (SL1);       \
  } while (0)

#define CVT_A2(FA, FB, AH, AL)                                                   \
  do {                                                                           \
    cvt_pair((FA)[0], (FA)[1], (AH).u[0], (AL).u[0]);                            \
    cvt_pair((FA)[2], (FA)[3], (AH).u[1], (AL).u[1]);                            \
    cvt_pair((FB)[0], (FB)[1], (AH).u[2], (AL).u[2]);                            \
    cvt_pair((FB)[2], (FB)[3], (AH).u[3], (AL).u[3]);                            \
  } while (0)

// split path: 3 MFMAs per col-tile
#define MFMA8F(AH, AL)                                                           \
  do {                                                                           \
    _Pragma("unroll")                                                            \
    for (int ct_ = 0; ct_ < 8; ++ct_) {                                          \
      int colrow_ = ct_ * 16 + li;                                               \
      int byte_ = colrow_ * 64 + (lg << 4);                                      \
      byte_ ^= ((colrow_ >> 1) & 3) << 4;                                        \
      Frag bh_, bl_;                                                             \
      bh_.v = *(const uint4*)((char*)bt_hi + byte_);                             \
      bl_.v = *(const uint4*)((char*)bt_lo + byte_);                             \
      acc[ct_] = __builtin_amdgcn_mfma_f32_16x16x32_bf16((AH).s, bl_.s, acc[ct_], 0, 0, 0); \
      acc[ct_] = __builtin_amdgcn_mfma_f32_16x16x32_bf16((AL).s, bh_.s, acc[ct_], 0, 0, 0); \
      acc[ct_] = __builtin_amdgcn_mfma_f32_16x16x32_bf16((AH).s, bh_.s, acc[ct_], 0, 0, 0); \
    }                                                                            \
  } while (0)

// bf16-A path: A_lo == 0 exactly -> 2 MFMAs per col-tile (bit-identical)
#define MFMA8H(AH)                                                               \
  do {                                                                           \
    _Pragma("unroll")                                                            \
    for (int ct_ = 0; ct_ < 8; ++ct_) {                                          \
      int colrow_ = ct_ * 16 + li;                                               \
      int byte_ = colrow_ * 64 + (lg << 4);                                      \
      byte_ ^= ((colrow_ >> 1) & 3) << 4;                                        \
      Frag bh_, bl_;                                                             \
      bh_.v = *(const uint4*)((char*)bt_hi + byte_);                             \
      bl_.v = *(const uint4*)((char*)bt_lo + byte_);                             \
      acc[ct_] = __builtin_amdgcn_mfma_f32_16x16x32_bf16((AH).s, bl_.s, acc[ct_], 0, 0, 0); \
      acc[ct_] = __builtin_amdgcn_mfma_f32_16x16x32_bf16((AH).s, bh_.s, acc[ct_], 0, 0, 0); \
    }                                                                            \
  } while (0)

#define W2H(KT, CR) (wl_hi + ((KT) >> 2) * 16384 + (CR) * 128 + ((KT) & 3) * 32 + c0 * 8)
#define W2L(KT, CR) (wl_lo + ((KT) >> 2) * 16384 + (CR) * 128 + ((KT) & 3) * 32 + c0 * 8)
// bf16 agg A source for local tile j (0..7): rel0 j 0..3, rel1 j 4..7
#define GSRC(J) ((J) < 4 ? (g0p + (J) * 32) : (g1p + ((J) - 4) * 32))

  f32x4 acc[8];
#pragma unroll
  for (int b = 0; b < 8; ++b) acc[b] = (f32x4)0.f;

  uint4 WA0, WA1, WA2, WA3, WB0, WB1, WB2, WB3;
  f32x4u X0a, X0b, X1a, X1b, X2a, X2b;
  uint4 Y0, Y1;

  // prologue: W tile 0, hin tiles 0..2
  WA0 = *(const uint4*)W2H(0, cr0); WA1 = *(const uint4*)W2L(0, cr0);
  WA2 = *(const uint4*)W2H(0, cr1); WA3 = *(const uint4*)W2L(0, cr1);
  X0a = *(const f32x4u*)(a0p);      X0b = *(const f32x4u*)(a0p + 4);
  X1a = *(const f32x4u*)(a0p + 32); X1b = *(const f32x4u*)(a0p + 36);
  X2a = *(const f32x4u*)(a0p + 64); X2b = *(const f32x4u*)(a0p + 68);

  // ---- f32 section: kt 0..3 ----
  // T0: consume X0(kt0); prefetch W1, X(kt3)->X0 slot
  STORE_BT(WA0, WA1, WA2, WA3);
  lgkm0_barrier();
  {
    Frag ah_, al_;
    CVT_A2(X0a, X0b, ah_, al_);
    WB0 = *(const uint4*)W2H(1, cr0); WB1 = *(const uint4*)W2L(1, cr0);
    WB2 = *(const uint4*)W2H(1, cr1); WB3 = *(const uint4*)W2L(1, cr1);
    X0a = *(const f32x4u*)(a0p + 96); X0b = *(const f32x4u*)(a0p + 100);
    MFMA8F(ah_, al_);
  }
  fence_barrier();
  // T1: consume X1(kt1); prefetch W2, Y0(agg tile 0)
  STORE_BT(WB0, WB1, WB2, WB3);
  lgkm0_barrier();
  {
    Frag ah_, al_;
    CVT_A2(X1a, X1b, ah_, al_);
    WA0 = *(const uint4*)W2H(2, cr0); WA1 = *(const uint4*)W2L(2, cr0);
    WA2 = *(const uint4*)W2H(2, cr1); WA3 = *(const uint4*)W2L(2, cr1);
    Y0 = *(const uint4*)GSRC(0);
    MFMA8F(ah_, al_);
  }
  fence_barrier();
  // T2: consume X2(kt2); prefetch W3, Y1(agg tile 1)
  STORE_BT(WA0, WA1, WA2, WA3);
  lgkm0_barrier();
  {
    Frag ah_, al_;
    CVT_A2(X2a, X2b, ah_, al_);
    WB0 = *(const uint4*)W2H(3, cr0); WB1 = *(const uint4*)W2L(3, cr0);
    WB2 = *(const uint4*)W2H(3, cr1); WB3 = *(const uint4*)W2L(3, cr1);
    Y1 = *(const uint4*)GSRC(1);
    MFMA8F(ah_, al_);
  }
  fence_barrier();
  // T3: consume X0(kt3); prefetch W4
  STORE_BT(WB0, WB1, WB2, WB3);
  lgkm0_barrier();
  {
    Frag ah_, al_;
    CVT_A2(X0a, X0b, ah_, al_);
    WA0 = *(const uint4*)W2H(4, cr0); WA1 = *(const uint4*)W2L(4, cr0);
    WA2 = *(const uint4*)W2H(4, cr1); WA3 = *(const uint4*)W2L(4, cr1);
    MFMA8F(ah_, al_);
  }
  fence_barrier();

  // ---- bf16 agg section: local tiles 0..7 (kt 4..11), Y ping-pong depth-2 ----
#define TILEB(WC0, WC1, WC2, WC3, WN0, WN1, WN2, WN3, YB, J)                     \
  do {                                                                           \
    STORE_BT(WC0, WC1, WC2, WC3);                                                \
    lgkm0_barrier();                                                             \
    Frag ah_;                                                                    \
    ah_.v = (YB);                                                                \
    {                                                                            \
      int kn_ = (J) + 5; if (kn_ > 11) kn_ = 11;                                 \
      WN0 = *(const uint4*)W2H(kn_, cr0); WN1 = *(const uint4*)W2L(kn_, cr0);    \
      WN2 = *(const uint4*)W2H(kn_, cr1); WN3 = *(const uint4*)W2L(kn_, cr1);    \
      int jy_ = (J) + 2; if (jy_ > 7) jy_ = 7;                                   \
      (YB) = *(const uint4*)GSRC(jy_);                                           \
    }                                                                            \
    MFMA8H(ah_);                                                                 \
    fence_barrier();                                                             \
  } while (0)

  TILEB(WA0, WA1, WA2, WA3, WB0, WB1, WB2, WB3, Y0, 0);
  TILEB(WB0, WB1, WB2, WB3, WA0, WA1, WA2, WA3, Y1, 1);
  TILEB(WA0, WA1, WA2, WA3, WB0, WB1, WB2, WB3, Y0, 2);
  TILEB(WB0, WB1, WB2, WB3, WA0, WA1, WA2, WA3, Y1, 3);
  TILEB(WA0, WA1, WA2, WA3, WB0, WB1, WB2, WB3, Y0, 4);
  TILEB(WB0, WB1, WB2, WB3, WA0, WA1, WA2, WA3, Y1, 5);
  TILEB(WA0, WA1, WA2, WA3, WB0, WB1, WB2, WB3, Y0, 6);
  TILEB(WB0, WB1, WB2, WB3, WA0, WA1, WA2, WA3, Y1, 7);

  // epilogue: + bias, store (and optional bf16 copy)
#pragma unroll
  for (int ct = 0; ct < 8; ++ct) {
    int col = ct * 16 + li;
    float bv = bias[col];
#pragma unroll
    for (int r = 0; r < 4; ++r) {
      int node = node0 + w * 16 + lg * 4 + r;
      if (node < NN) {
        float v = acc[ct][r] + bv;
        outp[(size_t)node * HD + col] = v;
        if (h16out) h16out[(size_t)node * HD + col] = bf16_rne(v);
      }
    }
  }

#undef TILEB
#undef GSRC
#undef W2H
#undef W2L
#undef MFMA8H
#undef MFMA8F
#undef CVT_A2
#undef STORE_BT
}

extern "C" void kernel_launch(void* const* d_in, const int* in_sizes, int n_in,
                              void* d_out, int out_size, void* d_ws, size_t ws_size,
                              hipStream_t stream) {
  const float* x    = (const float*)d_in[0];
  const int* ei     = (const int*)d_in[1];
  const int* et     = (const int*)d_in[2];
  const float* Wdes = (const float*)d_in[3];
  const float* bdes = (const float*)d_in[4];
  const float* Wtw  = (const float*)d_in[5];
  const float* btw  = (const float*)d_in[6];
  const float* Wnum = (const float*)d_in[7];
  const float* bnum = (const float*)d_in[8];
  const float* Wcat = (const float*)d_in[9];
  const float* bcat = (const float*)d_in[10];
  const float* Win  = (const float*)d_in[11];
  const float* bin  = (const float*)d_in[12];
  const float* pa   = (const float*)d_in[13];
  const float* root1 = (const float*)d_in[14];
  const float* rel1  = (const float*)d_in[15];
  const float* bias1 = (const float*)d_in[16];
  const float* root2 = (const float*)d_in[17];
  const float* rel2  = (const float*)d_in[18];
  const float* bias2 = (const float*)d_in[19];
  const float* Wcls  = (const float*)d_in[20];
  const float* bcls  = (const float*)d_in[21];
  float* out = (float*)d_out;

  char* p = (char*)d_ws;
  unsigned short* agg16 = (unsigned short*)p; p += (size_t)2 * NN * HD * 2;  // 51.2 MB
  float* hB = (float*)p;      p += (size_t)NN * HD * 4;       // 51.2 MB
  int* row_ptr = (int*)p;     p += ((size_t)NN + 4) * 4;
  int* cnt2 = (int*)p;        p += (size_t)2 * NN * 4;
  int* fillpos = (int*)p;     p += (size_t)NN * 4;
  int* entries = (int*)p;     p += (size_t)EE * 4;
  int* bsum = (int*)p;        p += 512;
  float* bfused = (float*)p;  p += 512;
  unsigned short* h16 = (unsigned short*)p; p += (size_t)NN * HD * 2;  // 25.6 MB
  unsigned short* Wt = (unsigned short*)p;  p += (size_t)WT_SITES * 2 * 2;

  // zero counters first (cnt2 + fillpos)
  (void)hipMemsetAsync(cnt2, 0, (size_t)3 * NN * 4, stream);
  // setup: weight pre-convert (blocks 0..1503) + edge count (blocks 1504..) fused
  k_setup<<<PREPW_BLOCKS + COUNT_BLOCKS, 256, 0, stream>>>(
      Wdes, Wtw, Wnum, Wcat, Win, root1, rel1, root2, rel2, Wcls, Wt,
      ei, et, cnt2);
  // classifier fusion: overwrite OFF_L2 with [root2;rel2]@Wcls, bfused = b2@Wcls+bcls
  k_fusew<<<385, 128, 0, stream>>>(root2, rel2, Wcls, bias2, bcls, Wt, bfused);

  // CSR scans
  int nb = (NN + 1023) / 1024;
  k_scan1<<<nb, 256, 0, stream>>>(cnt2, row_ptr, bsum);
  k_scan2<<<1, 128, 0, stream>>>(bsum, nb);
  k_scan3<<<(NN + 1 + 255) / 256, 256, 0, stream>>>(row_ptr, bsum);

  // h0 -> d_out (+ h16 bf16 copy), with CSR fill fused in (blocks >= PROJ128_NBLK)
  k_proj2<<<PROJ128_NBLK + FILL_BLOCKS, 256, 0, stream>>>(
      x, bdes, btw, bnum, bcat, bin, pa, Wt, out, h16,
      ei, et, row_ptr, fillpos, entries);
  // layer 1: gather neighbor means (bf16 in/out), then fused K=384 GEMM -> hB
  k_gather<<<NN / 4, 256, 0, stream>>>(h16, agg16, row_ptr, cnt2, entries);
  k_rgemm2<<<NBLK64, 256, 0, stream>>>(out, agg16, Wt + OFF_L1_HI, Wt + OFF_L1_LO,
                                       bias1, hB, h16);
  // layer 2 + classifier (algebraically fused): out = [hB|agg] @ (W2@Wcls) + bfused
  k_gather<<<NN / 4, 256, 0, stream>>>(h16, agg16, row_ptr, cnt2, entries);
  k_rgemm2<<<NBLK64, 256, 0, stream>>>(hB, agg16, Wt + OFF_L2_HI, Wt + OFF_L2_LO,
                                       bfused, out, (unsigned short*)nullptr);
}